// Round 1
// baseline (3266.998 us; speedup 1.0000x reference)
//
#include <hip/hip_runtime.h>
#include <math.h>

#define NPOS 32768
#define CC 512
#define CO 256

// ---- ws layout (float offsets) ----
#define OFF_CTX    0          // [2][8][32][32] = 16384
#define OFF_ZP     16384      // [2][256]
#define OFF_COLS   16896      // [2][512]
#define OFF_HIGH2  17920      // [2][256]
#define OFF_CONSTD 18432      // [2][256]
#define OFF_WKT    18944      // [512][256]
#define OFF_WQT    150016
#define OFF_WVT    281088
#define OFF_WRT    412160     // [256][512]
#define OFF_A1T    543232     // [512][512]
#define OFF_A2T    805376     // [512][256]
#define OFF_D1AT   936448     // [256][256]
#define OFF_D1BT   1001984    // [256][256]
#define OFF_PW1T   1067520    // [512][512]
#define OFF_PW2T   1329664    // [512][256]

// ---------------- kernel 0: weight transposes into ws ----------------
__global__ __launch_bounds__(256) void k0_transpose(
    const float* __restrict__ wk, const float* __restrict__ wq, const float* __restrict__ wv,
    const float* __restrict__ wr, const float* __restrict__ a1, const float* __restrict__ a2,
    const float* __restrict__ d1, const float* __restrict__ pw1, const float* __restrict__ pw2,
    float* __restrict__ ws) {
  int idx = blockIdx.x * 256 + threadIdx.x;
  if (idx < 131072) { int o = idx & 255, c = idx >> 8; ws[OFF_WKT + idx] = wk[o * 512 + c]; return; }
  idx -= 131072;
  if (idx < 131072) { int o = idx & 255, c = idx >> 8; ws[OFF_WQT + idx] = wq[o * 512 + c]; return; }
  idx -= 131072;
  if (idx < 131072) { int o = idx & 255, c = idx >> 8; ws[OFF_WVT + idx] = wv[o * 512 + c]; return; }
  idx -= 131072;
  if (idx < 131072) { int o = idx & 511, c = idx >> 9; ws[OFF_WRT + idx] = wr[o * 256 + c]; return; }
  idx -= 131072;
  if (idx < 262144) { int o = idx & 511, c = idx >> 9; ws[OFF_A1T + idx] = a1[o * 512 + c]; return; }
  idx -= 262144;
  if (idx < 131072) { int o = idx & 255, c = idx >> 8; ws[OFF_A2T + idx] = a2[o * 512 + c]; return; }
  idx -= 131072;
  if (idx < 65536) { int o = idx & 255, c = idx >> 8; ws[OFF_D1AT + idx] = d1[o * 512 + c]; return; }
  idx -= 65536;
  if (idx < 65536) { int o = idx & 255, c = idx >> 8; ws[OFF_D1BT + idx] = d1[o * 512 + 256 + c]; return; }
  idx -= 65536;
  if (idx < 262144) { int o = idx & 511, c = idx >> 9; ws[OFF_PW1T + idx] = pw1[o * 512 + c]; return; }
  idx -= 262144;
  if (idx < 131072) { int o = idx & 255, c = idx >> 8; ws[OFF_PW2T + idx] = pw2[o * 512 + c]; return; }
}

// ---------------- kernel 1: keys/values GEMM + ctx/Z/colsum partials ----------------
__global__ __launch_bounds__(512) void k1_reduce(
    const float* __restrict__ x, const float* __restrict__ y,
    const float* __restrict__ bk, const float* __restrict__ bv, float* __restrict__ ws) {
  __shared__ __align__(16) float SH[512 * 36];  // XT [512][36]; later VT [256][36] / CT [256][64]
  float* XT = SH;
  float* VT = SH;
  const int t = threadIdx.x;
  const int oc = t & 255, ph = t >> 8;
  const int h = oc >> 5, kk = oc & 31;
  const float* wkT = ws + OFF_WKT;
  const float* wvT = ws + OFF_WVT;
  float* ctxp = ws + OFF_CTX;
  float* Zp = ws + OFF_ZP;
  float* cols = ws + OFF_COLS;

  float ctx_acc[2][32];
#pragma unroll
  for (int b = 0; b < 2; ++b)
    for (int v = 0; v < 32; ++v) ctx_acc[b][v] = 0.f;
  float zacc[2] = {0.f, 0.f};
  float csum[2] = {0.f, 0.f};
  const float bko = bk[oc], bvo = bv[oc];

  for (int s = 0; s < 4; ++s) {
    const int n0 = blockIdx.x * 128 + s * 32;
    for (int b = 0; b < 2; ++b) {
      const float* src = b ? y : x;
      __syncthreads();  // previous VT reads done before overwriting SH
      for (int r = 0; r < 32; ++r) {
        int flat = r * 512 + t;
        int c = flat & 511, p = flat >> 9;
        XT[c * 36 + p] = src[(size_t)(n0 + p) * 512 + c];
      }
      __syncthreads();
      {  // column sums (channel = t)
        float cs = 0.f;
#pragma unroll
        for (int p = 0; p < 32; ++p) cs += XT[t * 36 + p];
        csum[b] += cs;
      }
      float ak[16], av[16];
#pragma unroll
      for (int i = 0; i < 16; ++i) { ak[i] = 0.f; av[i] = 0.f; }
      for (int c = 0; c < 512; ++c) {
        float wkv = wkT[c * 256 + oc];
        float wvv = wvT[c * 256 + oc];
        const float* xr = &XT[c * 36 + ph * 16];
#pragma unroll
        for (int i = 0; i < 16; ++i) {
          float xv = xr[i];
          ak[i] = fmaf(xv, wkv, ak[i]);
          av[i] = fmaf(xv, wvv, av[i]);
        }
      }
#pragma unroll
      for (int i = 0; i < 16; ++i) {
        ak[i] = __expf(ak[i] + bko);  // e = exp(keys)  (bounded, no max needed)
        zacc[b] += ak[i];
        av[i] += bvo;
      }
      __syncthreads();  // all XT reads done
#pragma unroll
      for (int i = 0; i < 16; ++i) VT[oc * 36 + ph * 16 + i] = av[i];
      __syncthreads();
      // ctx partial: e (own regs) x values rows
      for (int v = 0; v < 32; ++v) {
        const float* vr = &VT[(h * 32 + v) * 36 + ph * 16];
        float acc = ctx_acc[b][v];
#pragma unroll
        for (int i = 0; i < 16; ++i) acc = fmaf(ak[i], vr[i], acc);
        ctx_acc[b][v] = acc;
      }
    }
  }
  // combine ph halves in LDS, then one atomicAdd set
  __syncthreads();
  float* CT = SH;  // [256][64]
  if (ph == 1) {
#pragma unroll
    for (int b = 0; b < 2; ++b)
      for (int v = 0; v < 32; ++v) CT[oc * 64 + b * 32 + v] = ctx_acc[b][v];
  }
  __syncthreads();
  if (ph == 0) {
    for (int b = 0; b < 2; ++b)
      for (int v = 0; v < 32; ++v) {
        float val = ctx_acc[b][v] + CT[oc * 64 + b * 32 + v];
        atomicAdd(&ctxp[(((b * 8 + h) * 32 + kk) * 32) + v], val);
      }
  }
  for (int b = 0; b < 2; ++b) atomicAdd(&Zp[b * 256 + oc], zacc[b]);
  for (int b = 0; b < 2; ++b) atomicAdd(&cols[b * 512 + t], csum[b]);
}

// ---------------- kernel 2: finalize (pool chain, ctx/Z, const_d) ----------------
__global__ __launch_bounds__(256) void k2_finalize(
    const float* __restrict__ pbn1, const float* __restrict__ pbn2, float* __restrict__ ws) {
  __shared__ float HI[2 * 512];
  __shared__ float H1[2 * 512];
  __shared__ float H2[2 * 256];
  const int t = threadIdx.x;
  const float* pw1T = ws + OFF_PW1T;
  const float* pw2T = ws + OFF_PW2T;
  const float* d1bT = ws + OFF_D1BT;
  for (int idx = t; idx < 1024; idx += 256) HI[idx] = ws[OFF_COLS + idx] * (1.0f / 32768.0f);
  __syncthreads();
  for (int half = 0; half < 2; ++half) {
    int o = t + half * 256;
    float g = pbn1[o], be = pbn1[512 + o], mn = pbn1[1024 + o], va = pbn1[1536 + o];
    float sc = g * rsqrtf(va + 1e-5f), sh = be - mn * sc;
    for (int b = 0; b < 2; ++b) {
      float acc = 0.f;
      for (int c = 0; c < 512; ++c) acc = fmaf(pw1T[c * 512 + o], HI[b * 512 + c], acc);
      H1[b * 512 + o] = acc * sc + sh;
    }
  }
  __syncthreads();
  {
    int o = t;
    float g = pbn2[o], be = pbn2[256 + o], mn = pbn2[512 + o], va = pbn2[768 + o];
    float sc = g * rsqrtf(va + 1e-5f), sh = be - mn * sc;
    for (int b = 0; b < 2; ++b) {
      float acc = 0.f;
      for (int c = 0; c < 512; ++c) acc = fmaf(pw2T[c * 256 + o], H1[b * 512 + c], acc);
      float v = acc * sc + sh;
      H2[b * 256 + o] = v;
      ws[OFF_HIGH2 + b * 256 + o] = v;
    }
  }
  __syncthreads();
  {
    int o = t;
    for (int b = 0; b < 2; ++b) {
      float acc = 0.f;
      for (int c = 0; c < 256; ++c) acc = fmaf(d1bT[c * 256 + o], H2[b * 256 + c], acc);
      ws[OFF_CONSTD + b * 256 + o] = acc;
    }
  }
  for (int idx = t; idx < 16384; idx += 256) {
    int kch = (idx >> 5) & 255;  // b*256 + h*32+k  -> &255 = h*32+k
    int b = idx >> 13;
    ws[OFF_CTX + idx] = ws[OFF_CTX + idx] / ws[OFF_ZP + b * 256 + kch];
  }
}

// ---------------- kernel 3: main fused per-position pass ----------------
__global__ __launch_bounds__(512) void k3_main(
    const float* __restrict__ x, const float* __restrict__ y,
    const float* __restrict__ ea_bq, const float* __restrict__ ea_br,
    const float* __restrict__ abn1, const float* __restrict__ abn2,
    const float* __restrict__ dbn1, const float* __restrict__ d2w,
    const float* __restrict__ ws, float* __restrict__ out) {
  __shared__ __align__(16) float BUF0[512 * 36];  // XT -> T
  __shared__ __align__(16) float BUF1[256 * 36];  // Q -> att
  __shared__ __align__(16) float BUF2[256 * 36];  // low
  __shared__ float WGT[32];
  __shared__ float DPART[8][16][2];
  const int t = threadIdx.x;
  const int oc = t & 255, ph = t >> 8;
  const int h = oc >> 5;
  const int wave = t >> 6, lane = t & 63;
  const int n0 = blockIdx.x * 32;
  const float* wqT = ws + OFF_WQT;
  const float* wrT = ws + OFF_WRT;
  const float* a1T = ws + OFF_A1T;
  const float* a2T = ws + OFF_A2T;
  const float* d1aT = ws + OFF_D1AT;
  const float* ctx = ws + OFF_CTX;
  const float* high2 = ws + OFF_HIGH2;
  const float* constd = ws + OFF_CONSTD;

  float s1a, f1a, s1b, f1b, s2c, f2c, sdc, fdc;
  { float g = abn1[oc], be = abn1[512 + oc], mn = abn1[1024 + oc], va = abn1[1536 + oc];
    s1a = g * rsqrtf(va + 1e-5f); f1a = be - mn * s1a; }
  { int ch = 256 + oc; float g = abn1[ch], be = abn1[512 + ch], mn = abn1[1024 + ch], va = abn1[1536 + ch];
    s1b = g * rsqrtf(va + 1e-5f); f1b = be - mn * s1b; }
  { float g = abn2[oc], be = abn2[256 + oc], mn = abn2[512 + oc], va = abn2[768 + oc];
    s2c = g * rsqrtf(va + 1e-5f); f2c = be - mn * s2c; }
  { float g = dbn1[oc], be = dbn1[256 + oc], mn = dbn1[512 + oc], va = dbn1[768 + oc];
    sdc = g * rsqrtf(va + 1e-5f); fdc = be - mn * sdc; }
  const float d20 = d2w[oc], d21 = d2w[256 + oc];
  const float bqo = ea_bq[oc];
  const float bra = ea_br[oc], brb = ea_br[256 + oc];

  float outa[16], outb[16];
#pragma unroll
  for (int i = 0; i < 16; ++i) { outa[i] = 0.f; outb[i] = 0.f; }

  for (int b = 0; b < 2; ++b) {
    const float* src = b ? y : x;
    __syncthreads();
    for (int r = 0; r < 32; ++r) {
      int flat = r * 512 + t;
      int c = flat & 511, p = flat >> 9;
      BUF0[c * 36 + p] = src[(size_t)(n0 + p) * 512 + c];
    }
    __syncthreads();
    // residual + reprojection bias
#pragma unroll
    for (int i = 0; i < 16; ++i) {
      outa[i] += BUF0[oc * 36 + ph * 16 + i] + bra;
      outb[i] += BUF0[(256 + oc) * 36 + ph * 16 + i] + brb;
    }
    // fused queries + adapt1 GEMVs
    float aq[16], at0[16], at1[16];
#pragma unroll
    for (int i = 0; i < 16; ++i) { aq[i] = 0.f; at0[i] = 0.f; at1[i] = 0.f; }
    for (int c = 0; c < 512; ++c) {
      const float* xr = &BUF0[c * 36 + ph * 16];
      float wq = wqT[c * 256 + oc];
      float wa = a1T[c * 512 + oc];
      float wb = a1T[c * 512 + 256 + oc];
#pragma unroll
      for (int i = 0; i < 16; ++i) {
        float xv = xr[i];
        aq[i] = fmaf(xv, wq, aq[i]);
        at0[i] = fmaf(xv, wa, at0[i]);
        at1[i] = fmaf(xv, wb, at1[i]);
      }
    }
    // Q softmax over the 32 head-channels (contiguous 32-lane groups)
#pragma unroll
    for (int i = 0; i < 16; ++i) {
      float q = aq[i] + bqo;
      float mx = q;
      for (int m = 16; m >= 1; m >>= 1) mx = fmaxf(mx, __shfl_xor(mx, m, 32));
      float e = __expf(q - mx);
      float sm = e;
      for (int m = 16; m >= 1; m >>= 1) sm += __shfl_xor(sm, m, 32);
      aq[i] = e / sm;
    }
    __syncthreads();  // all BUF0 (X) reads done
#pragma unroll
    for (int i = 0; i < 16; ++i) {
      BUF0[oc * 36 + ph * 16 + i] = at0[i] * s1a + f1a;            // T = bn1(adapt1)
      BUF0[(256 + oc) * 36 + ph * 16 + i] = at1[i] * s1b + f1b;
      BUF1[oc * 36 + ph * 16 + i] = aq[i];                          // Q
    }
    __syncthreads();
    // att = ctx^T Q
    float att[16];
#pragma unroll
    for (int i = 0; i < 16; ++i) att[i] = 0.f;
    {
      const int v = oc & 31;
      for (int k2 = 0; k2 < 32; ++k2) {
        float cv = ctx[(((b * 8 + h) * 32 + k2) * 32) + v];
        const float* qr = &BUF1[(h * 32 + k2) * 36 + ph * 16];
#pragma unroll
        for (int i = 0; i < 16; ++i) att[i] = fmaf(cv, qr[i], att[i]);
      }
    }
    __syncthreads();
#pragma unroll
    for (int i = 0; i < 16; ++i) BUF1[oc * 36 + ph * 16 + i] = att[i];
    __syncthreads();
    // reprojection into output accumulators
    for (int v = 0; v < 256; ++v) {
      const float* ar = &BUF1[v * 36 + ph * 16];
      float wa_ = wrT[v * 512 + oc];
      float wb_ = wrT[v * 512 + 256 + oc];
#pragma unroll
      for (int i = 0; i < 16; ++i) {
        float a = ar[i];
        outa[i] = fmaf(a, wa_, outa[i]);
        outb[i] = fmaf(a, wb_, outb[i]);
      }
    }
    // adapt2 -> low
    float al[16];
#pragma unroll
    for (int i = 0; i < 16; ++i) al[i] = 0.f;
    for (int c = 0; c < 512; ++c) {
      const float* tr = &BUF0[c * 36 + ph * 16];
      float w = a2T[c * 256 + oc];
#pragma unroll
      for (int i = 0; i < 16; ++i) al[i] = fmaf(tr[i], w, al[i]);
    }
#pragma unroll
    for (int i = 0; i < 16; ++i) al[i] = al[i] * s2c + f2c;
    __syncthreads();
#pragma unroll
    for (int i = 0; i < 16; ++i) BUF2[oc * 36 + ph * 16 + i] = al[i];
    __syncthreads();
    // d = bn(delta_w1a @ low + const_d)
    float ad[16];
#pragma unroll
    for (int i = 0; i < 16; ++i) ad[i] = 0.f;
    for (int c = 0; c < 256; ++c) {
      const float* lr = &BUF2[c * 36 + ph * 16];
      float w = d1aT[c * 256 + oc];
#pragma unroll
      for (int i = 0; i < 16; ++i) ad[i] = fmaf(lr[i], w, ad[i]);
    }
    const float cdo = constd[b * 256 + oc];
#pragma unroll
    for (int i = 0; i < 16; ++i) ad[i] = (ad[i] + cdo) * sdc + fdc;
    // delta = delta_w2 @ d   (reduce over 256 channels = 4 waves x 64 lanes)
#pragma unroll
    for (int i = 0; i < 16; ++i) {
      float p0 = d20 * ad[i];
      float p1 = d21 * ad[i];
      for (int m = 32; m >= 1; m >>= 1) {
        p0 += __shfl_xor(p0, m, 64);
        p1 += __shfl_xor(p1, m, 64);
      }
      if (lane == 0) { DPART[wave][i][0] = p0; DPART[wave][i][1] = p1; }
    }
    __syncthreads();
    if (t < 32) {
      int p = t;
      int w0 = (p >> 4) * 4;
      int ii = p & 15;
      float dx = 0.f, dy = 0.f;
      for (int w2 = 0; w2 < 4; ++w2) { dx += DPART[w0 + w2][ii][0]; dy += DPART[w0 + w2][ii][1]; }
      float gx = -1.f + 2.f * (float)(n0 + p) / (float)(NPOS - 1) + dx;
      float gy = -1.f + dy;
      float ix = gx * 0.5f, iy = gy * 0.5f;
      float wx = fminf(fmaxf(1.f - fabsf(ix), 0.f), 1.f);
      float wy = fminf(fmaxf(1.f - fabsf(iy), 0.f), 1.f);
      WGT[p] = wx * wy;
    }
    __syncthreads();
    // CAM contribution
    const float h2o = high2[b * 256 + oc];
#pragma unroll
    for (int i = 0; i < 16; ++i) {
      outa[i] += h2o * WGT[ph * 16 + i];
      outb[i] += al[i];
    }
  }
#pragma unroll
  for (int i = 0; i < 16; ++i) {
    int row = n0 + ph * 16 + i;
    out[(size_t)row * 512 + oc] = 0.25f * outa[i];
    out[(size_t)row * 512 + 256 + oc] = 0.25f * outb[i];
  }
}

extern "C" void kernel_launch(void* const* d_in, const int* in_sizes, int n_in,
                              void* d_out, int out_size, void* d_ws, size_t ws_size,
                              hipStream_t stream) {
  const float* x = (const float*)d_in[0];
  const float* y = (const float*)d_in[1];
  const float* ea_wk = (const float*)d_in[2];
  const float* ea_bk = (const float*)d_in[3];
  const float* ea_wq = (const float*)d_in[4];
  const float* ea_bq = (const float*)d_in[5];
  const float* ea_wv = (const float*)d_in[6];
  const float* ea_bv = (const float*)d_in[7];
  const float* ea_wr = (const float*)d_in[8];
  const float* ea_br = (const float*)d_in[9];
  const float* pool_w1 = (const float*)d_in[10];
  const float* pool_bn1 = (const float*)d_in[11];
  const float* pool_w2 = (const float*)d_in[12];
  const float* pool_bn2 = (const float*)d_in[13];
  const float* adapt_w1 = (const float*)d_in[14];
  const float* adapt_bn1 = (const float*)d_in[15];
  const float* adapt_w2 = (const float*)d_in[16];
  const float* adapt_bn2 = (const float*)d_in[17];
  const float* delta_w1 = (const float*)d_in[18];
  const float* delta_bn1 = (const float*)d_in[19];
  const float* delta_w2 = (const float*)d_in[20];
  float* ws = (float*)d_ws;
  float* out = (float*)d_out;

  hipMemsetAsync(d_ws, 0, 17920 * sizeof(float), stream);  // ctx, Z, colsum partials
  k0_transpose<<<5632, 256, 0, stream>>>(ea_wk, ea_wq, ea_wv, ea_wr, adapt_w1, adapt_w2,
                                         delta_w1, pool_w1, pool_w2, ws);
  k1_reduce<<<256, 512, 0, stream>>>(x, y, ea_bk, ea_bv, ws);
  k2_finalize<<<1, 256, 0, stream>>>(pool_bn1, pool_bn2, ws);
  k3_main<<<1024, 512, 0, stream>>>(x, y, ea_bq, ea_br, adapt_bn1, adapt_bn2, delta_bn1,
                                    delta_w2, ws, out);
}

// Round 3
// 1637.630 us; speedup vs baseline: 1.9950x; 1.9950x over previous
//
#include <hip/hip_runtime.h>
#include <math.h>

// ---------------- ws byte offsets ----------------
#define B_CTXC   0          // 8 copies of ctx partials [8][16384] f32 = 524288
#define B_ZP     524288     // [2][256] f32
#define B_COLS   526336     // [2][512] f32
#define B_HIGH2  530432     // [2][256] f32
#define B_CONSTD 532480     // [2][2] f32 (+pad)
#define B_BIASO  532544     // [512] f32
#define B_CPP    534592     // [256] f32 (c'')
#define B_CTXT   535616     // [2][8][32][32] bf16 (A-layout: [v][k])
#define B_WDD    568384     // [2][256] f32
#define B_WDX    570432     // [2][512] f32
#define B_WL     574528     // [256][512] f32 (W_L'')
#define B_WBIG   1098816    // [528][512] bf16
#define B_WKV    1639488    // [512][512] bf16
#define B_WR     2163776    // [512][256] bf16
#define B_PW1T   2425920    // [512][512] f32 transposed
#define B_PW2T   3474496    // [512][256] f32 transposed
#define B_D1BT   3998784    // [256][256] f32 transposed

typedef __attribute__((ext_vector_type(8))) short bf16x8;
typedef __attribute__((ext_vector_type(4))) float f32x4;

#define MFMA(a, b, c) __builtin_amdgcn_mfma_f32_16x16x32_bf16(a, b, c, 0, 0, 0)

__device__ inline unsigned f2bfu(float f) {
  unsigned u = __float_as_uint(f);
  return (u + 0x7FFFu + ((u >> 16) & 1u)) >> 16;
}
__device__ inline unsigned pack2(float a, float b) { return f2bfu(a) | (f2bfu(b) << 16); }

// ---------------- kW1: W_L'' (fp32) + c'' ----------------
__global__ __launch_bounds__(512) void kW1(
    const float* __restrict__ a1, const float* __restrict__ abn1,
    const float* __restrict__ a2, const float* __restrict__ abn2,
    char* __restrict__ wsb) {
  __shared__ float S1[512], F1[512], redu[512];
  const int t = threadIdx.x, o = blockIdx.x;
  float* wsf = (float*)wsb;
  {
    float gg = abn1[t], be = abn1[512 + t], mn = abn1[1024 + t], va = abn1[1536 + t];
    float s = gg * rsqrtf(va + 1e-5f);
    S1[t] = s; F1[t] = be - mn * s;
  }
  float g2 = abn2[o], be2 = abn2[256 + o], mn2 = abn2[512 + o], va2 = abn2[768 + o];
  float s2 = g2 * rsqrtf(va2 + 1e-5f);
  float f2v = be2 - mn2 * s2;
  __syncthreads();
  float acc = 0.f;
  const float* a2r = a2 + o * 512;
  for (int m = 0; m < 512; ++m) acc = fmaf(a2r[m] * S1[m], a1[m * 512 + t], acc);
  wsf[(B_WL / 4) + o * 512 + t] = s2 * acc;
  redu[t] = a2r[t] * F1[t];
  __syncthreads();
  for (int sft = 256; sft >= 1; sft >>= 1) {
    if (t < sft) redu[t] += redu[t + sft];
    __syncthreads();
  }
  if (t == 0) wsf[(B_CPP / 4) + o] = s2 * redu[0] + f2v;
}

// ---------------- kW2: W_dd, W_dx ----------------
__global__ __launch_bounds__(512) void kW2(
    const float* __restrict__ d1, const float* __restrict__ dbn1,
    const float* __restrict__ d2, char* __restrict__ wsb) {
  __shared__ float SD[256], WDDl[512];
  const int t = threadIdx.x;
  float* wsf = (float*)wsb;
  if (t < 256) {
    float gg = dbn1[t], va = dbn1[768 + t];
    SD[t] = gg * rsqrtf(va + 1e-5f);
  }
  __syncthreads();
  {
    int j = t >> 8, v = t & 255;
    float acc = 0.f;
    for (int o = 0; o < 256; ++o) acc = fmaf(d2[j * 256 + o] * SD[o], d1[o * 512 + v], acc);
    WDDl[t] = acc;
    wsf[(B_WDD / 4) + t] = acc;
  }
  __syncthreads();
  {
    int c = t;
    float acc0 = 0.f, acc1 = 0.f;
    for (int v = 0; v < 256; ++v) {
      float wl = wsf[(B_WL / 4) + v * 512 + c];
      acc0 = fmaf(WDDl[v], wl, acc0);
      acc1 = fmaf(WDDl[256 + v], wl, acc1);
    }
    wsf[(B_WDX / 4) + c] = acc0;
    wsf[(B_WDX / 4) + 512 + c] = acc1;
  }
}

// ---------------- kPack: bf16 weight packs + fp32 transposes ----------------
__global__ __launch_bounds__(256) void kPack(
    const float* __restrict__ wq, const float* __restrict__ wk, const float* __restrict__ wv,
    const float* __restrict__ wr, const float* __restrict__ pw1, const float* __restrict__ pw2,
    const float* __restrict__ d1, char* __restrict__ wsb) {
  int i = blockIdx.x * 256 + threadIdx.x;
  float* wsf = (float*)wsb;
  unsigned short* u16 = (unsigned short*)wsb;
  if (i < 270336) {  // Wbig [528][512]
    int row = i >> 9, c = i & 511;
    float v;
    if (row < 256) v = wq[row * 512 + c];
    else if (row < 512) v = wsf[(B_WL / 4) + (row - 256) * 512 + c];
    else if (row < 514) v = wsf[(B_WDX / 4) + (row - 512) * 512 + c];
    else v = 0.f;
    u16[(B_WBIG / 2) + i] = (unsigned short)f2bfu(v);
    return;
  }
  i -= 270336;
  if (i < 262144) {  // Wkv [512][512]
    int row = i >> 9, c = i & 511;
    float v = row < 256 ? wk[row * 512 + c] : wv[(row - 256) * 512 + c];
    u16[(B_WKV / 2) + i] = (unsigned short)f2bfu(v);
    return;
  }
  i -= 262144;
  if (i < 131072) { u16[(B_WR / 2) + i] = (unsigned short)f2bfu(wr[i]); return; }
  i -= 131072;
  if (i < 262144) { int o = i >> 9, c = i & 511; wsf[(B_PW1T / 4) + c * 512 + o] = pw1[i]; return; }
  i -= 262144;
  if (i < 131072) { int o = i >> 9, c = i & 511; wsf[(B_PW2T / 4) + c * 256 + o] = pw2[i]; return; }
  i -= 131072;
  if (i < 65536) { int o = i >> 8, v = i & 255; wsf[(B_D1BT / 4) + v * 256 + o] = d1[o * 512 + 256 + v]; }
}

// ---------------- k1: keys/values MFMA + ctx/Z/colsum partials ----------------
__global__ __launch_bounds__(512, 2) void k1_reduce(
    const float* __restrict__ x, const float* __restrict__ y,
    const float* __restrict__ bk, const float* __restrict__ bv, char* __restrict__ wsb) {
  __shared__ __align__(16) unsigned char Xl[65536];
  __shared__ __align__(16) unsigned char el[32768];
  __shared__ __align__(16) unsigned char vl[32768];
  __shared__ float Red[1536];  // [0..511]=Z, [512..1535]=colsum
  const int t = threadIdx.x;
  const int wv_ = t >> 6, lo16 = t & 15, g = (t >> 4) & 3;
  const int pt = wv_ & 3, hf = wv_ >> 2;
  const int p0 = pt * 16;
  const char* Wkv = wsb + B_WKV;
  float* wsf = (float*)wsb;

  for (int i = t; i < 1536; i += 512) Red[i] = 0.f;
  float csum[2][8];
#pragma unroll
  for (int b2 = 0; b2 < 2; ++b2)
#pragma unroll
    for (int i = 0; i < 8; ++i) csum[b2][i] = 0.f;
  f32x4 ctxacc[2][2][2];
#pragma unroll
  for (int b2 = 0; b2 < 2; ++b2)
    for (int m = 0; m < 2; ++m)
      for (int n = 0; n < 2; ++n) ctxacc[b2][m][n] = (f32x4){0.f, 0.f, 0.f, 0.f};
  const int h = wv_;  // head for ctx phase (0..7)

  for (int s = 0; s < 2; ++s) {
    const int n0 = (blockIdx.x * 2 + s) * 64;
    for (int b = 0; b < 2; ++b) {
      const float* src = b ? y : x;
      __syncthreads();  // (A)
      for (int r = 0; r < 8; ++r) {
        int chunk = r * 512 + t;
        int prow = chunk >> 6, j = chunk & 63;
        const float* gp = src + (size_t)(n0 + prow) * 512 + j * 8;
        float4 u0 = *(const float4*)gp;
        float4 u1 = *(const float4*)(gp + 4);
        csum[b][0] += u0.x; csum[b][1] += u0.y; csum[b][2] += u0.z; csum[b][3] += u0.w;
        csum[b][4] += u1.x; csum[b][5] += u1.y; csum[b][6] += u1.z; csum[b][7] += u1.w;
        uint4 pk;
        pk.x = pack2(u0.x, u0.y); pk.y = pack2(u0.z, u0.w);
        pk.z = pack2(u1.x, u1.y); pk.w = pack2(u1.z, u1.w);
        int byte = (prow * 1024 + j * 16) ^ ((prow & 7) << 4);
        *(uint4*)(Xl + byte) = pk;
      }
      __syncthreads();  // (B)
      bf16x8 bx[16];
      {
        int rowX = p0 + lo16;
        int base = rowX * 1024 + g * 16;
        int swz = (rowX & 7) << 4;
#pragma unroll
        for (int ks = 0; ks < 16; ++ks) bx[ks] = *(const bf16x8*)(Xl + ((base + ks * 64) ^ swz));
      }
      for (int tp = 0; tp < 8; ++tp) {
        int t0 = hf * 16 + tp * 2, t1 = t0 + 1;
        f32x4 a0 = {0.f, 0.f, 0.f, 0.f}, a1 = {0.f, 0.f, 0.f, 0.f};
        const char* ap0 = Wkv + (t0 * 16 + lo16) * 1024 + g * 16;
        const char* ap1 = Wkv + (t1 * 16 + lo16) * 1024 + g * 16;
#pragma unroll
        for (int ks = 0; ks < 16; ++ks) {
          bf16x8 af0 = *(const bf16x8*)(ap0 + ks * 64);
          bf16x8 af1 = *(const bf16x8*)(ap1 + ks * 64);
          a0 = MFMA(af0, bx[ks], a0);
          a1 = MFMA(af1, bx[ks], a1);
        }
        int pp = p0 + lo16;
        if (hf == 0) {  // keys -> e, Z, el
          float e0[4], e1[4];
#pragma unroll
          for (int r = 0; r < 4; ++r) {
            e0[r] = __expf(a0[r] + bk[t0 * 16 + g * 4 + r]);
            e1[r] = __expf(a1[r] + bk[t1 * 16 + g * 4 + r]);
          }
#pragma unroll
          for (int r = 0; r < 4; ++r) {
            float v0 = e0[r], v1 = e1[r];
            for (int m = 8; m >= 1; m >>= 1) {
              v0 += __shfl_xor(v0, m, 16);
              v1 += __shfl_xor(v1, m, 16);
            }
            if (lo16 == 0) {
              atomicAdd(&Red[b * 256 + t0 * 16 + g * 4 + r], v0);
              atomicAdd(&Red[b * 256 + t1 * 16 + g * 4 + r], v1);
            }
          }
#pragma unroll
          for (int r = 0; r < 4; ++r) {
            int row0 = t0 * 16 + g * 4 + r;
            int row1 = t1 * 16 + g * 4 + r;
            *(unsigned short*)(el + ((row0 * 128 + pp * 2) ^ ((row0 & 7) << 4))) = (unsigned short)f2bfu(e0[r]);
            *(unsigned short*)(el + ((row1 * 128 + pp * 2) ^ ((row1 & 7) << 4))) = (unsigned short)f2bfu(e1[r]);
          }
        } else {  // values -> vl
#pragma unroll
          for (int r = 0; r < 4; ++r) {
            int row0 = (t0 - 16) * 16 + g * 4 + r;
            int row1 = (t1 - 16) * 16 + g * 4 + r;
            *(unsigned short*)(vl + ((row0 * 128 + pp * 2) ^ ((row0 & 7) << 4))) = (unsigned short)f2bfu(a0[r] + bv[row0]);
            *(unsigned short*)(vl + ((row1 * 128 + pp * 2) ^ ((row1 & 7) << 4))) = (unsigned short)f2bfu(a1[r] + bv[row1]);
          }
        }
      }
      __syncthreads();  // (C) el, vl ready
#pragma unroll
      for (int m = 0; m < 2; ++m)
#pragma unroll
        for (int n = 0; n < 2; ++n) {
          int rowe = h * 32 + m * 16 + lo16;
          int rowv = h * 32 + n * 16 + lo16;
#pragma unroll
          for (int ks = 0; ks < 2; ++ks) {
            bf16x8 ea = *(const bf16x8*)(el + ((rowe * 128 + ks * 64 + g * 16) ^ ((rowe & 7) << 4)));
            bf16x8 vb = *(const bf16x8*)(vl + ((rowv * 128 + ks * 64 + g * 16) ^ ((rowv & 7) << 4)));
            ctxacc[b][m][n] = MFMA(ea, vb, ctxacc[b][m][n]);
          }
        }
    }
  }
  // finalize: ctx partial atomics into 1-of-8 copies
  // ctx layout is [b][h][k_local][v]; D gives k_local = m*16 + g*4 + r (head-local!)
  {
    float* ctxg = wsf + (B_CTXC / 4) + (blockIdx.x & 7) * 16384;
#pragma unroll
    for (int b = 0; b < 2; ++b)
      for (int m = 0; m < 2; ++m)
        for (int n = 0; n < 2; ++n)
#pragma unroll
          for (int r = 0; r < 4; ++r) {
            int klocal = m * 16 + g * 4 + r;
            int vcol = n * 16 + lo16;
            atomicAdd(&ctxg[((b * 8 + h) * 32 + klocal) * 32 + vcol], ctxacc[b][m][n][r]);
          }
  }
#pragma unroll
  for (int b = 0; b < 2; ++b)
#pragma unroll
    for (int i = 0; i < 8; ++i) atomicAdd(&Red[512 + b * 512 + (t & 63) * 8 + i], csum[b][i]);
  __syncthreads();
  atomicAdd(&wsf[(B_ZP / 4) + t], Red[t]);
  atomicAdd(&wsf[(B_COLS / 4) + t], Red[512 + t]);
  atomicAdd(&wsf[(B_COLS / 4) + 512 + t], Red[1024 + t]);
}

// ---------------- k2: ctx normalize, pool chain, constD, biasOut ----------------
__global__ __launch_bounds__(512) void k2_finalize(
    const float* __restrict__ pbn1, const float* __restrict__ pbn2,
    const float* __restrict__ dbn1, const float* __restrict__ d2,
    const float* __restrict__ ea_br, char* __restrict__ wsb) {
  __shared__ float HI[1024], H1[1024], H2l[512], VB[512], slot[4];
  const int t = threadIdx.x;
  float* wsf = (float*)wsb;
  unsigned short* u16 = (unsigned short*)wsb;
  for (int idx = t; idx < 16384; idx += 512) {
    float s = 0.f;
#pragma unroll
    for (int c = 0; c < 8; ++c) s += wsf[(B_CTXC / 4) + c * 16384 + idx];
    int v = idx & 31, row = idx >> 5;
    int b = row >> 8, kr = row & 255;
    int hh = kr >> 5, kh = kr & 31;
    float val = s / wsf[(B_ZP / 4) + b * 256 + kr];
    u16[(B_CTXT / 2) + ((b * 8 + hh) * 32 + v) * 32 + kh] = (unsigned short)f2bfu(val);
  }
  if (t < 4) slot[t] = 0.f;
  for (int idx = t; idx < 1024; idx += 512) HI[idx] = wsf[(B_COLS / 4) + idx] * (1.f / 32768.f);
  __syncthreads();
  {
    int o = t;
    float gg = pbn1[o], be = pbn1[512 + o], mn = pbn1[1024 + o], va = pbn1[1536 + o];
    float sc = gg * rsqrtf(va + 1e-5f), sh = be - mn * sc;
    for (int b = 0; b < 2; ++b) {
      float acc = 0.f;
      for (int c = 0; c < 512; ++c) acc = fmaf(wsf[(B_PW1T / 4) + c * 512 + o], HI[b * 512 + c], acc);
      H1[b * 512 + o] = acc * sc + sh;
    }
  }
  __syncthreads();
  if (t < 256) {
    int o = t;
    float gg = pbn2[o], be = pbn2[256 + o], mn = pbn2[512 + o], va = pbn2[768 + o];
    float sc = gg * rsqrtf(va + 1e-5f), sh = be - mn * sc;
    for (int b = 0; b < 2; ++b) {
      float acc = 0.f;
      for (int c = 0; c < 512; ++c) acc = fmaf(wsf[(B_PW2T / 4) + c * 256 + o], H1[b * 512 + c], acc);
      float vv = acc * sc + sh;
      H2l[b * 256 + o] = vv;
      wsf[(B_HIGH2 / 4) + b * 256 + o] = vv;
    }
  }
  __syncthreads();
  if (t < 256) {
    int o = t;
    float gg = dbn1[o], be = dbn1[256 + o], mn = dbn1[512 + o], va = dbn1[768 + o];
    float sd = gg * rsqrtf(va + 1e-5f), fd = be - mn * sd;
    for (int b = 0; b < 2; ++b) {
      float acc = 0.f;
      for (int v = 0; v < 256; ++v) acc = fmaf(wsf[(B_D1BT / 4) + v * 256 + o], H2l[b * 256 + v], acc);
      VB[b * 256 + o] = sd * acc + fd;
    }
  }
  __syncthreads();
  if (t < 256) {
    int o = t;
    for (int b = 0; b < 2; ++b)
      for (int j = 0; j < 2; ++j) atomicAdd(&slot[b * 2 + j], d2[j * 256 + o] * VB[b * 256 + o]);
    float cp = wsf[(B_CPP / 4) + o];
    for (int j = 0; j < 2; ++j) {
      float w = wsf[(B_WDD / 4) + j * 256 + o] * cp;
      atomicAdd(&slot[0 + j], w);
      atomicAdd(&slot[2 + j], w);
    }
  }
  __syncthreads();
  if (t < 4) wsf[(B_CONSTD / 4) + t] = slot[t];
  {
    int o = t;
    float bb = 0.5f * ea_br[o];
    if (o >= 256) bb += 0.5f * wsf[(B_CPP / 4) + o - 256];
    wsf[(B_BIASO / 4) + o] = bb;
  }
}

// ---------------- k3: main fused per-position MFMA pass ----------------
__global__ __launch_bounds__(512, 2) void k3_main(
    const float* __restrict__ x, const float* __restrict__ y,
    const float* __restrict__ bq, const char* __restrict__ wsb,
    float* __restrict__ out) {
  __shared__ __align__(16) unsigned char Xl[65536];
  __shared__ __align__(16) unsigned char Ql[32768];
  __shared__ float wgtl[64];
  const int t = threadIdx.x;
  const int wv_ = t >> 6, lo16 = t & 15, g = (t >> 4) & 3;
  const int pt = wv_ & 3, hf = wv_ >> 2;
  const int p0 = pt * 16;
  const int n0 = blockIdx.x * 64;
  const char* Wbig = wsb + B_WBIG;
  const char* WR = wsb + B_WR;
  const char* CTXT = wsb + B_CTXT;
  const float* wsf = (const float*)wsb;
  unsigned char* Qslab = Ql + pt * 8192;

  f32x4 macc[16];  // hf==0: attS accumulators; hf==1: 0.25*(L0+L1)
#pragma unroll
  for (int i = 0; i < 16; ++i) macc[i] = (f32x4){0.f, 0.f, 0.f, 0.f};
  float wg0 = 0.f, wg1 = 0.f;

  for (int b = 0; b < 2; ++b) {
    const float* src = b ? y : x;
    __syncthreads();  // (A)
    for (int r = 0; r < 8; ++r) {
      int chunk = r * 512 + t;
      int prow = chunk >> 6, j = chunk & 63;
      const float* gp = src + (size_t)(n0 + prow) * 512 + j * 8;
      float4 u0 = *(const float4*)gp;
      float4 u1 = *(const float4*)(gp + 4);
      uint4 pk;
      pk.x = pack2(u0.x, u0.y); pk.y = pack2(u0.z, u0.w);
      pk.z = pack2(u1.x, u1.y); pk.w = pack2(u1.z, u1.w);
      int byte = (prow * 1024 + j * 16) ^ ((prow & 7) << 4);
      *(uint4*)(Xl + byte) = pk;
    }
    __syncthreads();  // (B)
    bf16x8 bx[16];
    {
      int rowX = p0 + lo16;
      int base = rowX * 1024 + g * 16;
      int swz = (rowX & 7) << 4;
#pragma unroll
      for (int ks = 0; ks < 16; ++ks) bx[ks] = *(const bf16x8*)(Xl + ((base + ks * 64) ^ swz));
    }
    for (int tp = 0; tp < 8; ++tp) {
      int t0 = hf * 16 + tp * 2, t1 = t0 + 1;
      f32x4 a0 = {0.f, 0.f, 0.f, 0.f}, a1 = {0.f, 0.f, 0.f, 0.f};
      const char* ap0 = Wbig + (t0 * 16 + lo16) * 1024 + g * 16;
      const char* ap1 = Wbig + (t1 * 16 + lo16) * 1024 + g * 16;
#pragma unroll
      for (int ks = 0; ks < 16; ++ks) {
        bf16x8 af0 = *(const bf16x8*)(ap0 + ks * 64);
        bf16x8 af1 = *(const bf16x8*)(ap1 + ks * 64);
        a0 = MFMA(af0, bx[ks], a0);
        a1 = MFMA(af1, bx[ks], a1);
      }
      if (hf == 0) {  // Q pair = head tp: bias + softmax over 32 head-channels
        int hh = tp;
        float q[8], e[8];
        float mx = -1e30f;
#pragma unroll
        for (int r = 0; r < 4; ++r) {
          q[r] = a0[r] + bq[hh * 32 + g * 4 + r];
          q[4 + r] = a1[r] + bq[hh * 32 + 16 + g * 4 + r];
          mx = fmaxf(mx, fmaxf(q[r], q[4 + r]));
        }
        mx = fmaxf(mx, __shfl_xor(mx, 16, 64));
        mx = fmaxf(mx, __shfl_xor(mx, 32, 64));
        float sm = 0.f;
#pragma unroll
        for (int r = 0; r < 8; ++r) { e[r] = __expf(q[r] - mx); sm += e[r]; }
        sm += __shfl_xor(sm, 16, 64);
        sm += __shfl_xor(sm, 32, 64);
        float inv = 1.f / sm;
        uint2 w0, w1;
        w0.x = pack2(e[0] * inv, e[1] * inv); w0.y = pack2(e[2] * inv, e[3] * inv);
        w1.x = pack2(e[4] * inv, e[5] * inv); w1.y = pack2(e[6] * inv, e[7] * inv);
        int base_q = lo16 * 512 + hh * 64 + g * 8;
        int swzq = (lo16 & 7) << 4;
        *(uint2*)(Qslab + (base_q ^ swzq)) = w0;
        *(uint2*)(Qslab + ((base_q + 32) ^ swzq)) = w1;
      } else {  // L tiles
        macc[tp * 2] += 0.25f * a0;
        macc[tp * 2 + 1] += 0.25f * a1;
      }
    }
    if (hf == 1) {  // delta tile (rows 512..527)
      f32x4 ad = {0.f, 0.f, 0.f, 0.f};
      const char* ap = Wbig + (512 + lo16) * 1024 + g * 16;
#pragma unroll
      for (int ks = 0; ks < 16; ++ks) {
        bf16x8 af = *(const bf16x8*)(ap + ks * 64);
        ad = MFMA(af, bx[ks], ad);
      }
      if (g == 0) {
        float d0 = ad[0] + wsf[(B_CONSTD / 4) + b * 2 + 0];
        float d1 = ad[1] + wsf[(B_CONSTD / 4) + b * 2 + 1];
        int pos = n0 + p0 + lo16;
        float gx = -1.f + 2.f * (float)pos / 32767.f + d0;
        float gy = -1.f + d1;
        float ix = gx * 0.5f, iy = gy * 0.5f;
        float wx = fminf(fmaxf(1.f - fabsf(ix), 0.f), 1.f);
        float wy = fminf(fmaxf(1.f - fabsf(iy), 0.f), 1.f);
        wgtl[p0 + lo16] = wx * wy;
      }
    } else {  // att: per-head mfma(ctxT, Q)
      int swzq = (lo16 & 7) << 4;
#pragma unroll
      for (int hh = 0; hh < 8; ++hh) {
        bf16x8 qf = *(const bf16x8*)(Qslab + ((lo16 * 512 + hh * 64 + g * 16) ^ swzq));
        const char* cp = CTXT + (b * 8 + hh) * 2048;
        bf16x8 c0 = *(const bf16x8*)(cp + lo16 * 64 + g * 16);
        bf16x8 c1 = *(const bf16x8*)(cp + (16 + lo16) * 64 + g * 16);
        macc[hh * 2] = MFMA(c0, qf, macc[hh * 2]);
        macc[hh * 2 + 1] = MFMA(c1, qf, macc[hh * 2 + 1]);
      }
    }
    __syncthreads();  // (C) wgtl ready
    if (hf == 0) {
      float w = wgtl[p0 + lo16];
      if (b == 0) wg0 = w; else wg1 = w;
    }
  }
  // attS (hf==0) -> LDS (reuse Qslab)
  if (hf == 0) {
    int swzq = (lo16 & 7) << 4;
#pragma unroll
    for (int hh = 0; hh < 8; ++hh)
#pragma unroll
      for (int m = 0; m < 2; ++m) {
        f32x4 v = macc[hh * 2 + m];
        uint2 w;
        w.x = pack2(v[0], v[1]); w.y = pack2(v[2], v[3]);
        int byte = (lo16 * 512 + hh * 64 + m * 32 + g * 8) ^ swzq;
        *(uint2*)(Qslab + byte) = w;
      }
  }
  __syncthreads();  // (D)
  bf16x8 br8[8];
  {
    int base = lo16 * 512 + g * 16;
    int swzq = (lo16 & 7) << 4;
#pragma unroll
    for (int ks = 0; ks < 8; ++ks) br8[ks] = *(const bf16x8*)(Qslab + ((base + ks * 64) ^ swzq));
  }
  const float* bo = wsf + (B_BIASO / 4);
  const size_t rowaddr = (size_t)(n0 + p0 + lo16) * 512;
  for (int tp = 0; tp < 8; ++tp) {
    int lt0 = tp * 2, lt1 = lt0 + 1;
    int ch0 = hf * 256 + lt0 * 16, ch1 = ch0 + 16;
    f32x4 r0 = {0.f, 0.f, 0.f, 0.f}, r1 = {0.f, 0.f, 0.f, 0.f};
    const char* ap0 = WR + (ch0 + lo16) * 512 + g * 16;
    const char* ap1 = WR + (ch1 + lo16) * 512 + g * 16;
#pragma unroll
    for (int ks = 0; ks < 8; ++ks) {
      bf16x8 a0 = *(const bf16x8*)(ap0 + ks * 64);
      bf16x8 a1 = *(const bf16x8*)(ap1 + ks * 64);
      r0 = MFMA(a0, br8[ks], r0);
      r1 = MFMA(a1, br8[ks], r1);
    }
#pragma unroll
    for (int half = 0; half < 2; ++half) {
      int lt = half ? lt1 : lt0;
      int cb = (half ? ch1 : ch0) + g * 4;
      f32x4 rr = half ? r1 : r0;
      f32x4 xr = *(const f32x4*)(x + rowaddr + cb);
      f32x4 yr = *(const f32x4*)(y + rowaddr + cb);
      f32x4 bb = *(const f32x4*)(bo + cb);
      f32x4 extra;
      if (hf == 0) {
        f32x4 h20 = *(const f32x4*)(wsf + (B_HIGH2 / 4) + cb);
        f32x4 h21 = *(const f32x4*)(wsf + (B_HIGH2 / 4) + 256 + cb);
        extra = (0.25f * wg0) * h20 + (0.25f * wg1) * h21;
      } else {
        extra = macc[lt];
      }
      f32x4 vout = extra + 0.25f * rr + 0.25f * (xr + yr) + bb;
      *(f32x4*)(out + rowaddr + cb) = vout;
    }
  }
}

extern "C" void kernel_launch(void* const* d_in, const int* in_sizes, int n_in,
                              void* d_out, int out_size, void* d_ws, size_t ws_size,
                              hipStream_t stream) {
  const float* x = (const float*)d_in[0];
  const float* y = (const float*)d_in[1];
  const float* ea_wk = (const float*)d_in[2];
  const float* ea_bk = (const float*)d_in[3];
  const float* ea_wq = (const float*)d_in[4];
  const float* ea_bq = (const float*)d_in[5];
  const float* ea_wv = (const float*)d_in[6];
  const float* ea_bv = (const float*)d_in[7];
  const float* ea_wr = (const float*)d_in[8];
  const float* ea_br = (const float*)d_in[9];
  const float* pool_w1 = (const float*)d_in[10];
  const float* pool_bn1 = (const float*)d_in[11];
  const float* pool_w2 = (const float*)d_in[12];
  const float* pool_bn2 = (const float*)d_in[13];
  const float* adapt_w1 = (const float*)d_in[14];
  const float* adapt_bn1 = (const float*)d_in[15];
  const float* adapt_w2 = (const float*)d_in[16];
  const float* adapt_bn2 = (const float*)d_in[17];
  const float* delta_w1 = (const float*)d_in[18];
  const float* delta_bn1 = (const float*)d_in[19];
  const float* delta_w2 = (const float*)d_in[20];
  char* ws = (char*)d_ws;
  float* out = (float*)d_out;

  hipMemsetAsync(ws, 0, 530432, stream);  // ctx copies + Z + colsum
  kW1<<<256, 512, 0, stream>>>(adapt_w1, adapt_bn1, adapt_w2, adapt_bn2, ws);
  kW2<<<1, 512, 0, stream>>>(delta_w1, delta_bn1, delta_w2, ws);
  kPack<<<4384, 256, 0, stream>>>(ea_wq, ea_wk, ea_wv, ea_wr, pool_w1, pool_w2, delta_w1, ws);
  k1_reduce<<<256, 512, 0, stream>>>(x, y, ea_bk, ea_bv, ws);
  k2_finalize<<<1, 512, 0, stream>>>(pool_bn1, pool_bn2, delta_bn1, delta_w2, ea_br, ws);
  k3_main<<<512, 512, 0, stream>>>(x, y, ea_bq, ws, out);
}

// Round 4
// 1514.663 us; speedup vs baseline: 2.1569x; 1.0812x over previous
//
#include <hip/hip_runtime.h>
#include <math.h>

// ---------------- ws byte offsets ----------------
#define B_CTXC   0          // 8 copies of ctx partials [8][16384] f32 = 524288
#define B_ZP     524288     // [2][256] f32
#define B_COLS   526336     // [2][512] f32
#define B_HIGH2  530432     // [2][256] f32
#define B_CONSTD 532480     // [2][2] f32 (+pad)
#define B_BIASO  532544     // [512] f32
#define B_CPP    534592     // [256] f32 (c'')
#define B_CTXT   535616     // [2][8] x 2 tiles x 1KB bf16, fragment-linear
#define B_WDD    568384     // [2][256] f32
#define B_WDX    570432     // [2][512] f32
#define B_WL     574528     // [256][512] f32 (W_L'')
#define B_WBIG   1098816    // 33 tiles x 16KB bf16, fragment-linear
#define B_WKV    1639488    // 32 tiles x 16KB bf16, fragment-linear
#define B_WR     2163776    // 32 tiles x 8KB bf16, fragment-linear
#define B_PW1T   2425920    // [512][512] f32 transposed
#define B_PW2T   3474496    // [512][256] f32 transposed
#define B_D1BT   3998784    // [256][256] f32 transposed

typedef __attribute__((ext_vector_type(8))) short bf16x8;
typedef __attribute__((ext_vector_type(4))) float f32x4;

#define MFMA(a, b, c) __builtin_amdgcn_mfma_f32_16x16x32_bf16(a, b, c, 0, 0, 0)

__device__ inline unsigned f2bfu(float f) {
  unsigned u = __float_as_uint(f);
  return (u + 0x7FFFu + ((u >> 16) & 1u)) >> 16;
}
__device__ inline unsigned pack2(float a, float b) { return f2bfu(a) | (f2bfu(b) << 16); }

// ---------------- kW1: W_L'' (fp32) + c'' ----------------
__global__ __launch_bounds__(512) void kW1(
    const float* __restrict__ a1, const float* __restrict__ abn1,
    const float* __restrict__ a2, const float* __restrict__ abn2,
    char* __restrict__ wsb) {
  __shared__ float S1[512], F1[512], redu[512];
  const int t = threadIdx.x, o = blockIdx.x;
  float* wsf = (float*)wsb;
  {
    float gg = abn1[t], be = abn1[512 + t], mn = abn1[1024 + t], va = abn1[1536 + t];
    float s = gg * rsqrtf(va + 1e-5f);
    S1[t] = s; F1[t] = be - mn * s;
  }
  float g2 = abn2[o], be2 = abn2[256 + o], mn2 = abn2[512 + o], va2 = abn2[768 + o];
  float s2 = g2 * rsqrtf(va2 + 1e-5f);
  float f2v = be2 - mn2 * s2;
  __syncthreads();
  float acc = 0.f;
  const float* a2r = a2 + o * 512;
  for (int m = 0; m < 512; ++m) acc = fmaf(a2r[m] * S1[m], a1[m * 512 + t], acc);
  wsf[(B_WL / 4) + o * 512 + t] = s2 * acc;
  redu[t] = a2r[t] * F1[t];
  __syncthreads();
  for (int sft = 256; sft >= 1; sft >>= 1) {
    if (t < sft) redu[t] += redu[t + sft];
    __syncthreads();
  }
  if (t == 0) wsf[(B_CPP / 4) + o] = s2 * redu[0] + f2v;
}

// ---------------- kW2: W_dd, W_dx ----------------
__global__ __launch_bounds__(512) void kW2(
    const float* __restrict__ d1, const float* __restrict__ dbn1,
    const float* __restrict__ d2, char* __restrict__ wsb) {
  __shared__ float SD[256], WDDl[512];
  const int t = threadIdx.x;
  float* wsf = (float*)wsb;
  if (t < 256) {
    float gg = dbn1[t], va = dbn1[768 + t];
    SD[t] = gg * rsqrtf(va + 1e-5f);
  }
  __syncthreads();
  {
    int j = t >> 8, v = t & 255;
    float acc = 0.f;
    for (int o = 0; o < 256; ++o) acc = fmaf(d2[j * 256 + o] * SD[o], d1[o * 512 + v], acc);
    WDDl[t] = acc;
    wsf[(B_WDD / 4) + t] = acc;
  }
  __syncthreads();
  {
    int c = t;
    float acc0 = 0.f, acc1 = 0.f;
    for (int v = 0; v < 256; ++v) {
      float wl = wsf[(B_WL / 4) + v * 512 + c];
      acc0 = fmaf(WDDl[v], wl, acc0);
      acc1 = fmaf(WDDl[256 + v], wl, acc1);
    }
    wsf[(B_WDX / 4) + c] = acc0;
    wsf[(B_WDX / 4) + 512 + c] = acc1;
  }
}

// ---------------- kPack: fragment-linear bf16 packs + fp32 transposes ----------------
// Packed layout: tile T covers 16 output rows; within a tile, address =
// T*(KS*1024) + ks*1024 + lane*16; lane (l&15)=row-in-tile, (l>>4)=k-subgroup;
// element j -> source col = ks*32 + (l>>4)*8 + j.
__global__ __launch_bounds__(256) void kPack(
    const float* __restrict__ wq, const float* __restrict__ wk, const float* __restrict__ wv,
    const float* __restrict__ wr, const float* __restrict__ pw1, const float* __restrict__ pw2,
    const float* __restrict__ d1, char* __restrict__ wsb) {
  int i = blockIdx.x * 256 + threadIdx.x;
  float* wsf = (float*)wsb;
  unsigned short* u16 = (unsigned short*)wsb;
  if (i < 270336) {  // Wbig: 33 tiles, K=512 (ks 0..15)
    int T = i >> 13, r = i & 8191;
    int ks = r >> 9, l = (r >> 3) & 63, j = r & 7;
    int row = T * 16 + (l & 15);
    int col = ks * 32 + (l >> 4) * 8 + j;
    float v;
    if (row < 256) v = wq[row * 512 + col];
    else if (row < 512) v = wsf[(B_WL / 4) + (row - 256) * 512 + col];
    else if (row < 514) v = wsf[(B_WDX / 4) + (row - 512) * 512 + col];
    else v = 0.f;
    u16[(B_WBIG / 2) + i] = (unsigned short)f2bfu(v);
    return;
  }
  i -= 270336;
  if (i < 262144) {  // Wkv: 32 tiles, K=512
    int T = i >> 13, r = i & 8191;
    int ks = r >> 9, l = (r >> 3) & 63, j = r & 7;
    int row = T * 16 + (l & 15);
    int col = ks * 32 + (l >> 4) * 8 + j;
    float v = row < 256 ? wk[row * 512 + col] : wv[(row - 256) * 512 + col];
    u16[(B_WKV / 2) + i] = (unsigned short)f2bfu(v);
    return;
  }
  i -= 262144;
  if (i < 131072) {  // WR: 32 tiles, K=256 (ks 0..7)
    int T = i >> 12, r = i & 4095;
    int ks = r >> 9, l = (r >> 3) & 63, j = r & 7;
    int row = T * 16 + (l & 15);
    int col = ks * 32 + (l >> 4) * 8 + j;
    u16[(B_WR / 2) + i] = (unsigned short)f2bfu(wr[row * 256 + col]);
    return;
  }
  i -= 131072;
  if (i < 262144) { int o = i >> 9, c = i & 511; wsf[(B_PW1T / 4) + c * 512 + o] = pw1[i]; return; }
  i -= 262144;
  if (i < 131072) { int o = i >> 9, c = i & 511; wsf[(B_PW2T / 4) + c * 256 + o] = pw2[i]; return; }
  i -= 131072;
  if (i < 65536) { int o = i >> 8, v = i & 255; wsf[(B_D1BT / 4) + v * 256 + o] = d1[o * 512 + 256 + v]; }
}

// ---------------- k1: keys/values MFMA + ctx/Z/colsum partials ----------------
__global__ __launch_bounds__(512, 2) void k1_reduce(
    const float* __restrict__ x, const float* __restrict__ y,
    const float* __restrict__ bk, const float* __restrict__ bv, char* __restrict__ wsb) {
  __shared__ __align__(16) unsigned char Xl[65536];  // X staging; overlaid: el=Xl, vl=Xl+32K
  __shared__ float Red[1536];  // [0..511]=Z, [512..1535]=colsum
  unsigned char* el = Xl;
  unsigned char* vl = Xl + 32768;
  const int t = threadIdx.x;
  const int wv_ = t >> 6, lo16 = t & 15, g = (t >> 4) & 3, l = t & 63;
  const int pt = wv_ & 3, hf = wv_ >> 2;
  const int p0 = pt * 16;
  const char* Wkv = wsb + B_WKV;
  float* wsf = (float*)wsb;

  for (int i = t; i < 1536; i += 512) Red[i] = 0.f;
  float csum[2][8];
#pragma unroll
  for (int b2 = 0; b2 < 2; ++b2)
#pragma unroll
    for (int i = 0; i < 8; ++i) csum[b2][i] = 0.f;
  f32x4 ctxacc[2][2][2];
#pragma unroll
  for (int b2 = 0; b2 < 2; ++b2)
    for (int m = 0; m < 2; ++m)
      for (int n = 0; n < 2; ++n) ctxacc[b2][m][n] = (f32x4){0.f, 0.f, 0.f, 0.f};
  const int h = wv_;  // head for ctx phase (0..7)
  const int n0 = blockIdx.x * 64;

  for (int b = 0; b < 2; ++b) {
    const float* src = b ? y : x;
    __syncthreads();  // (A) previous el/vl reads done
    for (int r = 0; r < 8; ++r) {
      int chunk = r * 512 + t;
      int prow = chunk >> 6, j = chunk & 63;
      const float* gp = src + (size_t)(n0 + prow) * 512 + j * 8;
      float4 u0 = *(const float4*)gp;
      float4 u1 = *(const float4*)(gp + 4);
      csum[b][0] += u0.x; csum[b][1] += u0.y; csum[b][2] += u0.z; csum[b][3] += u0.w;
      csum[b][4] += u1.x; csum[b][5] += u1.y; csum[b][6] += u1.z; csum[b][7] += u1.w;
      uint4 pk;
      pk.x = pack2(u0.x, u0.y); pk.y = pack2(u0.z, u0.w);
      pk.z = pack2(u1.x, u1.y); pk.w = pack2(u1.z, u1.w);
      int byte = (prow * 1024 + j * 16) ^ ((prow & 7) << 4);
      *(uint4*)(Xl + byte) = pk;
    }
    __syncthreads();  // (B)
    bf16x8 bx[16];
    {
      int rowX = p0 + lo16;
      int base = rowX * 1024 + g * 16;
      int swz = (rowX & 7) << 4;
#pragma unroll
      for (int ks = 0; ks < 16; ++ks) bx[ks] = *(const bf16x8*)(Xl + ((base + ks * 64) ^ swz));
    }
    __syncthreads();  // (B2) Xl dead; el/vl overlay writes allowed
    for (int tp = 0; tp < 8; ++tp) {
      int t0 = hf * 16 + tp * 2;
      f32x4 a0 = {0.f, 0.f, 0.f, 0.f}, a1 = {0.f, 0.f, 0.f, 0.f};
      const char* ap = Wkv + t0 * 16384 + l * 16;
#pragma unroll
      for (int ks = 0; ks < 16; ++ks) {
        bf16x8 af0 = *(const bf16x8*)(ap + ks * 1024);
        bf16x8 af1 = *(const bf16x8*)(ap + 16384 + ks * 1024);
        a0 = MFMA(af0, bx[ks], a0);
        a1 = MFMA(af1, bx[ks], a1);
      }
      int t1 = t0 + 1;
      int pp = p0 + lo16;
      if (hf == 0) {  // keys -> e, Z, el
        float e0[4], e1[4];
#pragma unroll
        for (int r = 0; r < 4; ++r) {
          e0[r] = __expf(a0[r] + bk[t0 * 16 + g * 4 + r]);
          e1[r] = __expf(a1[r] + bk[t1 * 16 + g * 4 + r]);
        }
#pragma unroll
        for (int r = 0; r < 4; ++r) {
          float v0 = e0[r], v1 = e1[r];
          for (int m = 8; m >= 1; m >>= 1) {
            v0 += __shfl_xor(v0, m, 16);
            v1 += __shfl_xor(v1, m, 16);
          }
          if (lo16 == 0) {
            atomicAdd(&Red[b * 256 + t0 * 16 + g * 4 + r], v0);
            atomicAdd(&Red[b * 256 + t1 * 16 + g * 4 + r], v1);
          }
        }
#pragma unroll
        for (int r = 0; r < 4; ++r) {
          int row0 = t0 * 16 + g * 4 + r;
          int row1 = t1 * 16 + g * 4 + r;
          *(unsigned short*)(el + ((row0 * 128 + pp * 2) ^ ((row0 & 7) << 4))) = (unsigned short)f2bfu(e0[r]);
          *(unsigned short*)(el + ((row1 * 128 + pp * 2) ^ ((row1 & 7) << 4))) = (unsigned short)f2bfu(e1[r]);
        }
      } else {  // values -> vl
#pragma unroll
        for (int r = 0; r < 4; ++r) {
          int row0 = (t0 - 16) * 16 + g * 4 + r;
          int row1 = (t1 - 16) * 16 + g * 4 + r;
          *(unsigned short*)(vl + ((row0 * 128 + pp * 2) ^ ((row0 & 7) << 4))) = (unsigned short)f2bfu(a0[r] + bv[row0]);
          *(unsigned short*)(vl + ((row1 * 128 + pp * 2) ^ ((row1 & 7) << 4))) = (unsigned short)f2bfu(a1[r] + bv[row1]);
        }
      }
    }
    __syncthreads();  // (C) el, vl ready
#pragma unroll
    for (int m = 0; m < 2; ++m)
#pragma unroll
      for (int n = 0; n < 2; ++n) {
        int rowe = h * 32 + m * 16 + lo16;
        int rowv = h * 32 + n * 16 + lo16;
#pragma unroll
        for (int ks = 0; ks < 2; ++ks) {
          bf16x8 ea = *(const bf16x8*)(el + ((rowe * 128 + ks * 64 + g * 16) ^ ((rowe & 7) << 4)));
          bf16x8 vb = *(const bf16x8*)(vl + ((rowv * 128 + ks * 64 + g * 16) ^ ((rowv & 7) << 4)));
          ctxacc[b][m][n] = MFMA(ea, vb, ctxacc[b][m][n]);
        }
      }
  }
  // finalize: ctx partial atomics; ctx layout [b][h][k_local][v]
  {
    float* ctxg = wsf + (B_CTXC / 4) + (blockIdx.x & 7) * 16384;
#pragma unroll
    for (int b = 0; b < 2; ++b)
      for (int m = 0; m < 2; ++m)
        for (int n = 0; n < 2; ++n)
#pragma unroll
          for (int r = 0; r < 4; ++r) {
            int klocal = m * 16 + g * 4 + r;
            int vcol = n * 16 + lo16;
            atomicAdd(&ctxg[((b * 8 + h) * 32 + klocal) * 32 + vcol], ctxacc[b][m][n][r]);
          }
  }
#pragma unroll
  for (int b = 0; b < 2; ++b)
#pragma unroll
    for (int i = 0; i < 8; ++i) atomicAdd(&Red[512 + b * 512 + (t & 63) * 8 + i], csum[b][i]);
  __syncthreads();
  atomicAdd(&wsf[(B_ZP / 4) + t], Red[t]);
  atomicAdd(&wsf[(B_COLS / 4) + t], Red[512 + t]);
  atomicAdd(&wsf[(B_COLS / 4) + 512 + t], Red[1024 + t]);
}

// ---------------- k2: ctx normalize (packed write), pool chain, constD, biasOut ----------------
__global__ __launch_bounds__(512) void k2_finalize(
    const float* __restrict__ pbn1, const float* __restrict__ pbn2,
    const float* __restrict__ dbn1, const float* __restrict__ d2,
    const float* __restrict__ ea_br, char* __restrict__ wsb) {
  __shared__ float HI[1024], H1[1024], H2l[512], VB[512], slot[4];
  const int t = threadIdx.x;
  float* wsf = (float*)wsb;
  unsigned short* u16 = (unsigned short*)wsb;
  for (int idx = t; idx < 16384; idx += 512) {
    float s = 0.f;
#pragma unroll
    for (int c = 0; c < 8; ++c) s += wsf[(B_CTXC / 4) + c * 16384 + idx];
    int v = idx & 31, row = idx >> 5;
    int b = row >> 8, kr = row & 255;
    int hh = kr >> 5, kh = kr & 31;
    float val = s / wsf[(B_ZP / 4) + b * 256 + kr];
    // fragment-linear ctx: tile ((b*8+hh)*2 + v/16), lane=(v&15)+16*(kh>>3), elem=kh&7
    int m = v >> 4;
    int lane = (v & 15) + ((kh >> 3) << 4);
    int j = kh & 7;
    u16[(B_CTXT / 2) + (((b * 8 + hh) * 2 + m) << 9) + lane * 8 + j] = (unsigned short)f2bfu(val);
  }
  if (t < 4) slot[t] = 0.f;
  for (int idx = t; idx < 1024; idx += 512) HI[idx] = wsf[(B_COLS / 4) + idx] * (1.f / 32768.f);
  __syncthreads();
  {
    int o = t;
    float gg = pbn1[o], be = pbn1[512 + o], mn = pbn1[1024 + o], va = pbn1[1536 + o];
    float sc = gg * rsqrtf(va + 1e-5f), sh = be - mn * sc;
    for (int b = 0; b < 2; ++b) {
      float acc = 0.f;
      for (int c = 0; c < 512; ++c) acc = fmaf(wsf[(B_PW1T / 4) + c * 512 + o], HI[b * 512 + c], acc);
      H1[b * 512 + o] = acc * sc + sh;
    }
  }
  __syncthreads();
  if (t < 256) {
    int o = t;
    float gg = pbn2[o], be = pbn2[256 + o], mn = pbn2[512 + o], va = pbn2[768 + o];
    float sc = gg * rsqrtf(va + 1e-5f), sh = be - mn * sc;
    for (int b = 0; b < 2; ++b) {
      float acc = 0.f;
      for (int c = 0; c < 512; ++c) acc = fmaf(wsf[(B_PW2T / 4) + c * 256 + o], H1[b * 512 + c], acc);
      float vv = acc * sc + sh;
      H2l[b * 256 + o] = vv;
      wsf[(B_HIGH2 / 4) + b * 256 + o] = vv;
    }
  }
  __syncthreads();
  if (t < 256) {
    int o = t;
    float gg = dbn1[o], be = dbn1[256 + o], mn = dbn1[512 + o], va = dbn1[768 + o];
    float sd = gg * rsqrtf(va + 1e-5f), fd = be - mn * sd;
    for (int b = 0; b < 2; ++b) {
      float acc = 0.f;
      for (int v = 0; v < 256; ++v) acc = fmaf(wsf[(B_D1BT / 4) + v * 256 + o], H2l[b * 256 + v], acc);
      VB[b * 256 + o] = sd * acc + fd;
    }
  }
  __syncthreads();
  if (t < 256) {
    int o = t;
    for (int b = 0; b < 2; ++b)
      for (int j = 0; j < 2; ++j) atomicAdd(&slot[b * 2 + j], d2[j * 256 + o] * VB[b * 256 + o]);
    float cp = wsf[(B_CPP / 4) + o];
    for (int j = 0; j < 2; ++j) {
      float w = wsf[(B_WDD / 4) + j * 256 + o] * cp;
      atomicAdd(&slot[0 + j], w);
      atomicAdd(&slot[2 + j], w);
    }
  }
  __syncthreads();
  if (t < 4) wsf[(B_CONSTD / 4) + t] = slot[t];
  {
    int o = t;
    float bb = 0.5f * ea_br[o];
    if (o >= 256) bb += 0.5f * wsf[(B_CPP / 4) + o - 256];
    wsf[(B_BIASO / 4) + o] = bb;
  }
}

// ---------------- k3: main fused per-position MFMA pass ----------------
__global__ __launch_bounds__(512, 2) void k3_main(
    const float* __restrict__ x, const float* __restrict__ y,
    const float* __restrict__ bq, const char* __restrict__ wsb,
    float* __restrict__ out) {
  __shared__ __align__(16) unsigned char Xl[65536];  // X staging; overlaid Q/attS slabs
  __shared__ float wgtl[64];
  const int t = threadIdx.x;
  const int wv_ = t >> 6, lo16 = t & 15, g = (t >> 4) & 3, l = t & 63;
  const int pt = wv_ & 3, hf = wv_ >> 2;
  const int p0 = pt * 16;
  const int n0 = blockIdx.x * 64;
  const char* Wbig = wsb + B_WBIG;
  const char* WRp = wsb + B_WR;
  const char* CTXT = wsb + B_CTXT;
  const float* wsf = (const float*)wsb;
  unsigned char* Qslab = Xl + pt * 8192;

  f32x4 macc[16];  // hf==0: attS accumulators; hf==1: 0.25*(L0+L1)
#pragma unroll
  for (int i = 0; i < 16; ++i) macc[i] = (f32x4){0.f, 0.f, 0.f, 0.f};
  float wg0 = 0.f, wg1 = 0.f;

  for (int b = 0; b < 2; ++b) {
    const float* src = b ? y : x;
    __syncthreads();  // (A) previous Qslab reads done
    for (int r = 0; r < 8; ++r) {
      int chunk = r * 512 + t;
      int prow = chunk >> 6, j = chunk & 63;
      const float* gp = src + (size_t)(n0 + prow) * 512 + j * 8;
      float4 u0 = *(const float4*)gp;
      float4 u1 = *(const float4*)(gp + 4);
      uint4 pk;
      pk.x = pack2(u0.x, u0.y); pk.y = pack2(u0.z, u0.w);
      pk.z = pack2(u1.x, u1.y); pk.w = pack2(u1.z, u1.w);
      int byte = (prow * 1024 + j * 16) ^ ((prow & 7) << 4);
      *(uint4*)(Xl + byte) = pk;
    }
    __syncthreads();  // (B)
    bf16x8 bx[16];
    {
      int rowX = p0 + lo16;
      int base = rowX * 1024 + g * 16;
      int swz = (rowX & 7) << 4;
#pragma unroll
      for (int ks = 0; ks < 16; ++ks) bx[ks] = *(const bf16x8*)(Xl + ((base + ks * 64) ^ swz));
    }
    __syncthreads();  // (B2) Xl dead; Qslab overlay writes allowed
    for (int tp = 0; tp < 8; ++tp) {
      int t0 = hf * 16 + tp * 2;
      f32x4 a0 = {0.f, 0.f, 0.f, 0.f}, a1 = {0.f, 0.f, 0.f, 0.f};
      const char* ap = Wbig + t0 * 16384 + l * 16;
#pragma unroll
      for (int ks = 0; ks < 16; ++ks) {
        bf16x8 af0 = *(const bf16x8*)(ap + ks * 1024);
        bf16x8 af1 = *(const bf16x8*)(ap + 16384 + ks * 1024);
        a0 = MFMA(af0, bx[ks], a0);
        a1 = MFMA(af1, bx[ks], a1);
      }
      int t1 = t0 + 1;
      if (hf == 0) {  // Q pair = head tp: bias + softmax over 32 head-channels
        int hh = tp;
        float q[8], e[8];
        float mx = -1e30f;
#pragma unroll
        for (int r = 0; r < 4; ++r) {
          q[r] = a0[r] + bq[hh * 32 + g * 4 + r];
          q[4 + r] = a1[r] + bq[hh * 32 + 16 + g * 4 + r];
          mx = fmaxf(mx, fmaxf(q[r], q[4 + r]));
        }
        mx = fmaxf(mx, __shfl_xor(mx, 16, 64));
        mx = fmaxf(mx, __shfl_xor(mx, 32, 64));
        float sm = 0.f;
#pragma unroll
        for (int r = 0; r < 8; ++r) { e[r] = __expf(q[r] - mx); sm += e[r]; }
        sm += __shfl_xor(sm, 16, 64);
        sm += __shfl_xor(sm, 32, 64);
        float inv = 1.f / sm;
        uint2 w0, w1;
        w0.x = pack2(e[0] * inv, e[1] * inv); w0.y = pack2(e[2] * inv, e[3] * inv);
        w1.x = pack2(e[4] * inv, e[5] * inv); w1.y = pack2(e[6] * inv, e[7] * inv);
        int base_q = lo16 * 512 + hh * 64 + g * 8;
        int swzq = (lo16 & 7) << 4;
        *(uint2*)(Qslab + (base_q ^ swzq)) = w0;
        *(uint2*)(Qslab + ((base_q + 32) ^ swzq)) = w1;
      } else {  // L tiles
        macc[tp * 2] += 0.25f * a0;
        macc[tp * 2 + 1] += 0.25f * a1;
      }
    }
    if (hf == 1) {  // delta tile (rows 512..527 = packed tile 32)
      f32x4 ad = {0.f, 0.f, 0.f, 0.f};
      const char* ap = Wbig + 32 * 16384 + l * 16;
#pragma unroll
      for (int ks = 0; ks < 16; ++ks) {
        bf16x8 af = *(const bf16x8*)(ap + ks * 1024);
        ad = MFMA(af, bx[ks], ad);
      }
      if (g == 0) {
        float d0 = ad[0] + wsf[(B_CONSTD / 4) + b * 2 + 0];
        float d1 = ad[1] + wsf[(B_CONSTD / 4) + b * 2 + 1];
        int pos = n0 + p0 + lo16;
        float gx = -1.f + 2.f * (float)pos / 32767.f + d0;
        float gy = -1.f + d1;
        float ix = gx * 0.5f, iy = gy * 0.5f;
        float wx = fminf(fmaxf(1.f - fabsf(ix), 0.f), 1.f);
        float wy = fminf(fmaxf(1.f - fabsf(iy), 0.f), 1.f);
        wgtl[p0 + lo16] = wx * wy;
      }
    } else {  // att: per-head mfma(ctx_packed, Q)
      int swzq = (lo16 & 7) << 4;
#pragma unroll
      for (int hh = 0; hh < 8; ++hh) {
        bf16x8 qf = *(const bf16x8*)(Qslab + ((lo16 * 512 + hh * 64 + g * 16) ^ swzq));
        const char* cp = CTXT + (b * 8 + hh) * 2048 + l * 16;
        bf16x8 c0 = *(const bf16x8*)(cp);
        bf16x8 c1 = *(const bf16x8*)(cp + 1024);
        macc[hh * 2] = MFMA(c0, qf, macc[hh * 2]);
        macc[hh * 2 + 1] = MFMA(c1, qf, macc[hh * 2 + 1]);
      }
    }
    __syncthreads();  // (C) wgtl ready
    if (hf == 0) {
      float w = wgtl[p0 + lo16];
      if (b == 0) wg0 = w; else wg1 = w;
    }
  }
  // attS (hf==0) -> LDS (reuse Qslab)
  if (hf == 0) {
    int swzq = (lo16 & 7) << 4;
#pragma unroll
    for (int hh = 0; hh < 8; ++hh)
#pragma unroll
      for (int m = 0; m < 2; ++m) {
        f32x4 v = macc[hh * 2 + m];
        uint2 w;
        w.x = pack2(v[0], v[1]); w.y = pack2(v[2], v[3]);
        int byte = (lo16 * 512 + hh * 64 + m * 32 + g * 8) ^ swzq;
        *(uint2*)(Qslab + byte) = w;
      }
  }
  __syncthreads();  // (D)
  bf16x8 br8[8];
  {
    int base = lo16 * 512 + g * 16;
    int swzq = (lo16 & 7) << 4;
#pragma unroll
    for (int ks = 0; ks < 8; ++ks) br8[ks] = *(const bf16x8*)(Qslab + ((base + ks * 64) ^ swzq));
  }
  const float* bo = wsf + (B_BIASO / 4);
  const size_t rowaddr = (size_t)(n0 + p0 + lo16) * 512;
  for (int tp = 0; tp < 8; ++tp) {
    int lt0 = tp * 2, lt1 = lt0 + 1;
    int ch0 = hf * 256 + lt0 * 16, ch1 = ch0 + 16;
    int T0 = hf * 16 + lt0;  // WR tile indices
    f32x4 r0 = {0.f, 0.f, 0.f, 0.f}, r1 = {0.f, 0.f, 0.f, 0.f};
    const char* ap = WRp + T0 * 8192 + l * 16;
#pragma unroll
    for (int ks = 0; ks < 8; ++ks) {
      bf16x8 a0 = *(const bf16x8*)(ap + ks * 1024);
      bf16x8 a1 = *(const bf16x8*)(ap + 8192 + ks * 1024);
      r0 = MFMA(a0, br8[ks], r0);
      r1 = MFMA(a1, br8[ks], r1);
    }
#pragma unroll
    for (int half = 0; half < 2; ++half) {
      int lt = half ? lt1 : lt0;
      int cb = (half ? ch1 : ch0) + g * 4;
      f32x4 rr = half ? r1 : r0;
      f32x4 xr = *(const f32x4*)(x + rowaddr + cb);
      f32x4 yr = *(const f32x4*)(y + rowaddr + cb);
      f32x4 bb = *(const f32x4*)(bo + cb);
      f32x4 extra;
      if (hf == 0) {
        f32x4 h20 = *(const f32x4*)(wsf + (B_HIGH2 / 4) + cb);
        f32x4 h21 = *(const f32x4*)(wsf + (B_HIGH2 / 4) + 256 + cb);
        extra = (0.25f * wg0) * h20 + (0.25f * wg1) * h21;
      } else {
        extra = macc[lt];
      }
      f32x4 vout = extra + 0.25f * rr + 0.25f * (xr + yr) + bb;
      *(f32x4*)(out + rowaddr + cb) = vout;
    }
  }
}

extern "C" void kernel_launch(void* const* d_in, const int* in_sizes, int n_in,
                              void* d_out, int out_size, void* d_ws, size_t ws_size,
                              hipStream_t stream) {
  const float* x = (const float*)d_in[0];
  const float* y = (const float*)d_in[1];
  const float* ea_wk = (const float*)d_in[2];
  const float* ea_bk = (const float*)d_in[3];
  const float* ea_wq = (const float*)d_in[4];
  const float* ea_bq = (const float*)d_in[5];
  const float* ea_wv = (const float*)d_in[6];
  const float* ea_bv = (const float*)d_in[7];
  const float* ea_wr = (const float*)d_in[8];
  const float* ea_br = (const float*)d_in[9];
  const float* pool_w1 = (const float*)d_in[10];
  const float* pool_bn1 = (const float*)d_in[11];
  const float* pool_w2 = (const float*)d_in[12];
  const float* pool_bn2 = (const float*)d_in[13];
  const float* adapt_w1 = (const float*)d_in[14];
  const float* adapt_bn1 = (const float*)d_in[15];
  const float* adapt_w2 = (const float*)d_in[16];
  const float* adapt_bn2 = (const float*)d_in[17];
  const float* delta_w1 = (const float*)d_in[18];
  const float* delta_bn1 = (const float*)d_in[19];
  const float* delta_w2 = (const float*)d_in[20];
  char* ws = (char*)d_ws;
  float* out = (float*)d_out;

  hipMemsetAsync(ws, 0, 530432, stream);  // ctx copies + Z + colsum
  kW1<<<256, 512, 0, stream>>>(adapt_w1, adapt_bn1, adapt_w2, adapt_bn2, ws);
  kW2<<<1, 512, 0, stream>>>(delta_w1, delta_bn1, delta_w2, ws);
  kPack<<<4384, 256, 0, stream>>>(ea_wq, ea_wk, ea_wv, ea_wr, pool_w1, pool_w2, delta_w1, ws);
  k1_reduce<<<512, 512, 0, stream>>>(x, y, ea_bk, ea_bv, ws);
  k2_finalize<<<1, 512, 0, stream>>>(pool_bn1, pool_bn2, delta_bn1, delta_w2, ea_br, ws);
  k3_main<<<512, 512, 0, stream>>>(x, y, ea_bq, ws, out);
}

// Round 5
// 948.614 us; speedup vs baseline: 3.4440x; 1.5967x over previous
//
#include <hip/hip_runtime.h>
#include <math.h>

// ---------------- ws byte offsets ----------------
#define B_CTXC   0          // 8 copies of ctx partials [8][16384] f32 = 524288
#define B_ZP     524288     // [2][256] f32
#define B_COLS   526336     // [2][512] f32
#define B_HIGH2  530432     // [2][256] f32
#define B_CONSTD 532480     // [2][2] f32 (+pad)
#define B_BIASO  532544     // [512] f32
#define B_CPP    534592     // [256] f32 (c'')
#define B_CTXT   535616     // [2][8] x 2 tiles x 1KB bf16, fragment-linear
#define B_WDD    568384     // [2][256] f32
#define B_WDX    570432     // [2][512] f32
#define B_WL     574528     // [256][512] f32 (W_L'')
#define B_WBIG   1098816    // 33 tiles x 16KB bf16, fragment-linear
#define B_WKV    1639488    // 32 tiles x 16KB bf16, fragment-linear
#define B_WR     2163776    // 32 tiles x 8KB bf16, fragment-linear
#define B_PW1T   2425920    // [512][512] f32 transposed
#define B_PW2T   3474496    // [512][256] f32 transposed
#define B_D1BT   3998784    // [256][256] f32 transposed

typedef __attribute__((ext_vector_type(8))) short bf16x8;
typedef __attribute__((ext_vector_type(4))) float f32x4;

#define MFMA(a, b, c) __builtin_amdgcn_mfma_f32_16x16x32_bf16(a, b, c, 0, 0, 0)

__device__ inline unsigned f2bfu(float f) {
  unsigned u = __float_as_uint(f);
  return (u + 0x7FFFu + ((u >> 16) & 1u)) >> 16;
}
__device__ inline unsigned pack2(float a, float b) { return f2bfu(a) | (f2bfu(b) << 16); }

// ---------------- kW1: W_L'' (fp32) + c'' ----------------
__global__ __launch_bounds__(512) void kW1(
    const float* __restrict__ a1, const float* __restrict__ abn1,
    const float* __restrict__ a2, const float* __restrict__ abn2,
    char* __restrict__ wsb) {
  __shared__ float S1[512], F1[512], redu[512];
  const int t = threadIdx.x, o = blockIdx.x;
  float* wsf = (float*)wsb;
  {
    float gg = abn1[t], be = abn1[512 + t], mn = abn1[1024 + t], va = abn1[1536 + t];
    float s = gg * rsqrtf(va + 1e-5f);
    S1[t] = s; F1[t] = be - mn * s;
  }
  float g2 = abn2[o], be2 = abn2[256 + o], mn2 = abn2[512 + o], va2 = abn2[768 + o];
  float s2 = g2 * rsqrtf(va2 + 1e-5f);
  float f2v = be2 - mn2 * s2;
  __syncthreads();
  float acc = 0.f;
  const float* a2r = a2 + o * 512;
  for (int m = 0; m < 512; ++m) acc = fmaf(a2r[m] * S1[m], a1[m * 512 + t], acc);
  wsf[(B_WL / 4) + o * 512 + t] = s2 * acc;
  redu[t] = a2r[t] * F1[t];
  __syncthreads();
  for (int sft = 256; sft >= 1; sft >>= 1) {
    if (t < sft) redu[t] += redu[t + sft];
    __syncthreads();
  }
  if (t == 0) wsf[(B_CPP / 4) + o] = s2 * redu[0] + f2v;
}

// ---------------- kW2: W_dd, W_dx ----------------
__global__ __launch_bounds__(512) void kW2(
    const float* __restrict__ d1, const float* __restrict__ dbn1,
    const float* __restrict__ d2, char* __restrict__ wsb) {
  __shared__ float SD[256], WDDl[512];
  const int t = threadIdx.x;
  float* wsf = (float*)wsb;
  if (t < 256) {
    float gg = dbn1[t], va = dbn1[768 + t];
    SD[t] = gg * rsqrtf(va + 1e-5f);
  }
  __syncthreads();
  {
    int j = t >> 8, v = t & 255;
    float acc = 0.f;
    for (int o = 0; o < 256; ++o) acc = fmaf(d2[j * 256 + o] * SD[o], d1[o * 512 + v], acc);
    WDDl[t] = acc;
    wsf[(B_WDD / 4) + t] = acc;
  }
  __syncthreads();
  {
    int c = t;
    float acc0 = 0.f, acc1 = 0.f;
    for (int v = 0; v < 256; ++v) {
      float wl = wsf[(B_WL / 4) + v * 512 + c];
      acc0 = fmaf(WDDl[v], wl, acc0);
      acc1 = fmaf(WDDl[256 + v], wl, acc1);
    }
    wsf[(B_WDX / 4) + c] = acc0;
    wsf[(B_WDX / 4) + 512 + c] = acc1;
  }
}

// ---------------- kPack: fragment-linear bf16 packs + fp32 transposes ----------------
__global__ __launch_bounds__(256) void kPack(
    const float* __restrict__ wq, const float* __restrict__ wk, const float* __restrict__ wv,
    const float* __restrict__ wr, const float* __restrict__ pw1, const float* __restrict__ pw2,
    const float* __restrict__ d1, char* __restrict__ wsb) {
  int i = blockIdx.x * 256 + threadIdx.x;
  float* wsf = (float*)wsb;
  unsigned short* u16 = (unsigned short*)wsb;
  if (i < 270336) {  // Wbig: 33 tiles, K=512 (ks 0..15)
    int T = i >> 13, r = i & 8191;
    int ks = r >> 9, l = (r >> 3) & 63, j = r & 7;
    int row = T * 16 + (l & 15);
    int col = ks * 32 + (l >> 4) * 8 + j;
    float v;
    if (row < 256) v = wq[row * 512 + col];
    else if (row < 512) v = wsf[(B_WL / 4) + (row - 256) * 512 + col];
    else if (row < 514) v = wsf[(B_WDX / 4) + (row - 512) * 512 + col];
    else v = 0.f;
    u16[(B_WBIG / 2) + i] = (unsigned short)f2bfu(v);
    return;
  }
  i -= 270336;
  if (i < 262144) {  // Wkv: 32 tiles, K=512
    int T = i >> 13, r = i & 8191;
    int ks = r >> 9, l = (r >> 3) & 63, j = r & 7;
    int row = T * 16 + (l & 15);
    int col = ks * 32 + (l >> 4) * 8 + j;
    float v = row < 256 ? wk[row * 512 + col] : wv[(row - 256) * 512 + col];
    u16[(B_WKV / 2) + i] = (unsigned short)f2bfu(v);
    return;
  }
  i -= 262144;
  if (i < 131072) {  // WR: 32 tiles, K=256 (ks 0..7)
    int T = i >> 12, r = i & 4095;
    int ks = r >> 9, l = (r >> 3) & 63, j = r & 7;
    int row = T * 16 + (l & 15);
    int col = ks * 32 + (l >> 4) * 8 + j;
    u16[(B_WR / 2) + i] = (unsigned short)f2bfu(wr[row * 256 + col]);
    return;
  }
  i -= 131072;
  if (i < 262144) { int o = i >> 9, c = i & 511; wsf[(B_PW1T / 4) + c * 512 + o] = pw1[i]; return; }
  i -= 262144;
  if (i < 131072) { int o = i >> 9, c = i & 511; wsf[(B_PW2T / 4) + c * 256 + o] = pw2[i]; return; }
  i -= 131072;
  if (i < 65536) { int o = i >> 8, v = i & 255; wsf[(B_D1BT / 4) + v * 256 + o] = d1[o * 512 + 256 + v]; }
}

// ---------------- k1: keys/values MFMA + ctx/Z/colsum partials ----------------
__global__ __launch_bounds__(512, 2) void k1_reduce(
    const float* __restrict__ x, const float* __restrict__ y,
    const float* __restrict__ bk, const float* __restrict__ bv, char* __restrict__ wsb) {
  __shared__ __align__(16) unsigned char Xl[65536];  // X staging; overlaid: el=Xl, vl=Xl+32K
  __shared__ float Red[1536];  // [0..511]=Z, [512..1535]=colsum
  unsigned char* el = Xl;
  unsigned char* vl = Xl + 32768;
  const int t = threadIdx.x;
  const int wv_ = t >> 6, lo16 = t & 15, g = (t >> 4) & 3, l = t & 63;
  const int pt = wv_ & 3, hf = wv_ >> 2;
  const int p0 = pt * 16;
  const char* Wkv = wsb + B_WKV;
  float* wsf = (float*)wsb;

  for (int i = t; i < 1536; i += 512) Red[i] = 0.f;
  float csum[2][8];
#pragma unroll
  for (int b2 = 0; b2 < 2; ++b2)
#pragma unroll
    for (int i = 0; i < 8; ++i) csum[b2][i] = 0.f;
  f32x4 ctxacc[2][2][2];
#pragma unroll
  for (int b2 = 0; b2 < 2; ++b2)
#pragma unroll
    for (int m = 0; m < 2; ++m)
#pragma unroll
      for (int n = 0; n < 2; ++n) ctxacc[b2][m][n] = (f32x4){0.f, 0.f, 0.f, 0.f};
  const int h = wv_;  // head for ctx phase (0..7)
  const int n0 = blockIdx.x * 64;

#pragma unroll
  for (int b = 0; b < 2; ++b) {
    const float* src = b ? y : x;
    __syncthreads();  // (A) previous el/vl reads done
    for (int r = 0; r < 8; ++r) {
      int chunk = r * 512 + t;
      int prow = chunk >> 6, j = chunk & 63;
      const float* gp = src + (size_t)(n0 + prow) * 512 + j * 8;
      float4 u0 = *(const float4*)gp;
      float4 u1 = *(const float4*)(gp + 4);
      csum[b][0] += u0.x; csum[b][1] += u0.y; csum[b][2] += u0.z; csum[b][3] += u0.w;
      csum[b][4] += u1.x; csum[b][5] += u1.y; csum[b][6] += u1.z; csum[b][7] += u1.w;
      uint4 pk;
      pk.x = pack2(u0.x, u0.y); pk.y = pack2(u0.z, u0.w);
      pk.z = pack2(u1.x, u1.y); pk.w = pack2(u1.z, u1.w);
      int byte = (prow * 1024 + j * 16) ^ ((prow & 7) << 4);
      *(uint4*)(Xl + byte) = pk;
    }
    __syncthreads();  // (B)
    bf16x8 bx[16];
    {
      int rowX = p0 + lo16;
      int base = rowX * 1024 + g * 16;
      int swz = (rowX & 7) << 4;
#pragma unroll
      for (int ks = 0; ks < 16; ++ks) bx[ks] = *(const bf16x8*)(Xl + ((base + ks * 64) ^ swz));
    }
    __syncthreads();  // (B2) Xl dead; el/vl overlay writes allowed
#pragma unroll
    for (int tp = 0; tp < 8; ++tp) {
      int t0 = hf * 16 + tp * 2;
      f32x4 a0 = {0.f, 0.f, 0.f, 0.f}, a1 = {0.f, 0.f, 0.f, 0.f};
      const char* ap = Wkv + t0 * 16384 + l * 16;
#pragma unroll
      for (int ks = 0; ks < 16; ++ks) {
        bf16x8 af0 = *(const bf16x8*)(ap + ks * 1024);
        bf16x8 af1 = *(const bf16x8*)(ap + 16384 + ks * 1024);
        a0 = MFMA(af0, bx[ks], a0);
        a1 = MFMA(af1, bx[ks], a1);
      }
      int t1 = t0 + 1;
      int pp = p0 + lo16;
      if (hf == 0) {  // keys -> e, Z, el
        float e0[4], e1[4];
#pragma unroll
        for (int r = 0; r < 4; ++r) {
          e0[r] = __expf(a0[r] + bk[t0 * 16 + g * 4 + r]);
          e1[r] = __expf(a1[r] + bk[t1 * 16 + g * 4 + r]);
        }
#pragma unroll
        for (int r = 0; r < 4; ++r) {
          float v0 = e0[r], v1 = e1[r];
          for (int m = 8; m >= 1; m >>= 1) {
            v0 += __shfl_xor(v0, m, 16);
            v1 += __shfl_xor(v1, m, 16);
          }
          if (lo16 == 0) {
            atomicAdd(&Red[b * 256 + t0 * 16 + g * 4 + r], v0);
            atomicAdd(&Red[b * 256 + t1 * 16 + g * 4 + r], v1);
          }
        }
#pragma unroll
        for (int r = 0; r < 4; ++r) {
          int row0 = t0 * 16 + g * 4 + r;
          int row1 = t1 * 16 + g * 4 + r;
          *(unsigned short*)(el + ((row0 * 128 + pp * 2) ^ ((row0 & 7) << 4))) = (unsigned short)f2bfu(e0[r]);
          *(unsigned short*)(el + ((row1 * 128 + pp * 2) ^ ((row1 & 7) << 4))) = (unsigned short)f2bfu(e1[r]);
        }
      } else {  // values -> vl
#pragma unroll
        for (int r = 0; r < 4; ++r) {
          int row0 = (t0 - 16) * 16 + g * 4 + r;
          int row1 = (t1 - 16) * 16 + g * 4 + r;
          *(unsigned short*)(vl + ((row0 * 128 + pp * 2) ^ ((row0 & 7) << 4))) = (unsigned short)f2bfu(a0[r] + bv[row0]);
          *(unsigned short*)(vl + ((row1 * 128 + pp * 2) ^ ((row1 & 7) << 4))) = (unsigned short)f2bfu(a1[r] + bv[row1]);
        }
      }
    }
    __syncthreads();  // (C) el, vl ready
#pragma unroll
    for (int m = 0; m < 2; ++m)
#pragma unroll
      for (int n = 0; n < 2; ++n) {
        int rowe = h * 32 + m * 16 + lo16;
        int rowv = h * 32 + n * 16 + lo16;
#pragma unroll
        for (int ks = 0; ks < 2; ++ks) {
          bf16x8 ea = *(const bf16x8*)(el + ((rowe * 128 + ks * 64 + g * 16) ^ ((rowe & 7) << 4)));
          bf16x8 vb = *(const bf16x8*)(vl + ((rowv * 128 + ks * 64 + g * 16) ^ ((rowv & 7) << 4)));
          ctxacc[b][m][n] = MFMA(ea, vb, ctxacc[b][m][n]);
        }
      }
  }
  // finalize: ctx partial atomics; ctx layout [b][h][k_local][v]
  {
    float* ctxg = wsf + (B_CTXC / 4) + (blockIdx.x & 7) * 16384;
#pragma unroll
    for (int b = 0; b < 2; ++b)
#pragma unroll
      for (int m = 0; m < 2; ++m)
#pragma unroll
        for (int n = 0; n < 2; ++n)
#pragma unroll
          for (int r = 0; r < 4; ++r) {
            int klocal = m * 16 + g * 4 + r;
            int vcol = n * 16 + lo16;
            atomicAdd(&ctxg[((b * 8 + h) * 32 + klocal) * 32 + vcol], ctxacc[b][m][n][r]);
          }
  }
#pragma unroll
  for (int b = 0; b < 2; ++b)
#pragma unroll
    for (int i = 0; i < 8; ++i) atomicAdd(&Red[512 + b * 512 + (t & 63) * 8 + i], csum[b][i]);
  __syncthreads();
  atomicAdd(&wsf[(B_ZP / 4) + t], Red[t]);
  atomicAdd(&wsf[(B_COLS / 4) + t], Red[512 + t]);
  atomicAdd(&wsf[(B_COLS / 4) + 512 + t], Red[1024 + t]);
}

// ---------------- k2: ctx normalize (packed write), pool chain, constD, biasOut ----------------
__global__ __launch_bounds__(512) void k2_finalize(
    const float* __restrict__ pbn1, const float* __restrict__ pbn2,
    const float* __restrict__ dbn1, const float* __restrict__ d2,
    const float* __restrict__ ea_br, char* __restrict__ wsb) {
  __shared__ float HI[1024], H1[1024], H2l[512], VB[512], slot[4];
  const int t = threadIdx.x;
  float* wsf = (float*)wsb;
  unsigned short* u16 = (unsigned short*)wsb;
  for (int idx = t; idx < 16384; idx += 512) {
    float s = 0.f;
#pragma unroll
    for (int c = 0; c < 8; ++c) s += wsf[(B_CTXC / 4) + c * 16384 + idx];
    int v = idx & 31, row = idx >> 5;
    int b = row >> 8, kr = row & 255;
    int hh = kr >> 5, kh = kr & 31;
    float val = s / wsf[(B_ZP / 4) + b * 256 + kr];
    int m = v >> 4;
    int lane = (v & 15) + ((kh >> 3) << 4);
    int j = kh & 7;
    u16[(B_CTXT / 2) + (((b * 8 + hh) * 2 + m) << 9) + lane * 8 + j] = (unsigned short)f2bfu(val);
  }
  if (t < 4) slot[t] = 0.f;
  for (int idx = t; idx < 1024; idx += 512) HI[idx] = wsf[(B_COLS / 4) + idx] * (1.f / 32768.f);
  __syncthreads();
  {
    int o = t;
    float gg = pbn1[o], be = pbn1[512 + o], mn = pbn1[1024 + o], va = pbn1[1536 + o];
    float sc = gg * rsqrtf(va + 1e-5f), sh = be - mn * sc;
    for (int b = 0; b < 2; ++b) {
      float acc = 0.f;
      for (int c = 0; c < 512; ++c) acc = fmaf(wsf[(B_PW1T / 4) + c * 512 + o], HI[b * 512 + c], acc);
      H1[b * 512 + o] = acc * sc + sh;
    }
  }
  __syncthreads();
  if (t < 256) {
    int o = t;
    float gg = pbn2[o], be = pbn2[256 + o], mn = pbn2[512 + o], va = pbn2[768 + o];
    float sc = gg * rsqrtf(va + 1e-5f), sh = be - mn * sc;
    for (int b = 0; b < 2; ++b) {
      float acc = 0.f;
      for (int c = 0; c < 512; ++c) acc = fmaf(wsf[(B_PW2T / 4) + c * 256 + o], H1[b * 512 + c], acc);
      float vv = acc * sc + sh;
      H2l[b * 256 + o] = vv;
      wsf[(B_HIGH2 / 4) + b * 256 + o] = vv;
    }
  }
  __syncthreads();
  if (t < 256) {
    int o = t;
    float gg = dbn1[o], be = dbn1[256 + o], mn = dbn1[512 + o], va = dbn1[768 + o];
    float sd = gg * rsqrtf(va + 1e-5f), fd = be - mn * sd;
    for (int b = 0; b < 2; ++b) {
      float acc = 0.f;
      for (int v = 0; v < 256; ++v) acc = fmaf(wsf[(B_D1BT / 4) + v * 256 + o], H2l[b * 256 + v], acc);
      VB[b * 256 + o] = sd * acc + fd;
    }
  }
  __syncthreads();
  if (t < 256) {
    int o = t;
    for (int b = 0; b < 2; ++b)
      for (int j = 0; j < 2; ++j) atomicAdd(&slot[b * 2 + j], d2[j * 256 + o] * VB[b * 256 + o]);
    float cp = wsf[(B_CPP / 4) + o];
    for (int j = 0; j < 2; ++j) {
      float w = wsf[(B_WDD / 4) + j * 256 + o] * cp;
      atomicAdd(&slot[0 + j], w);
      atomicAdd(&slot[2 + j], w);
    }
  }
  __syncthreads();
  if (t < 4) wsf[(B_CONSTD / 4) + t] = slot[t];
  {
    int o = t;
    float bb = 0.5f * ea_br[o];
    if (o >= 256) bb += 0.5f * wsf[(B_CPP / 4) + o - 256];
    wsf[(B_BIASO / 4) + o] = bb;
  }
}

// ---------------- k3: main fused per-position MFMA pass ----------------
__global__ __launch_bounds__(512, 2) void k3_main(
    const float* __restrict__ x, const float* __restrict__ y,
    const float* __restrict__ bq, const char* __restrict__ wsb,
    float* __restrict__ out) {
  __shared__ __align__(16) unsigned char Xl[65536];  // X staging; overlaid Q/attS slabs
  __shared__ float wgtl[64];
  const int t = threadIdx.x;
  const int wv_ = t >> 6, lo16 = t & 15, g = (t >> 4) & 3, l = t & 63;
  const int pt = wv_ & 3, hf = wv_ >> 2;
  const int p0 = pt * 16;
  const int n0 = blockIdx.x * 64;
  const char* Wbig = wsb + B_WBIG;
  const char* WRp = wsb + B_WR;
  const char* CTXT = wsb + B_CTXT;
  const float* wsf = (const float*)wsb;
  unsigned char* Qslab = Xl + pt * 8192;

  f32x4 macc[16];  // hf==0: attS accumulators; hf==1: 0.25*(L0+L1)
#pragma unroll
  for (int i = 0; i < 16; ++i) macc[i] = (f32x4){0.f, 0.f, 0.f, 0.f};
  float wg0 = 0.f, wg1 = 0.f;

#pragma unroll
  for (int b = 0; b < 2; ++b) {
    const float* src = b ? y : x;
    __syncthreads();  // (A) previous Qslab reads done
    for (int r = 0; r < 8; ++r) {
      int chunk = r * 512 + t;
      int prow = chunk >> 6, j = chunk & 63;
      const float* gp = src + (size_t)(n0 + prow) * 512 + j * 8;
      float4 u0 = *(const float4*)gp;
      float4 u1 = *(const float4*)(gp + 4);
      uint4 pk;
      pk.x = pack2(u0.x, u0.y); pk.y = pack2(u0.z, u0.w);
      pk.z = pack2(u1.x, u1.y); pk.w = pack2(u1.z, u1.w);
      int byte = (prow * 1024 + j * 16) ^ ((prow & 7) << 4);
      *(uint4*)(Xl + byte) = pk;
    }
    __syncthreads();  // (B)
    bf16x8 bx[16];
    {
      int rowX = p0 + lo16;
      int base = rowX * 1024 + g * 16;
      int swz = (rowX & 7) << 4;
#pragma unroll
      for (int ks = 0; ks < 16; ++ks) bx[ks] = *(const bf16x8*)(Xl + ((base + ks * 64) ^ swz));
    }
    __syncthreads();  // (B2) Xl dead; Qslab overlay writes allowed
#pragma unroll
    for (int tp = 0; tp < 8; ++tp) {
      int t0 = hf * 16 + tp * 2;
      f32x4 a0 = {0.f, 0.f, 0.f, 0.f}, a1 = {0.f, 0.f, 0.f, 0.f};
      const char* ap = Wbig + t0 * 16384 + l * 16;
#pragma unroll
      for (int ks = 0; ks < 16; ++ks) {
        bf16x8 af0 = *(const bf16x8*)(ap + ks * 1024);
        bf16x8 af1 = *(const bf16x8*)(ap + 16384 + ks * 1024);
        a0 = MFMA(af0, bx[ks], a0);
        a1 = MFMA(af1, bx[ks], a1);
      }
      int t1 = t0 + 1;
      if (hf == 0) {  // Q pair = head tp: bias + softmax over 32 head-channels
        int hh = tp;
        float q[8], e[8];
        float mx = -1e30f;
#pragma unroll
        for (int r = 0; r < 4; ++r) {
          q[r] = a0[r] + bq[hh * 32 + g * 4 + r];
          q[4 + r] = a1[r] + bq[hh * 32 + 16 + g * 4 + r];
          mx = fmaxf(mx, fmaxf(q[r], q[4 + r]));
        }
        mx = fmaxf(mx, __shfl_xor(mx, 16, 64));
        mx = fmaxf(mx, __shfl_xor(mx, 32, 64));
        float sm = 0.f;
#pragma unroll
        for (int r = 0; r < 8; ++r) { e[r] = __expf(q[r] - mx); sm += e[r]; }
        sm += __shfl_xor(sm, 16, 64);
        sm += __shfl_xor(sm, 32, 64);
        float inv = 1.f / sm;
        uint2 w0, w1;
        w0.x = pack2(e[0] * inv, e[1] * inv); w0.y = pack2(e[2] * inv, e[3] * inv);
        w1.x = pack2(e[4] * inv, e[5] * inv); w1.y = pack2(e[6] * inv, e[7] * inv);
        int base_q = lo16 * 512 + hh * 64 + g * 8;
        int swzq = (lo16 & 7) << 4;
        *(uint2*)(Qslab + (base_q ^ swzq)) = w0;
        *(uint2*)(Qslab + ((base_q + 32) ^ swzq)) = w1;
      } else {  // L tiles
        macc[tp * 2] += 0.25f * a0;
        macc[tp * 2 + 1] += 0.25f * a1;
      }
    }
    if (hf == 1) {  // delta tile (rows 512..527 = packed tile 32)
      f32x4 ad = {0.f, 0.f, 0.f, 0.f};
      const char* ap = Wbig + 32 * 16384 + l * 16;
#pragma unroll
      for (int ks = 0; ks < 16; ++ks) {
        bf16x8 af = *(const bf16x8*)(ap + ks * 1024);
        ad = MFMA(af, bx[ks], ad);
      }
      if (g == 0) {
        float d0 = ad[0] + wsf[(B_CONSTD / 4) + b * 2 + 0];
        float d1 = ad[1] + wsf[(B_CONSTD / 4) + b * 2 + 1];
        int pos = n0 + p0 + lo16;
        float gx = -1.f + 2.f * (float)pos / 32767.f + d0;
        float gy = -1.f + d1;
        float ix = gx * 0.5f, iy = gy * 0.5f;
        float wx = fminf(fmaxf(1.f - fabsf(ix), 0.f), 1.f);
        float wy = fminf(fmaxf(1.f - fabsf(iy), 0.f), 1.f);
        wgtl[p0 + lo16] = wx * wy;
      }
    } else {  // att: per-head mfma(ctx_packed, Q)
      int swzq = (lo16 & 7) << 4;
#pragma unroll
      for (int hh = 0; hh < 8; ++hh) {
        bf16x8 qf = *(const bf16x8*)(Qslab + ((lo16 * 512 + hh * 64 + g * 16) ^ swzq));
        const char* cp = CTXT + (b * 8 + hh) * 2048 + l * 16;
        bf16x8 c0 = *(const bf16x8*)(cp);
        bf16x8 c1 = *(const bf16x8*)(cp + 1024);
        macc[hh * 2] = MFMA(c0, qf, macc[hh * 2]);
        macc[hh * 2 + 1] = MFMA(c1, qf, macc[hh * 2 + 1]);
      }
    }
    __syncthreads();  // (C) wgtl ready
    if (hf == 0) {
      float w = wgtl[p0 + lo16];
      if (b == 0) wg0 = w; else wg1 = w;
    }
  }
  // attS (hf==0) -> LDS (reuse Qslab)
  if (hf == 0) {
    int swzq = (lo16 & 7) << 4;
#pragma unroll
    for (int hh = 0; hh < 8; ++hh)
#pragma unroll
      for (int m = 0; m < 2; ++m) {
        f32x4 v = macc[hh * 2 + m];
        uint2 w;
        w.x = pack2(v[0], v[1]); w.y = pack2(v[2], v[3]);
        int byte = (lo16 * 512 + hh * 64 + m * 32 + g * 8) ^ swzq;
        *(uint2*)(Qslab + byte) = w;
      }
  }
  __syncthreads();  // (D)
  bf16x8 br8[8];
  {
    int base = lo16 * 512 + g * 16;
    int swzq = (lo16 & 7) << 4;
#pragma unroll
    for (int ks = 0; ks < 8; ++ks) br8[ks] = *(const bf16x8*)(Qslab + ((base + ks * 64) ^ swzq));
  }
  const float* bo = wsf + (B_BIASO / 4);
  const size_t rowaddr = (size_t)(n0 + p0 + lo16) * 512;
#pragma unroll
  for (int tp = 0; tp < 8; ++tp) {
    int lt0 = tp * 2, lt1 = lt0 + 1;
    int ch0 = hf * 256 + lt0 * 16, ch1 = ch0 + 16;
    int T0 = hf * 16 + lt0;  // WR tile indices
    f32x4 r0 = {0.f, 0.f, 0.f, 0.f}, r1 = {0.f, 0.f, 0.f, 0.f};
    const char* ap = WRp + T0 * 8192 + l * 16;
#pragma unroll
    for (int ks = 0; ks < 8; ++ks) {
      bf16x8 a0 = *(const bf16x8*)(ap + ks * 1024);
      bf16x8 a1 = *(const bf16x8*)(ap + 8192 + ks * 1024);
      r0 = MFMA(a0, br8[ks], r0);
      r1 = MFMA(a1, br8[ks], r1);
    }
#pragma unroll
    for (int half = 0; half < 2; ++half) {
      int lt = half ? lt1 : lt0;
      int cb = (half ? ch1 : ch0) + g * 4;
      f32x4 rr = half ? r1 : r0;
      f32x4 xr = *(const f32x4*)(x + rowaddr + cb);
      f32x4 yr = *(const f32x4*)(y + rowaddr + cb);
      f32x4 bb = *(const f32x4*)(bo + cb);
      f32x4 extra;
      if (hf == 0) {
        f32x4 h20 = *(const f32x4*)(wsf + (B_HIGH2 / 4) + cb);
        f32x4 h21 = *(const f32x4*)(wsf + (B_HIGH2 / 4) + 256 + cb);
        extra = (0.25f * wg0) * h20 + (0.25f * wg1) * h21;
      } else {
        extra = macc[lt];
      }
      f32x4 vout = extra + 0.25f * rr + 0.25f * (xr + yr) + bb;
      *(f32x4*)(out + rowaddr + cb) = vout;
    }
  }
}

extern "C" void kernel_launch(void* const* d_in, const int* in_sizes, int n_in,
                              void* d_out, int out_size, void* d_ws, size_t ws_size,
                              hipStream_t stream) {
  const float* x = (const float*)d_in[0];
  const float* y = (const float*)d_in[1];
  const float* ea_wk = (const float*)d_in[2];
  const float* ea_bk = (const float*)d_in[3];
  const float* ea_wq = (const float*)d_in[4];
  const float* ea_bq = (const float*)d_in[5];
  const float* ea_wv = (const float*)d_in[6];
  const float* ea_bv = (const float*)d_in[7];
  const float* ea_wr = (const float*)d_in[8];
  const float* ea_br = (const float*)d_in[9];
  const float* pool_w1 = (const float*)d_in[10];
  const float* pool_bn1 = (const float*)d_in[11];
  const float* pool_w2 = (const float*)d_in[12];
  const float* pool_bn2 = (const float*)d_in[13];
  const float* adapt_w1 = (const float*)d_in[14];
  const float* adapt_bn1 = (const float*)d_in[15];
  const float* adapt_w2 = (const float*)d_in[16];
  const float* adapt_bn2 = (const float*)d_in[17];
  const float* delta_w1 = (const float*)d_in[18];
  const float* delta_bn1 = (const float*)d_in[19];
  const float* delta_w2 = (const float*)d_in[20];
  char* ws = (char*)d_ws;
  float* out = (float*)d_out;

  hipMemsetAsync(ws, 0, 530432, stream);  // ctx copies + Z + colsum
  kW1<<<256, 512, 0, stream>>>(adapt_w1, adapt_bn1, adapt_w2, adapt_bn2, ws);
  kW2<<<1, 512, 0, stream>>>(delta_w1, delta_bn1, delta_w2, ws);
  kPack<<<4384, 256, 0, stream>>>(ea_wq, ea_wk, ea_wv, ea_wr, pool_w1, pool_w2, delta_w1, ws);
  k1_reduce<<<512, 512, 0, stream>>>(x, y, ea_bk, ea_bv, ws);
  k2_finalize<<<1, 512, 0, stream>>>(pool_bn1, pool_bn2, delta_bn1, delta_w2, ea_br, ws);
  k3_main<<<512, 512, 0, stream>>>(x, y, ea_bq, ws, out);
}

// Round 6
// 870.495 us; speedup vs baseline: 3.7530x; 1.0897x over previous
//
#include <hip/hip_runtime.h>
#include <math.h>

// ---------------- ws byte offsets ----------------
#define B_CTXC   0          // single summed ctx [2][8][32][32] f32 = 65536 B
#define B_ZP     524288     // [2][256] f32
#define B_COLS   526336     // [2][512] f32
#define B_HIGH2  530432     // [2][256] f32
#define B_CONSTD 532480     // [2][2] f32 (+pad)
#define B_BIASO  532544     // [512] f32
#define B_CPP    534592     // [256] f32 (c'')
#define B_CTXT   535616     // [2][8] x 2 tiles x 1KB bf16, fragment-linear
#define B_WDD    568384     // [2][256] f32
#define B_WDX    570432     // [2][512] f32
#define B_WL     574528     // [256][512] f32 (W_L'')
#define B_WBIG   1098816    // 33 tiles x 16KB bf16, fragment-linear
#define B_WKV    1639488    // 32 tiles x 16KB bf16, fragment-linear
#define B_WR     2163776    // 32 tiles x 8KB bf16, fragment-linear
#define B_PW1T   2425920    // [512][512] f32 transposed
#define B_PW2T   3474496    // [512][256] f32 transposed
#define B_D1BT   3998784    // [256][256] f32 transposed
// d_out scratch (before k3 overwrites): [512][8192] u32 ctx partials at float-
// offset 0, [512][1536] f32 red partials at float-offset 4194304.

typedef __attribute__((ext_vector_type(8))) short bf16x8;
typedef __attribute__((ext_vector_type(4))) float f32x4;

#define MFMA(a, b, c) __builtin_amdgcn_mfma_f32_16x16x32_bf16(a, b, c, 0, 0, 0)

__device__ inline unsigned f2bfu(float f) {
  unsigned u = __float_as_uint(f);
  return (u + 0x7FFFu + ((u >> 16) & 1u)) >> 16;
}
__device__ inline unsigned pack2(float a, float b) { return f2bfu(a) | (f2bfu(b) << 16); }

// ---------------- kW1: W_L'' (fp32) + c'' ----------------
__global__ __launch_bounds__(512) void kW1(
    const float* __restrict__ a1, const float* __restrict__ abn1,
    const float* __restrict__ a2, const float* __restrict__ abn2,
    char* __restrict__ wsb) {
  __shared__ float S1[512], F1[512], redu[512];
  const int t = threadIdx.x, o = blockIdx.x;
  float* wsf = (float*)wsb;
  {
    float gg = abn1[t], be = abn1[512 + t], mn = abn1[1024 + t], va = abn1[1536 + t];
    float s = gg * rsqrtf(va + 1e-5f);
    S1[t] = s; F1[t] = be - mn * s;
  }
  float g2 = abn2[o], be2 = abn2[256 + o], mn2 = abn2[512 + o], va2 = abn2[768 + o];
  float s2 = g2 * rsqrtf(va2 + 1e-5f);
  float f2v = be2 - mn2 * s2;
  __syncthreads();
  float acc = 0.f;
  const float* a2r = a2 + o * 512;
  for (int m = 0; m < 512; ++m) acc = fmaf(a2r[m] * S1[m], a1[m * 512 + t], acc);
  wsf[(B_WL / 4) + o * 512 + t] = s2 * acc;
  redu[t] = a2r[t] * F1[t];
  __syncthreads();
  for (int sft = 256; sft >= 1; sft >>= 1) {
    if (t < sft) redu[t] += redu[t + sft];
    __syncthreads();
  }
  if (t == 0) wsf[(B_CPP / 4) + o] = s2 * redu[0] + f2v;
}

// ---------------- kW2: W_dd, W_dx ----------------
__global__ __launch_bounds__(512) void kW2(
    const float* __restrict__ d1, const float* __restrict__ dbn1,
    const float* __restrict__ d2, char* __restrict__ wsb) {
  __shared__ float SD[256], WDDl[512];
  const int t = threadIdx.x;
  float* wsf = (float*)wsb;
  if (t < 256) {
    float gg = dbn1[t], va = dbn1[768 + t];
    SD[t] = gg * rsqrtf(va + 1e-5f);
  }
  __syncthreads();
  {
    int j = t >> 8, v = t & 255;
    float acc = 0.f;
    for (int o = 0; o < 256; ++o) acc = fmaf(d2[j * 256 + o] * SD[o], d1[o * 512 + v], acc);
    WDDl[t] = acc;
    wsf[(B_WDD / 4) + t] = acc;
  }
  __syncthreads();
  {
    int c = t;
    float acc0 = 0.f, acc1 = 0.f;
    for (int v = 0; v < 256; ++v) {
      float wl = wsf[(B_WL / 4) + v * 512 + c];
      acc0 = fmaf(WDDl[v], wl, acc0);
      acc1 = fmaf(WDDl[256 + v], wl, acc1);
    }
    wsf[(B_WDX / 4) + c] = acc0;
    wsf[(B_WDX / 4) + 512 + c] = acc1;
  }
}

// ---------------- kPack: fragment-linear bf16 packs + fp32 transposes ----------------
__global__ __launch_bounds__(256) void kPack(
    const float* __restrict__ wq, const float* __restrict__ wk, const float* __restrict__ wv,
    const float* __restrict__ wr, const float* __restrict__ pw1, const float* __restrict__ pw2,
    const float* __restrict__ d1, char* __restrict__ wsb) {
  int i = blockIdx.x * 256 + threadIdx.x;
  float* wsf = (float*)wsb;
  unsigned short* u16 = (unsigned short*)wsb;
  if (i < 270336) {  // Wbig: 33 tiles, K=512 (ks 0..15)
    int T = i >> 13, r = i & 8191;
    int ks = r >> 9, l = (r >> 3) & 63, j = r & 7;
    int row = T * 16 + (l & 15);
    int col = ks * 32 + (l >> 4) * 8 + j;
    float v;
    if (row < 256) v = wq[row * 512 + col];
    else if (row < 512) v = wsf[(B_WL / 4) + (row - 256) * 512 + col];
    else if (row < 514) v = wsf[(B_WDX / 4) + (row - 512) * 512 + col];
    else v = 0.f;
    u16[(B_WBIG / 2) + i] = (unsigned short)f2bfu(v);
    return;
  }
  i -= 270336;
  if (i < 262144) {  // Wkv: 32 tiles, K=512
    int T = i >> 13, r = i & 8191;
    int ks = r >> 9, l = (r >> 3) & 63, j = r & 7;
    int row = T * 16 + (l & 15);
    int col = ks * 32 + (l >> 4) * 8 + j;
    float v = row < 256 ? wk[row * 512 + col] : wv[(row - 256) * 512 + col];
    u16[(B_WKV / 2) + i] = (unsigned short)f2bfu(v);
    return;
  }
  i -= 262144;
  if (i < 131072) {  // WR: 32 tiles, K=256 (ks 0..7)
    int T = i >> 12, r = i & 4095;
    int ks = r >> 9, l = (r >> 3) & 63, j = r & 7;
    int row = T * 16 + (l & 15);
    int col = ks * 32 + (l >> 4) * 8 + j;
    u16[(B_WR / 2) + i] = (unsigned short)f2bfu(wr[row * 256 + col]);
    return;
  }
  i -= 131072;
  if (i < 262144) { int o = i >> 9, c = i & 511; wsf[(B_PW1T / 4) + c * 512 + o] = pw1[i]; return; }
  i -= 262144;
  if (i < 131072) { int o = i >> 9, c = i & 511; wsf[(B_PW2T / 4) + c * 256 + o] = pw2[i]; return; }
  i -= 131072;
  if (i < 65536) { int o = i >> 8, v = i & 255; wsf[(B_D1BT / 4) + v * 256 + o] = d1[o * 512 + 256 + v]; }
}

// ---------------- k1: keys/values MFMA + ctx/Z/colsum partials (NO atomics) ----------------
__global__ __launch_bounds__(512, 1) void k1_reduce(
    const float* __restrict__ x, const float* __restrict__ y,
    const float* __restrict__ bk, const float* __restrict__ bv,
    const char* __restrict__ wsb, float* __restrict__ outp) {
  __shared__ __align__(16) unsigned char Xl[65536];  // X staging; overlaid: el=Xl, vl=Xl+32K
  __shared__ float Red[1536];  // [0..511]=Z, [512..1535]=colsum
  unsigned char* el = Xl;
  unsigned char* vl = Xl + 32768;
  const int t = threadIdx.x;
  const int wv_ = t >> 6, lo16 = t & 15, g = (t >> 4) & 3, l = t & 63;
  const int pt = wv_ & 3, hf = wv_ >> 2;
  const int p0 = pt * 16;
  const char* Wkv = wsb + B_WKV;

  for (int i = t; i < 1536; i += 512) Red[i] = 0.f;
  float csum[2][8];
#pragma unroll
  for (int b2 = 0; b2 < 2; ++b2)
#pragma unroll
    for (int i = 0; i < 8; ++i) csum[b2][i] = 0.f;
  f32x4 ctxacc[2][2][2];
#pragma unroll
  for (int b2 = 0; b2 < 2; ++b2)
#pragma unroll
    for (int m = 0; m < 2; ++m)
#pragma unroll
      for (int n = 0; n < 2; ++n) ctxacc[b2][m][n] = (f32x4){0.f, 0.f, 0.f, 0.f};
  const int h = wv_;  // head for ctx phase (0..7)
  const int n0 = blockIdx.x * 64;

#pragma unroll
  for (int b = 0; b < 2; ++b) {
    const float* src = b ? y : x;
    __syncthreads();  // (A) previous el/vl reads done
    for (int r = 0; r < 8; ++r) {
      int chunk = r * 512 + t;
      int prow = chunk >> 6, j = chunk & 63;
      const float* gp = src + (size_t)(n0 + prow) * 512 + j * 8;
      float4 u0 = *(const float4*)gp;
      float4 u1 = *(const float4*)(gp + 4);
      csum[b][0] += u0.x; csum[b][1] += u0.y; csum[b][2] += u0.z; csum[b][3] += u0.w;
      csum[b][4] += u1.x; csum[b][5] += u1.y; csum[b][6] += u1.z; csum[b][7] += u1.w;
      uint4 pk;
      pk.x = pack2(u0.x, u0.y); pk.y = pack2(u0.z, u0.w);
      pk.z = pack2(u1.x, u1.y); pk.w = pack2(u1.z, u1.w);
      int byte = (prow * 1024 + j * 16) ^ ((prow & 7) << 4);
      *(uint4*)(Xl + byte) = pk;
    }
    __syncthreads();  // (B)
    bf16x8 bx[16];
    {
      int rowX = p0 + lo16;
      int base = rowX * 1024 + g * 16;
      int swz = (rowX & 7) << 4;
#pragma unroll
      for (int ks = 0; ks < 16; ++ks) bx[ks] = *(const bf16x8*)(Xl + ((base + ks * 64) ^ swz));
    }
    __syncthreads();  // (B2) Xl dead; el/vl overlay writes allowed
#pragma unroll
    for (int tp = 0; tp < 8; ++tp) {
      int t0 = hf * 16 + tp * 2;
      f32x4 a0 = {0.f, 0.f, 0.f, 0.f}, a1 = {0.f, 0.f, 0.f, 0.f};
      const char* ap = Wkv + t0 * 16384 + l * 16;
#pragma unroll
      for (int ks = 0; ks < 16; ++ks) {
        bf16x8 af0 = *(const bf16x8*)(ap + ks * 1024);
        bf16x8 af1 = *(const bf16x8*)(ap + 16384 + ks * 1024);
        a0 = MFMA(af0, bx[ks], a0);
        a1 = MFMA(af1, bx[ks], a1);
      }
      int t1 = t0 + 1;
      int pp = p0 + lo16;
      if (hf == 0) {  // keys -> e, Z, el
        float e0[4], e1[4];
#pragma unroll
        for (int r = 0; r < 4; ++r) {
          e0[r] = __expf(a0[r] + bk[t0 * 16 + g * 4 + r]);
          e1[r] = __expf(a1[r] + bk[t1 * 16 + g * 4 + r]);
        }
#pragma unroll
        for (int r = 0; r < 4; ++r) {
          float v0 = e0[r], v1 = e1[r];
          for (int m = 8; m >= 1; m >>= 1) {
            v0 += __shfl_xor(v0, m, 16);
            v1 += __shfl_xor(v1, m, 16);
          }
          if (lo16 == 0) {
            atomicAdd(&Red[b * 256 + t0 * 16 + g * 4 + r], v0);
            atomicAdd(&Red[b * 256 + t1 * 16 + g * 4 + r], v1);
          }
        }
#pragma unroll
        for (int r = 0; r < 4; ++r) {
          int row0 = t0 * 16 + g * 4 + r;
          int row1 = t1 * 16 + g * 4 + r;
          *(unsigned short*)(el + ((row0 * 128 + pp * 2) ^ ((row0 & 7) << 4))) = (unsigned short)f2bfu(e0[r]);
          *(unsigned short*)(el + ((row1 * 128 + pp * 2) ^ ((row1 & 7) << 4))) = (unsigned short)f2bfu(e1[r]);
        }
      } else {  // values -> vl
#pragma unroll
        for (int r = 0; r < 4; ++r) {
          int row0 = (t0 - 16) * 16 + g * 4 + r;
          int row1 = (t1 - 16) * 16 + g * 4 + r;
          *(unsigned short*)(vl + ((row0 * 128 + pp * 2) ^ ((row0 & 7) << 4))) = (unsigned short)f2bfu(a0[r] + bv[row0]);
          *(unsigned short*)(vl + ((row1 * 128 + pp * 2) ^ ((row1 & 7) << 4))) = (unsigned short)f2bfu(a1[r] + bv[row1]);
        }
      }
    }
    __syncthreads();  // (C) el, vl ready
#pragma unroll
    for (int m = 0; m < 2; ++m)
#pragma unroll
      for (int n = 0; n < 2; ++n) {
        int rowe = h * 32 + m * 16 + lo16;
        int rowv = h * 32 + n * 16 + lo16;
#pragma unroll
        for (int ks = 0; ks < 2; ++ks) {
          bf16x8 ea = *(const bf16x8*)(el + ((rowe * 128 + ks * 64 + g * 16) ^ ((rowe & 7) << 4)));
          bf16x8 vb = *(const bf16x8*)(vl + ((rowv * 128 + ks * 64 + g * 16) ^ ((rowv & 7) << 4)));
          ctxacc[b][m][n] = MFMA(ea, vb, ctxacc[b][m][n]);
        }
      }
  }
  __syncthreads();  // Red complete
  // plain-store partials into d_out scratch (fully coalesced, no atomics)
  {
    unsigned* ctxp = (unsigned*)outp + (size_t)blockIdx.x * 8192;
#pragma unroll
    for (int b = 0; b < 2; ++b)
#pragma unroll
      for (int m = 0; m < 2; ++m)
#pragma unroll
        for (int r = 0; r < 4; ++r)
          ctxp[((b * 2 + m) * 4 + r) * 512 + t] = pack2(ctxacc[b][m][0][r], ctxacc[b][m][1][r]);
    float* redp = outp + 4194304 + blockIdx.x * 1536;
    for (int i = t; i < 1536; i += 512) redp[i] = Red[i];
  }
}

// ---------------- k1b: sum the 512 partial copies ----------------
__global__ __launch_bounds__(512) void k1b(const float* __restrict__ outp, char* __restrict__ wsb) {
  const int t = threadIdx.x;
  float* wsf = (float*)wsb;
  if (blockIdx.x < 16) {
    int slot = blockIdx.x * 512 + t;
    const unsigned* p = (const unsigned*)outp;
    float s0 = 0.f, s1 = 0.f;
    for (int c = 0; c < 512; ++c) {
      unsigned w = p[c * 8192 + slot];
      s0 += __uint_as_float(w << 16);
      s1 += __uint_as_float(w & 0xffff0000u);
    }
    int t_ = slot & 511, bmr = slot >> 9;
    int r = bmr & 3, m = (bmr >> 2) & 1, b = bmr >> 3;
    int h = t_ >> 6, g = (t_ >> 4) & 3, lo16 = t_ & 15;
    int klocal = m * 16 + g * 4 + r;
    int base = ((b * 8 + h) * 32 + klocal) * 32;
    wsf[(B_CTXC / 4) + base + lo16] = s0;
    wsf[(B_CTXC / 4) + base + 16 + lo16] = s1;
  } else {
    const float* rp = outp + 4194304;
    for (int j = t; j < 1536; j += 512) {
      float s = 0.f;
      for (int c = 0; c < 512; ++c) s += rp[c * 1536 + j];
      if (j < 512) wsf[(B_ZP / 4) + j] = s;
      else wsf[(B_COLS / 4) + (j - 512)] = s;
    }
  }
}

// ---------------- k2: ctx normalize (packed write), pool chain, constD, biasOut ----------------
__global__ __launch_bounds__(512) void k2_finalize(
    const float* __restrict__ pbn1, const float* __restrict__ pbn2,
    const float* __restrict__ dbn1, const float* __restrict__ d2,
    const float* __restrict__ ea_br, char* __restrict__ wsb) {
  __shared__ float HI[1024], H1[1024], H2l[512], VB[512], slot[4];
  const int t = threadIdx.x;
  float* wsf = (float*)wsb;
  unsigned short* u16 = (unsigned short*)wsb;
  for (int idx = t; idx < 16384; idx += 512) {
    float s = wsf[(B_CTXC / 4) + idx];
    int v = idx & 31, row = idx >> 5;
    int b = row >> 8, kr = row & 255;
    int hh = kr >> 5, kh = kr & 31;
    float val = s / wsf[(B_ZP / 4) + b * 256 + kr];
    int m = v >> 4;
    int lane = (v & 15) + ((kh >> 3) << 4);
    int j = kh & 7;
    u16[(B_CTXT / 2) + (((b * 8 + hh) * 2 + m) << 9) + lane * 8 + j] = (unsigned short)f2bfu(val);
  }
  if (t < 4) slot[t] = 0.f;
  for (int idx = t; idx < 1024; idx += 512) HI[idx] = wsf[(B_COLS / 4) + idx] * (1.f / 32768.f);
  __syncthreads();
  {
    int o = t;
    float gg = pbn1[o], be = pbn1[512 + o], mn = pbn1[1024 + o], va = pbn1[1536 + o];
    float sc = gg * rsqrtf(va + 1e-5f), sh = be - mn * sc;
    for (int b = 0; b < 2; ++b) {
      float acc = 0.f;
      for (int c = 0; c < 512; ++c) acc = fmaf(wsf[(B_PW1T / 4) + c * 512 + o], HI[b * 512 + c], acc);
      H1[b * 512 + o] = acc * sc + sh;
    }
  }
  __syncthreads();
  if (t < 256) {
    int o = t;
    float gg = pbn2[o], be = pbn2[256 + o], mn = pbn2[512 + o], va = pbn2[768 + o];
    float sc = gg * rsqrtf(va + 1e-5f), sh = be - mn * sc;
    for (int b = 0; b < 2; ++b) {
      float acc = 0.f;
      for (int c = 0; c < 512; ++c) acc = fmaf(wsf[(B_PW2T / 4) + c * 256 + o], H1[b * 512 + c], acc);
      float vv = acc * sc + sh;
      H2l[b * 256 + o] = vv;
      wsf[(B_HIGH2 / 4) + b * 256 + o] = vv;
    }
  }
  __syncthreads();
  if (t < 256) {
    int o = t;
    float gg = dbn1[o], be = dbn1[256 + o], mn = dbn1[512 + o], va = dbn1[768 + o];
    float sd = gg * rsqrtf(va + 1e-5f), fd = be - mn * sd;
    for (int b = 0; b < 2; ++b) {
      float acc = 0.f;
      for (int v = 0; v < 256; ++v) acc = fmaf(wsf[(B_D1BT / 4) + v * 256 + o], H2l[b * 256 + v], acc);
      VB[b * 256 + o] = sd * acc + fd;
    }
  }
  __syncthreads();
  if (t < 256) {
    int o = t;
    for (int b = 0; b < 2; ++b)
      for (int j = 0; j < 2; ++j) atomicAdd(&slot[b * 2 + j], d2[j * 256 + o] * VB[b * 256 + o]);
    float cp = wsf[(B_CPP / 4) + o];
    for (int j = 0; j < 2; ++j) {
      float w = wsf[(B_WDD / 4) + j * 256 + o] * cp;
      atomicAdd(&slot[0 + j], w);
      atomicAdd(&slot[2 + j], w);
    }
  }
  __syncthreads();
  if (t < 4) wsf[(B_CONSTD / 4) + t] = slot[t];
  {
    int o = t;
    float bb = 0.5f * ea_br[o];
    if (o >= 256) bb += 0.5f * wsf[(B_CPP / 4) + o - 256];
    wsf[(B_BIASO / 4) + o] = bb;
  }
}

// ---------------- k3: main fused per-position MFMA pass ----------------
__global__ __launch_bounds__(512, 1) void k3_main(
    const float* __restrict__ x, const float* __restrict__ y,
    const float* __restrict__ bq, const char* __restrict__ wsb,
    float* __restrict__ out) {
  __shared__ __align__(16) unsigned char Xl[65536];  // X staging; overlaid Q/attS slabs
  __shared__ float wgtl[64];
  const int t = threadIdx.x;
  const int wv_ = t >> 6, lo16 = t & 15, g = (t >> 4) & 3, l = t & 63;
  const int pt = wv_ & 3, hf = wv_ >> 2;
  const int p0 = pt * 16;
  const int n0 = blockIdx.x * 64;
  const char* Wbig = wsb + B_WBIG;
  const char* WRp = wsb + B_WR;
  const char* CTXT = wsb + B_CTXT;
  const float* wsf = (const float*)wsb;
  unsigned char* Qslab = Xl + pt * 8192;

  f32x4 macc[16];  // hf==0: attS accumulators; hf==1: 0.25*(L0+L1)
#pragma unroll
  for (int i = 0; i < 16; ++i) macc[i] = (f32x4){0.f, 0.f, 0.f, 0.f};
  float wg0 = 0.f, wg1 = 0.f;

#pragma unroll
  for (int b = 0; b < 2; ++b) {
    const float* src = b ? y : x;
    __syncthreads();  // (A) previous Qslab reads done
    for (int r = 0; r < 8; ++r) {
      int chunk = r * 512 + t;
      int prow = chunk >> 6, j = chunk & 63;
      const float* gp = src + (size_t)(n0 + prow) * 512 + j * 8;
      float4 u0 = *(const float4*)gp;
      float4 u1 = *(const float4*)(gp + 4);
      uint4 pk;
      pk.x = pack2(u0.x, u0.y); pk.y = pack2(u0.z, u0.w);
      pk.z = pack2(u1.x, u1.y); pk.w = pack2(u1.z, u1.w);
      int byte = (prow * 1024 + j * 16) ^ ((prow & 7) << 4);
      *(uint4*)(Xl + byte) = pk;
    }
    __syncthreads();  // (B)
    bf16x8 bx[16];
    {
      int rowX = p0 + lo16;
      int base = rowX * 1024 + g * 16;
      int swz = (rowX & 7) << 4;
#pragma unroll
      for (int ks = 0; ks < 16; ++ks) bx[ks] = *(const bf16x8*)(Xl + ((base + ks * 64) ^ swz));
    }
    __syncthreads();  // (B2) Xl dead; Qslab overlay writes allowed
#pragma unroll
    for (int tp = 0; tp < 8; ++tp) {
      int t0 = hf * 16 + tp * 2;
      f32x4 a0 = {0.f, 0.f, 0.f, 0.f}, a1 = {0.f, 0.f, 0.f, 0.f};
      const char* ap = Wbig + t0 * 16384 + l * 16;
#pragma unroll
      for (int ks = 0; ks < 16; ++ks) {
        bf16x8 af0 = *(const bf16x8*)(ap + ks * 1024);
        bf16x8 af1 = *(const bf16x8*)(ap + 16384 + ks * 1024);
        a0 = MFMA(af0, bx[ks], a0);
        a1 = MFMA(af1, bx[ks], a1);
      }
      int t1 = t0 + 1;
      if (hf == 0) {  // Q pair = head tp: bias + softmax over 32 head-channels
        int hh = tp;
        float q[8], e[8];
        float mx = -1e30f;
#pragma unroll
        for (int r = 0; r < 4; ++r) {
          q[r] = a0[r] + bq[hh * 32 + g * 4 + r];
          q[4 + r] = a1[r] + bq[hh * 32 + 16 + g * 4 + r];
          mx = fmaxf(mx, fmaxf(q[r], q[4 + r]));
        }
        mx = fmaxf(mx, __shfl_xor(mx, 16, 64));
        mx = fmaxf(mx, __shfl_xor(mx, 32, 64));
        float sm = 0.f;
#pragma unroll
        for (int r = 0; r < 8; ++r) { e[r] = __expf(q[r] - mx); sm += e[r]; }
        sm += __shfl_xor(sm, 16, 64);
        sm += __shfl_xor(sm, 32, 64);
        float inv = 1.f / sm;
        uint2 w0, w1;
        w0.x = pack2(e[0] * inv, e[1] * inv); w0.y = pack2(e[2] * inv, e[3] * inv);
        w1.x = pack2(e[4] * inv, e[5] * inv); w1.y = pack2(e[6] * inv, e[7] * inv);
        int base_q = lo16 * 512 + hh * 64 + g * 8;
        int swzq = (lo16 & 7) << 4;
        *(uint2*)(Qslab + (base_q ^ swzq)) = w0;
        *(uint2*)(Qslab + ((base_q + 32) ^ swzq)) = w1;
      } else {  // L tiles
        macc[tp * 2] += 0.25f * a0;
        macc[tp * 2 + 1] += 0.25f * a1;
      }
    }
    if (hf == 1) {  // delta tile (rows 512..527 = packed tile 32)
      f32x4 ad = {0.f, 0.f, 0.f, 0.f};
      const char* ap = Wbig + 32 * 16384 + l * 16;
#pragma unroll
      for (int ks = 0; ks < 16; ++ks) {
        bf16x8 af = *(const bf16x8*)(ap + ks * 1024);
        ad = MFMA(af, bx[ks], ad);
      }
      if (g == 0) {
        float d0 = ad[0] + wsf[(B_CONSTD / 4) + b * 2 + 0];
        float d1 = ad[1] + wsf[(B_CONSTD / 4) + b * 2 + 1];
        int pos = n0 + p0 + lo16;
        float gx = -1.f + 2.f * (float)pos / 32767.f + d0;
        float gy = -1.f + d1;
        float ix = gx * 0.5f, iy = gy * 0.5f;
        float wx = fminf(fmaxf(1.f - fabsf(ix), 0.f), 1.f);
        float wy = fminf(fmaxf(1.f - fabsf(iy), 0.f), 1.f);
        wgtl[p0 + lo16] = wx * wy;
      }
    } else {  // att: per-head mfma(ctx_packed, Q)
      int swzq = (lo16 & 7) << 4;
#pragma unroll
      for (int hh = 0; hh < 8; ++hh) {
        bf16x8 qf = *(const bf16x8*)(Qslab + ((lo16 * 512 + hh * 64 + g * 16) ^ swzq));
        const char* cp = CTXT + (b * 8 + hh) * 2048 + l * 16;
        bf16x8 c0 = *(const bf16x8*)(cp);
        bf16x8 c1 = *(const bf16x8*)(cp + 1024);
        macc[hh * 2] = MFMA(c0, qf, macc[hh * 2]);
        macc[hh * 2 + 1] = MFMA(c1, qf, macc[hh * 2 + 1]);
      }
    }
    __syncthreads();  // (C) wgtl ready
    if (hf == 0) {
      float w = wgtl[p0 + lo16];
      if (b == 0) wg0 = w; else wg1 = w;
    }
  }
  // attS (hf==0) -> LDS (reuse Qslab)
  if (hf == 0) {
    int swzq = (lo16 & 7) << 4;
#pragma unroll
    for (int hh = 0; hh < 8; ++hh)
#pragma unroll
      for (int m = 0; m < 2; ++m) {
        f32x4 v = macc[hh * 2 + m];
        uint2 w;
        w.x = pack2(v[0], v[1]); w.y = pack2(v[2], v[3]);
        int byte = (lo16 * 512 + hh * 64 + m * 32 + g * 8) ^ swzq;
        *(uint2*)(Qslab + byte) = w;
      }
  }
  __syncthreads();  // (D)
  bf16x8 br8[8];
  {
    int base = lo16 * 512 + g * 16;
    int swzq = (lo16 & 7) << 4;
#pragma unroll
    for (int ks = 0; ks < 8; ++ks) br8[ks] = *(const bf16x8*)(Qslab + ((base + ks * 64) ^ swzq));
  }
  const float* bo = wsf + (B_BIASO / 4);
  const size_t rowaddr = (size_t)(n0 + p0 + lo16) * 512;
#pragma unroll
  for (int tp = 0; tp < 8; ++tp) {
    int lt0 = tp * 2, lt1 = lt0 + 1;
    int ch0 = hf * 256 + lt0 * 16, ch1 = ch0 + 16;
    int T0 = hf * 16 + lt0;  // WR tile indices
    f32x4 r0 = {0.f, 0.f, 0.f, 0.f}, r1 = {0.f, 0.f, 0.f, 0.f};
    const char* ap = WRp + T0 * 8192 + l * 16;
#pragma unroll
    for (int ks = 0; ks < 8; ++ks) {
      bf16x8 a0 = *(const bf16x8*)(ap + ks * 1024);
      bf16x8 a1 = *(const bf16x8*)(ap + 8192 + ks * 1024);
      r0 = MFMA(a0, br8[ks], r0);
      r1 = MFMA(a1, br8[ks], r1);
    }
#pragma unroll
    for (int half = 0; half < 2; ++half) {
      int lt = half ? lt1 : lt0;
      int cb = (half ? ch1 : ch0) + g * 4;
      f32x4 rr = half ? r1 : r0;
      f32x4 xr = *(const f32x4*)(x + rowaddr + cb);
      f32x4 yr = *(const f32x4*)(y + rowaddr + cb);
      f32x4 bb = *(const f32x4*)(bo + cb);
      f32x4 extra;
      if (hf == 0) {
        f32x4 h20 = *(const f32x4*)(wsf + (B_HIGH2 / 4) + cb);
        f32x4 h21 = *(const f32x4*)(wsf + (B_HIGH2 / 4) + 256 + cb);
        extra = (0.25f * wg0) * h20 + (0.25f * wg1) * h21;
      } else {
        extra = macc[lt];
      }
      f32x4 vout = extra + 0.25f * rr + 0.25f * (xr + yr) + bb;
      *(f32x4*)(out + rowaddr + cb) = vout;
    }
  }
}

extern "C" void kernel_launch(void* const* d_in, const int* in_sizes, int n_in,
                              void* d_out, int out_size, void* d_ws, size_t ws_size,
                              hipStream_t stream) {
  const float* x = (const float*)d_in[0];
  const float* y = (const float*)d_in[1];
  const float* ea_wk = (const float*)d_in[2];
  const float* ea_bk = (const float*)d_in[3];
  const float* ea_wq = (const float*)d_in[4];
  const float* ea_bq = (const float*)d_in[5];
  const float* ea_wv = (const float*)d_in[6];
  const float* ea_bv = (const float*)d_in[7];
  const float* ea_wr = (const float*)d_in[8];
  const float* ea_br = (const float*)d_in[9];
  const float* pool_w1 = (const float*)d_in[10];
  const float* pool_bn1 = (const float*)d_in[11];
  const float* pool_w2 = (const float*)d_in[12];
  const float* pool_bn2 = (const float*)d_in[13];
  const float* adapt_w1 = (const float*)d_in[14];
  const float* adapt_bn1 = (const float*)d_in[15];
  const float* adapt_w2 = (const float*)d_in[16];
  const float* adapt_bn2 = (const float*)d_in[17];
  const float* delta_w1 = (const float*)d_in[18];
  const float* delta_bn1 = (const float*)d_in[19];
  const float* delta_w2 = (const float*)d_in[20];
  char* ws = (char*)d_ws;
  float* out = (float*)d_out;

  kW1<<<256, 512, 0, stream>>>(adapt_w1, adapt_bn1, adapt_w2, adapt_bn2, ws);
  kW2<<<1, 512, 0, stream>>>(delta_w1, delta_bn1, delta_w2, ws);
  kPack<<<4384, 256, 0, stream>>>(ea_wq, ea_wk, ea_wv, ea_wr, pool_w1, pool_w2, delta_w1, ws);
  k1_reduce<<<512, 512, 0, stream>>>(x, y, ea_bk, ea_bv, ws, out);
  k1b<<<17, 512, 0, stream>>>(out, ws);
  k2_finalize<<<1, 512, 0, stream>>>(pool_bn1, pool_bn2, delta_bn1, delta_w2, ea_br, ws);
  k3_main<<<512, 512, 0, stream>>>(x, y, ea_bq, ws, out);
}

// Round 7
// 829.541 us; speedup vs baseline: 3.9383x; 1.0494x over previous
//
#include <hip/hip_runtime.h>
#include <math.h>

// ---------------- ws byte offsets ----------------
#define B_CTXC   0          // single summed ctx [2][8][32][32] f32 = 65536 B
#define B_ZP     524288     // [2][256] f32
#define B_COLS   526336     // [2][512] f32
#define B_HIGH2  530432     // [2][256] f32
#define B_CONSTD 532480     // [2][2] f32 (+pad)
#define B_BIASO  532544     // [512] f32
#define B_CPP    534592     // [256] f32 (c'')
#define B_CTXT   535616     // [2][8] x 2 tiles x 1KB bf16, fragment-linear
#define B_WDD    568384     // [2][256] f32
#define B_WDX    570432     // [2][512] f32
#define B_WL     574528     // [256][512] f32 (W_L'')
#define B_WBIG   1098816    // 33 tiles x 16KB bf16, fragment-linear
#define B_WKV    1639488    // 32 tiles x 16KB bf16, fragment-linear
#define B_WR     2163776    // 32 tiles x 8KB bf16, fragment-linear
#define B_PW1T   2425920    // [512][512] f32 transposed
#define B_PW2T   3474496    // [512][256] f32 transposed
#define B_D1BT   3998784    // [256][256] f32 transposed
// d_out scratch (before k3 overwrites): [512][8192] u32 ctx partials at float-
// offset 0, [512][1536] f32 red partials at float-offset 4194304.

typedef __attribute__((ext_vector_type(8))) short bf16x8;
typedef __attribute__((ext_vector_type(4))) float f32x4;

#define MFMA(a, b, c) __builtin_amdgcn_mfma_f32_16x16x32_bf16(a, b, c, 0, 0, 0)

__device__ inline unsigned f2bfu(float f) {
  unsigned u = __float_as_uint(f);
  return (u + 0x7FFFu + ((u >> 16) & 1u)) >> 16;
}
__device__ inline unsigned pack2(float a, float b) { return f2bfu(a) | (f2bfu(b) << 16); }

// ---------------- kW1: W_L'' (fp32) + c'' ----------------
__global__ __launch_bounds__(512) void kW1(
    const float* __restrict__ a1, const float* __restrict__ abn1,
    const float* __restrict__ a2, const float* __restrict__ abn2,
    char* __restrict__ wsb) {
  __shared__ float S1[512], F1[512], redu[512];
  const int t = threadIdx.x, o = blockIdx.x;
  float* wsf = (float*)wsb;
  {
    float gg = abn1[t], be = abn1[512 + t], mn = abn1[1024 + t], va = abn1[1536 + t];
    float s = gg * rsqrtf(va + 1e-5f);
    S1[t] = s; F1[t] = be - mn * s;
  }
  float g2 = abn2[o], be2 = abn2[256 + o], mn2 = abn2[512 + o], va2 = abn2[768 + o];
  float s2 = g2 * rsqrtf(va2 + 1e-5f);
  float f2v = be2 - mn2 * s2;
  __syncthreads();
  float acc = 0.f;
  const float* a2r = a2 + o * 512;
  for (int m = 0; m < 512; ++m) acc = fmaf(a2r[m] * S1[m], a1[m * 512 + t], acc);
  wsf[(B_WL / 4) + o * 512 + t] = s2 * acc;
  redu[t] = a2r[t] * F1[t];
  __syncthreads();
  for (int sft = 256; sft >= 1; sft >>= 1) {
    if (t < sft) redu[t] += redu[t + sft];
    __syncthreads();
  }
  if (t == 0) wsf[(B_CPP / 4) + o] = s2 * redu[0] + f2v;
}

// ---------------- kW2: W_dd, W_dx ----------------
__global__ __launch_bounds__(512) void kW2(
    const float* __restrict__ d1, const float* __restrict__ dbn1,
    const float* __restrict__ d2, char* __restrict__ wsb) {
  __shared__ float SD[256], WDDl[512];
  const int t = threadIdx.x;
  float* wsf = (float*)wsb;
  if (t < 256) {
    float gg = dbn1[t], va = dbn1[768 + t];
    SD[t] = gg * rsqrtf(va + 1e-5f);
  }
  __syncthreads();
  {
    int j = t >> 8, v = t & 255;
    float acc = 0.f;
    for (int o = 0; o < 256; ++o) acc = fmaf(d2[j * 256 + o] * SD[o], d1[o * 512 + v], acc);
    WDDl[t] = acc;
    wsf[(B_WDD / 4) + t] = acc;
  }
  __syncthreads();
  {
    int c = t;
    float acc0 = 0.f, acc1 = 0.f;
    for (int v = 0; v < 256; ++v) {
      float wl = wsf[(B_WL / 4) + v * 512 + c];
      acc0 = fmaf(WDDl[v], wl, acc0);
      acc1 = fmaf(WDDl[256 + v], wl, acc1);
    }
    wsf[(B_WDX / 4) + c] = acc0;
    wsf[(B_WDX / 4) + 512 + c] = acc1;
  }
}

// ---------------- kPack: fragment-linear bf16 packs + fp32 transposes ----------------
__global__ __launch_bounds__(256) void kPack(
    const float* __restrict__ wq, const float* __restrict__ wk, const float* __restrict__ wv,
    const float* __restrict__ wr, const float* __restrict__ pw1, const float* __restrict__ pw2,
    const float* __restrict__ d1, char* __restrict__ wsb) {
  int i = blockIdx.x * 256 + threadIdx.x;
  float* wsf = (float*)wsb;
  unsigned short* u16 = (unsigned short*)wsb;
  if (i < 270336) {  // Wbig: 33 tiles, K=512 (ks 0..15)
    int T = i >> 13, r = i & 8191;
    int ks = r >> 9, l = (r >> 3) & 63, j = r & 7;
    int row = T * 16 + (l & 15);
    int col = ks * 32 + (l >> 4) * 8 + j;
    float v;
    if (row < 256) v = wq[row * 512 + col];
    else if (row < 512) v = wsf[(B_WL / 4) + (row - 256) * 512 + col];
    else if (row < 514) v = wsf[(B_WDX / 4) + (row - 512) * 512 + col];
    else v = 0.f;
    u16[(B_WBIG / 2) + i] = (unsigned short)f2bfu(v);
    return;
  }
  i -= 270336;
  if (i < 262144) {  // Wkv: 32 tiles, K=512
    int T = i >> 13, r = i & 8191;
    int ks = r >> 9, l = (r >> 3) & 63, j = r & 7;
    int row = T * 16 + (l & 15);
    int col = ks * 32 + (l >> 4) * 8 + j;
    float v = row < 256 ? wk[row * 512 + col] : wv[(row - 256) * 512 + col];
    u16[(B_WKV / 2) + i] = (unsigned short)f2bfu(v);
    return;
  }
  i -= 262144;
  if (i < 131072) {  // WR: 32 tiles, K=256 (ks 0..7)
    int T = i >> 12, r = i & 4095;
    int ks = r >> 9, l = (r >> 3) & 63, j = r & 7;
    int row = T * 16 + (l & 15);
    int col = ks * 32 + (l >> 4) * 8 + j;
    u16[(B_WR / 2) + i] = (unsigned short)f2bfu(wr[row * 256 + col]);
    return;
  }
  i -= 131072;
  if (i < 262144) { int o = i >> 9, c = i & 511; wsf[(B_PW1T / 4) + c * 512 + o] = pw1[i]; return; }
  i -= 262144;
  if (i < 131072) { int o = i >> 9, c = i & 511; wsf[(B_PW2T / 4) + c * 256 + o] = pw2[i]; return; }
  i -= 131072;
  if (i < 65536) { int o = i >> 8, v = i & 255; wsf[(B_D1BT / 4) + v * 256 + o] = d1[o * 512 + 256 + v]; }
}

// ---------------- k1: keys/values MFMA + ctx/Z/colsum partials ----------------
// B-fragments re-read from LDS per MFMA (no bx[16] preload -> no spills).
__global__ __launch_bounds__(512, 2) void k1_reduce(
    const float* __restrict__ x, const float* __restrict__ y,
    const float* __restrict__ bk, const float* __restrict__ bv,
    const char* __restrict__ wsb, float* __restrict__ outp) {
  __shared__ __align__(16) unsigned char Xl[65536];
  __shared__ __align__(16) unsigned char el[32768];
  __shared__ __align__(16) unsigned char vl[32768];
  __shared__ float Red[1536];  // [0..511]=Z, [512..1535]=colsum
  const int t = threadIdx.x;
  const int wv_ = t >> 6, lo16 = t & 15, g = (t >> 4) & 3, l = t & 63;
  const int pt = wv_ & 3, hf = wv_ >> 2;
  const int p0 = pt * 16;
  const char* Wkv = wsb + B_WKV;

  for (int i = t; i < 1536; i += 512) Red[i] = 0.f;
  float csum[2][8];
#pragma unroll
  for (int b2 = 0; b2 < 2; ++b2)
#pragma unroll
    for (int i = 0; i < 8; ++i) csum[b2][i] = 0.f;
  f32x4 ctxacc[2][2][2];
#pragma unroll
  for (int b2 = 0; b2 < 2; ++b2)
#pragma unroll
    for (int m = 0; m < 2; ++m)
#pragma unroll
      for (int n = 0; n < 2; ++n) ctxacc[b2][m][n] = (f32x4){0.f, 0.f, 0.f, 0.f};
  const int h = wv_;  // head for ctx phase (0..7)
  const int n0 = blockIdx.x * 64;
  const int rowX = p0 + lo16;
  const int bbase = rowX * 1024 + g * 16;
  const int bswz = (rowX & 7) << 4;

#pragma unroll
  for (int b = 0; b < 2; ++b) {
    const float* src = b ? y : x;
    __syncthreads();  // (A) Xl reads of prev iter + el/vl ctx reads done
#pragma unroll
    for (int r = 0; r < 8; ++r) {
      int chunk = r * 512 + t;
      int prow = chunk >> 6, j = chunk & 63;
      const float* gp = src + (size_t)(n0 + prow) * 512 + j * 8;
      float4 u0 = *(const float4*)gp;
      float4 u1 = *(const float4*)(gp + 4);
      csum[b][0] += u0.x; csum[b][1] += u0.y; csum[b][2] += u0.z; csum[b][3] += u0.w;
      csum[b][4] += u1.x; csum[b][5] += u1.y; csum[b][6] += u1.z; csum[b][7] += u1.w;
      uint4 pk;
      pk.x = pack2(u0.x, u0.y); pk.y = pack2(u0.z, u0.w);
      pk.z = pack2(u1.x, u1.y); pk.w = pack2(u1.z, u1.w);
      int byte = (prow * 1024 + j * 16) ^ ((prow & 7) << 4);
      *(uint4*)(Xl + byte) = pk;
    }
    __syncthreads();  // (B)
#pragma unroll
    for (int tp = 0; tp < 8; ++tp) {
      int t0 = hf * 16 + tp * 2;
      f32x4 a0 = {0.f, 0.f, 0.f, 0.f}, a1 = {0.f, 0.f, 0.f, 0.f};
      const char* ap = Wkv + t0 * 16384 + l * 16;
#pragma unroll
      for (int ks = 0; ks < 16; ++ks) {
        bf16x8 bxf = *(const bf16x8*)(Xl + ((bbase + ks * 64) ^ bswz));
        bf16x8 af0 = *(const bf16x8*)(ap + ks * 1024);
        bf16x8 af1 = *(const bf16x8*)(ap + 16384 + ks * 1024);
        a0 = MFMA(af0, bxf, a0);
        a1 = MFMA(af1, bxf, a1);
      }
      int t1 = t0 + 1;
      int pp = p0 + lo16;
      if (hf == 0) {  // keys -> e, Z, el
        float e0[4], e1[4];
#pragma unroll
        for (int r = 0; r < 4; ++r) {
          e0[r] = __expf(a0[r] + bk[t0 * 16 + g * 4 + r]);
          e1[r] = __expf(a1[r] + bk[t1 * 16 + g * 4 + r]);
        }
#pragma unroll
        for (int r = 0; r < 4; ++r) {
          float v0 = e0[r], v1 = e1[r];
          for (int m = 8; m >= 1; m >>= 1) {
            v0 += __shfl_xor(v0, m, 16);
            v1 += __shfl_xor(v1, m, 16);
          }
          if (lo16 == 0) {
            atomicAdd(&Red[b * 256 + t0 * 16 + g * 4 + r], v0);
            atomicAdd(&Red[b * 256 + t1 * 16 + g * 4 + r], v1);
          }
        }
#pragma unroll
        for (int r = 0; r < 4; ++r) {
          int row0 = t0 * 16 + g * 4 + r;
          int row1 = t1 * 16 + g * 4 + r;
          *(unsigned short*)(el + ((row0 * 128 + pp * 2) ^ ((row0 & 7) << 4))) = (unsigned short)f2bfu(e0[r]);
          *(unsigned short*)(el + ((row1 * 128 + pp * 2) ^ ((row1 & 7) << 4))) = (unsigned short)f2bfu(e1[r]);
        }
      } else {  // values -> vl
#pragma unroll
        for (int r = 0; r < 4; ++r) {
          int row0 = (t0 - 16) * 16 + g * 4 + r;
          int row1 = (t1 - 16) * 16 + g * 4 + r;
          *(unsigned short*)(vl + ((row0 * 128 + pp * 2) ^ ((row0 & 7) << 4))) = (unsigned short)f2bfu(a0[r] + bv[row0]);
          *(unsigned short*)(vl + ((row1 * 128 + pp * 2) ^ ((row1 & 7) << 4))) = (unsigned short)f2bfu(a1[r] + bv[row1]);
        }
      }
    }
    __syncthreads();  // (C) el, vl ready
#pragma unroll
    for (int m = 0; m < 2; ++m)
#pragma unroll
      for (int n = 0; n < 2; ++n) {
        int rowe = h * 32 + m * 16 + lo16;
        int rowv = h * 32 + n * 16 + lo16;
#pragma unroll
        for (int ks = 0; ks < 2; ++ks) {
          bf16x8 ea = *(const bf16x8*)(el + ((rowe * 128 + ks * 64 + g * 16) ^ ((rowe & 7) << 4)));
          bf16x8 vb = *(const bf16x8*)(vl + ((rowv * 128 + ks * 64 + g * 16) ^ ((rowv & 7) << 4)));
          ctxacc[b][m][n] = MFMA(ea, vb, ctxacc[b][m][n]);
        }
      }
  }
  __syncthreads();  // Red complete
  // plain-store partials into d_out scratch (fully coalesced, no atomics)
  {
    unsigned* ctxp = (unsigned*)outp + (size_t)blockIdx.x * 8192;
#pragma unroll
    for (int b = 0; b < 2; ++b)
#pragma unroll
      for (int m = 0; m < 2; ++m)
#pragma unroll
        for (int r = 0; r < 4; ++r)
          ctxp[((b * 2 + m) * 4 + r) * 512 + t] = pack2(ctxacc[b][m][0][r], ctxacc[b][m][1][r]);
    float* redp = outp + 4194304 + blockIdx.x * 1536;
    for (int i = t; i < 1536; i += 512) redp[i] = Red[i];
  }
}

// ---------------- k1b: sum the 512 partial copies ----------------
__global__ __launch_bounds__(512) void k1b(const float* __restrict__ outp, char* __restrict__ wsb) {
  const int t = threadIdx.x;
  float* wsf = (float*)wsb;
  if (blockIdx.x < 16) {
    int slot = blockIdx.x * 512 + t;
    const unsigned* p = (const unsigned*)outp;
    float s0 = 0.f, s1 = 0.f;
    for (int c = 0; c < 512; ++c) {
      unsigned w = p[c * 8192 + slot];
      s0 += __uint_as_float(w << 16);
      s1 += __uint_as_float(w & 0xffff0000u);
    }
    int t_ = slot & 511, bmr = slot >> 9;
    int r = bmr & 3, m = (bmr >> 2) & 1, b = bmr >> 3;
    int h = t_ >> 6, g = (t_ >> 4) & 3, lo16 = t_ & 15;
    int klocal = m * 16 + g * 4 + r;
    int base = ((b * 8 + h) * 32 + klocal) * 32;
    wsf[(B_CTXC / 4) + base + lo16] = s0;
    wsf[(B_CTXC / 4) + base + 16 + lo16] = s1;
  } else {
    const float* rp = outp + 4194304;
    for (int j = t; j < 1536; j += 512) {
      float s = 0.f;
      for (int c = 0; c < 512; ++c) s += rp[c * 1536 + j];
      if (j < 512) wsf[(B_ZP / 4) + j] = s;
      else wsf[(B_COLS / 4) + (j - 512)] = s;
    }
  }
}

// ---------------- k2: ctx normalize (packed write), pool chain, constD, biasOut ----------------
__global__ __launch_bounds__(512) void k2_finalize(
    const float* __restrict__ pbn1, const float* __restrict__ pbn2,
    const float* __restrict__ dbn1, const float* __restrict__ d2,
    const float* __restrict__ ea_br, char* __restrict__ wsb) {
  __shared__ float HI[1024], H1[1024], H2l[512], VB[512], slot[4];
  const int t = threadIdx.x;
  float* wsf = (float*)wsb;
  unsigned short* u16 = (unsigned short*)wsb;
  for (int idx = t; idx < 16384; idx += 512) {
    float s = wsf[(B_CTXC / 4) + idx];
    int v = idx & 31, row = idx >> 5;
    int b = row >> 8, kr = row & 255;
    int hh = kr >> 5, kh = kr & 31;
    float val = s / wsf[(B_ZP / 4) + b * 256 + kr];
    int m = v >> 4;
    int lane = (v & 15) + ((kh >> 3) << 4);
    int j = kh & 7;
    u16[(B_CTXT / 2) + (((b * 8 + hh) * 2 + m) << 9) + lane * 8 + j] = (unsigned short)f2bfu(val);
  }
  if (t < 4) slot[t] = 0.f;
  for (int idx = t; idx < 1024; idx += 512) HI[idx] = wsf[(B_COLS / 4) + idx] * (1.f / 32768.f);
  __syncthreads();
  {
    int o = t;
    float gg = pbn1[o], be = pbn1[512 + o], mn = pbn1[1024 + o], va = pbn1[1536 + o];
    float sc = gg * rsqrtf(va + 1e-5f), sh = be - mn * sc;
    for (int b = 0; b < 2; ++b) {
      float acc = 0.f;
      for (int c = 0; c < 512; ++c) acc = fmaf(wsf[(B_PW1T / 4) + c * 512 + o], HI[b * 512 + c], acc);
      H1[b * 512 + o] = acc * sc + sh;
    }
  }
  __syncthreads();
  if (t < 256) {
    int o = t;
    float gg = pbn2[o], be = pbn2[256 + o], mn = pbn2[512 + o], va = pbn2[768 + o];
    float sc = gg * rsqrtf(va + 1e-5f), sh = be - mn * sc;
    for (int b = 0; b < 2; ++b) {
      float acc = 0.f;
      for (int c = 0; c < 512; ++c) acc = fmaf(wsf[(B_PW2T / 4) + c * 256 + o], H1[b * 512 + c], acc);
      float vv = acc * sc + sh;
      H2l[b * 256 + o] = vv;
      wsf[(B_HIGH2 / 4) + b * 256 + o] = vv;
    }
  }
  __syncthreads();
  if (t < 256) {
    int o = t;
    float gg = dbn1[o], be = dbn1[256 + o], mn = dbn1[512 + o], va = dbn1[768 + o];
    float sd = gg * rsqrtf(va + 1e-5f), fd = be - mn * sd;
    for (int b = 0; b < 2; ++b) {
      float acc = 0.f;
      for (int v = 0; v < 256; ++v) acc = fmaf(wsf[(B_D1BT / 4) + v * 256 + o], H2l[b * 256 + v], acc);
      VB[b * 256 + o] = sd * acc + fd;
    }
  }
  __syncthreads();
  if (t < 256) {
    int o = t;
    for (int b = 0; b < 2; ++b)
      for (int j = 0; j < 2; ++j) atomicAdd(&slot[b * 2 + j], d2[j * 256 + o] * VB[b * 256 + o]);
    float cp = wsf[(B_CPP / 4) + o];
    for (int j = 0; j < 2; ++j) {
      float w = wsf[(B_WDD / 4) + j * 256 + o] * cp;
      atomicAdd(&slot[0 + j], w);
      atomicAdd(&slot[2 + j], w);
    }
  }
  __syncthreads();
  if (t < 4) wsf[(B_CONSTD / 4) + t] = slot[t];
  {
    int o = t;
    float bb = 0.5f * ea_br[o];
    if (o >= 256) bb += 0.5f * wsf[(B_CPP / 4) + o - 256];
    wsf[(B_BIASO / 4) + o] = bb;
  }
}

// ---------------- k3: main fused per-position MFMA pass ----------------
// B-fragments re-read from LDS per MFMA (no bx[16] preload -> no spills).
__global__ __launch_bounds__(512, 2) void k3_main(
    const float* __restrict__ x, const float* __restrict__ y,
    const float* __restrict__ bq, const char* __restrict__ wsb,
    float* __restrict__ out) {
  __shared__ __align__(16) unsigned char Xl[65536];
  __shared__ __align__(16) unsigned char Ql[32768];
  __shared__ float wgtl[64];
  const int t = threadIdx.x;
  const int wv_ = t >> 6, lo16 = t & 15, g = (t >> 4) & 3, l = t & 63;
  const int pt = wv_ & 3, hf = wv_ >> 2;
  const int p0 = pt * 16;
  const int n0 = blockIdx.x * 64;
  const char* Wbig = wsb + B_WBIG;
  const char* WRp = wsb + B_WR;
  const char* CTXT = wsb + B_CTXT;
  const float* wsf = (const float*)wsb;
  unsigned char* Qslab = Ql + pt * 8192;

  f32x4 macc[16];  // hf==0: attS accumulators; hf==1: 0.25*(L0+L1)
#pragma unroll
  for (int i = 0; i < 16; ++i) macc[i] = (f32x4){0.f, 0.f, 0.f, 0.f};
  float wg0 = 0.f, wg1 = 0.f;
  const int rowX = p0 + lo16;
  const int bbase = rowX * 1024 + g * 16;
  const int bswz = (rowX & 7) << 4;

#pragma unroll
  for (int b = 0; b < 2; ++b) {
    const float* src = b ? y : x;
    __syncthreads();  // (A) prev-iter Xl/Qslab reads done
#pragma unroll
    for (int r = 0; r < 8; ++r) {
      int chunk = r * 512 + t;
      int prow = chunk >> 6, j = chunk & 63;
      const float* gp = src + (size_t)(n0 + prow) * 512 + j * 8;
      float4 u0 = *(const float4*)gp;
      float4 u1 = *(const float4*)(gp + 4);
      uint4 pk;
      pk.x = pack2(u0.x, u0.y); pk.y = pack2(u0.z, u0.w);
      pk.z = pack2(u1.x, u1.y); pk.w = pack2(u1.z, u1.w);
      int byte = (prow * 1024 + j * 16) ^ ((prow & 7) << 4);
      *(uint4*)(Xl + byte) = pk;
    }
    __syncthreads();  // (B)
#pragma unroll
    for (int tp = 0; tp < 8; ++tp) {
      int t0 = hf * 16 + tp * 2;
      f32x4 a0 = {0.f, 0.f, 0.f, 0.f}, a1 = {0.f, 0.f, 0.f, 0.f};
      const char* ap = Wbig + t0 * 16384 + l * 16;
#pragma unroll
      for (int ks = 0; ks < 16; ++ks) {
        bf16x8 bxf = *(const bf16x8*)(Xl + ((bbase + ks * 64) ^ bswz));
        bf16x8 af0 = *(const bf16x8*)(ap + ks * 1024);
        bf16x8 af1 = *(const bf16x8*)(ap + 16384 + ks * 1024);
        a0 = MFMA(af0, bxf, a0);
        a1 = MFMA(af1, bxf, a1);
      }
      int t1 = t0 + 1;
      if (hf == 0) {  // Q pair = head tp: bias + softmax over 32 head-channels
        int hh = tp;
        float q[8], e[8];
        float mx = -1e30f;
#pragma unroll
        for (int r = 0; r < 4; ++r) {
          q[r] = a0[r] + bq[hh * 32 + g * 4 + r];
          q[4 + r] = a1[r] + bq[hh * 32 + 16 + g * 4 + r];
          mx = fmaxf(mx, fmaxf(q[r], q[4 + r]));
        }
        mx = fmaxf(mx, __shfl_xor(mx, 16, 64));
        mx = fmaxf(mx, __shfl_xor(mx, 32, 64));
        float sm = 0.f;
#pragma unroll
        for (int r = 0; r < 8; ++r) { e[r] = __expf(q[r] - mx); sm += e[r]; }
        sm += __shfl_xor(sm, 16, 64);
        sm += __shfl_xor(sm, 32, 64);
        float inv = 1.f / sm;
        uint2 w0, w1;
        w0.x = pack2(e[0] * inv, e[1] * inv); w0.y = pack2(e[2] * inv, e[3] * inv);
        w1.x = pack2(e[4] * inv, e[5] * inv); w1.y = pack2(e[6] * inv, e[7] * inv);
        int base_q = lo16 * 512 + hh * 64 + g * 8;
        int swzq = (lo16 & 7) << 4;
        *(uint2*)(Qslab + (base_q ^ swzq)) = w0;
        *(uint2*)(Qslab + ((base_q + 32) ^ swzq)) = w1;
      } else {  // L tiles
        macc[tp * 2] += 0.25f * a0;
        macc[tp * 2 + 1] += 0.25f * a1;
      }
    }
    if (hf == 1) {  // delta tile (rows 512..527 = packed tile 32)
      f32x4 ad = {0.f, 0.f, 0.f, 0.f};
      const char* ap = Wbig + 32 * 16384 + l * 16;
#pragma unroll
      for (int ks = 0; ks < 16; ++ks) {
        bf16x8 bxf = *(const bf16x8*)(Xl + ((bbase + ks * 64) ^ bswz));
        bf16x8 af = *(const bf16x8*)(ap + ks * 1024);
        ad = MFMA(af, bxf, ad);
      }
      if (g == 0) {
        float d0 = ad[0] + wsf[(B_CONSTD / 4) + b * 2 + 0];
        float d1 = ad[1] + wsf[(B_CONSTD / 4) + b * 2 + 1];
        int pos = n0 + p0 + lo16;
        float gx = -1.f + 2.f * (float)pos / 32767.f + d0;
        float gy = -1.f + d1;
        float ix = gx * 0.5f, iy = gy * 0.5f;
        float wx = fminf(fmaxf(1.f - fabsf(ix), 0.f), 1.f);
        float wy = fminf(fmaxf(1.f - fabsf(iy), 0.f), 1.f);
        wgtl[p0 + lo16] = wx * wy;
      }
    } else {  // att: per-head mfma(ctx_packed, Q)
      int swzq = (lo16 & 7) << 4;
#pragma unroll
      for (int hh = 0; hh < 8; ++hh) {
        bf16x8 qf = *(const bf16x8*)(Qslab + ((lo16 * 512 + hh * 64 + g * 16) ^ swzq));
        const char* cp = CTXT + (b * 8 + hh) * 2048 + l * 16;
        bf16x8 c0 = *(const bf16x8*)(cp);
        bf16x8 c1 = *(const bf16x8*)(cp + 1024);
        macc[hh * 2] = MFMA(c0, qf, macc[hh * 2]);
        macc[hh * 2 + 1] = MFMA(c1, qf, macc[hh * 2 + 1]);
      }
    }
    __syncthreads();  // (C) wgtl ready
    if (hf == 0) {
      float w = wgtl[p0 + lo16];
      if (b == 0) wg0 = w; else wg1 = w;
    }
  }
  // attS (hf==0) -> LDS (reuse Qslab)
  if (hf == 0) {
    int swzq = (lo16 & 7) << 4;
#pragma unroll
    for (int hh = 0; hh < 8; ++hh)
#pragma unroll
      for (int m = 0; m < 2; ++m) {
        f32x4 v = macc[hh * 2 + m];
        uint2 w;
        w.x = pack2(v[0], v[1]); w.y = pack2(v[2], v[3]);
        int byte = (lo16 * 512 + hh * 64 + m * 32 + g * 8) ^ swzq;
        *(uint2*)(Qslab + byte) = w;
      }
  }
  __syncthreads();  // (D)
  const float* bo = wsf + (B_BIASO / 4);
  const size_t rowaddr = (size_t)(n0 + p0 + lo16) * 512;
  const int swzq2 = (lo16 & 7) << 4;
#pragma unroll
  for (int tp = 0; tp < 8; ++tp) {
    int lt0 = tp * 2, lt1 = lt0 + 1;
    int ch0 = hf * 256 + lt0 * 16, ch1 = ch0 + 16;
    int T0 = hf * 16 + lt0;  // WR tile indices
    f32x4 r0 = {0.f, 0.f, 0.f, 0.f}, r1 = {0.f, 0.f, 0.f, 0.f};
    const char* ap = WRp + T0 * 8192 + l * 16;
#pragma unroll
    for (int ks = 0; ks < 8; ++ks) {
      bf16x8 brf = *(const bf16x8*)(Qslab + ((lo16 * 512 + g * 16 + ks * 64) ^ swzq2));
      bf16x8 a0 = *(const bf16x8*)(ap + ks * 1024);
      bf16x8 a1 = *(const bf16x8*)(ap + 8192 + ks * 1024);
      r0 = MFMA(a0, brf, r0);
      r1 = MFMA(a1, brf, r1);
    }
#pragma unroll
    for (int half = 0; half < 2; ++half) {
      int lt = half ? lt1 : lt0;
      int cb = (half ? ch1 : ch0) + g * 4;
      f32x4 rr = half ? r1 : r0;
      f32x4 xr = *(const f32x4*)(x + rowaddr + cb);
      f32x4 yr = *(const f32x4*)(y + rowaddr + cb);
      f32x4 bb = *(const f32x4*)(bo + cb);
      f32x4 extra;
      if (hf == 0) {
        f32x4 h20 = *(const f32x4*)(wsf + (B_HIGH2 / 4) + cb);
        f32x4 h21 = *(const f32x4*)(wsf + (B_HIGH2 / 4) + 256 + cb);
        extra = (0.25f * wg0) * h20 + (0.25f * wg1) * h21;
      } else {
        extra = macc[lt];
      }
      f32x4 vout = extra + 0.25f * rr + 0.25f * (xr + yr) + bb;
      *(f32x4*)(out + rowaddr + cb) = vout;
    }
  }
}

extern "C" void kernel_launch(void* const* d_in, const int* in_sizes, int n_in,
                              void* d_out, int out_size, void* d_ws, size_t ws_size,
                              hipStream_t stream) {
  const float* x = (const float*)d_in[0];
  const float* y = (const float*)d_in[1];
  const float* ea_wk = (const float*)d_in[2];
  const float* ea_bk = (const float*)d_in[3];
  const float* ea_wq = (const float*)d_in[4];
  const float* ea_bq = (const float*)d_in[5];
  const float* ea_wv = (const float*)d_in[6];
  const float* ea_bv = (const float*)d_in[7];
  const float* ea_wr = (const float*)d_in[8];
  const float* ea_br = (const float*)d_in[9];
  const float* pool_w1 = (const float*)d_in[10];
  const float* pool_bn1 = (const float*)d_in[11];
  const float* pool_w2 = (const float*)d_in[12];
  const float* pool_bn2 = (const float*)d_in[13];
  const float* adapt_w1 = (const float*)d_in[14];
  const float* adapt_bn1 = (const float*)d_in[15];
  const float* adapt_w2 = (const float*)d_in[16];
  const float* adapt_bn2 = (const float*)d_in[17];
  const float* delta_w1 = (const float*)d_in[18];
  const float* delta_bn1 = (const float*)d_in[19];
  const float* delta_w2 = (const float*)d_in[20];
  char* ws = (char*)d_ws;
  float* out = (float*)d_out;

  kW1<<<256, 512, 0, stream>>>(adapt_w1, adapt_bn1, adapt_w2, adapt_bn2, ws);
  kW2<<<1, 512, 0, stream>>>(delta_w1, delta_bn1, delta_w2, ws);
  kPack<<<4384, 256, 0, stream>>>(ea_wq, ea_wk, ea_wv, ea_wr, pool_w1, pool_w2, delta_w1, ws);
  k1_reduce<<<512, 512, 0, stream>>>(x, y, ea_bk, ea_bv, ws, out);
  k1b<<<17, 512, 0, stream>>>(out, ws);
  k2_finalize<<<1, 512, 0, stream>>>(pool_bn1, pool_bn2, delta_bn1, delta_w2, ea_br, ws);
  k3_main<<<512, 512, 0, stream>>>(x, y, ea_bq, ws, out);
}

// Round 8
// 692.324 us; speedup vs baseline: 4.7189x; 1.1982x over previous
//
#include <hip/hip_runtime.h>
#include <math.h>

// ---------------- ws byte offsets ----------------
#define B_CTXC   0          // single summed ctx [2][8][32][32] f32 = 65536 B
#define B_ZP     524288     // [2][256] f32
#define B_COLS   526336     // [2][512] f32
#define B_HIGH2  530432     // [2][256] f32
#define B_CONSTD 532480     // [2][2] f32 (+pad)
#define B_BIASO  532544     // [512] f32
#define B_CPP    534592     // [256] f32 (c'')
#define B_CTXT   535616     // [2][8] x 2 tiles x 1KB bf16, fragment-linear
#define B_WDD    568384     // [2][256] f32
#define B_WDX    570432     // [2][512] f32
#define B_WL     574528     // [256][512] f32 (W_L'')
#define B_WBIG   1098816    // 33 tiles x 16KB bf16, fragment-linear
#define B_WKV    1639488    // 32 tiles x 16KB bf16, fragment-linear
#define B_WR     2163776    // 32 tiles x 8KB bf16, fragment-linear
#define B_PW1T   2425920    // [512][512] f32 transposed
#define B_PW2T   3474496    // [512][256] f32 transposed
#define B_D1BT   3998784    // [256][256] f32 transposed
// d_out scratch (before k3 overwrites): [1024][8192] u32 ctx partials at u32
// index 0 (32MB), [1024][1536] f32 red partials at float offset 8388608.

typedef __attribute__((ext_vector_type(8))) short bf16x8;
typedef __attribute__((ext_vector_type(4))) float f32x4;

#define MFMA(a, b, c) __builtin_amdgcn_mfma_f32_16x16x32_bf16(a, b, c, 0, 0, 0)

__device__ inline unsigned f2bfu(float f) {
  unsigned u = __float_as_uint(f);
  return (u + 0x7FFFu + ((u >> 16) & 1u)) >> 16;
}
__device__ inline unsigned pack2(float a, float b) { return f2bfu(a) | (f2bfu(b) << 16); }

// ---------------- kW1: W_L'' (fp32) + c'' ----------------
__global__ __launch_bounds__(512) void kW1(
    const float* __restrict__ a1, const float* __restrict__ abn1,
    const float* __restrict__ a2, const float* __restrict__ abn2,
    char* __restrict__ wsb) {
  __shared__ float S1[512], F1[512], redu[512];
  const int t = threadIdx.x, o = blockIdx.x;
  float* wsf = (float*)wsb;
  {
    float gg = abn1[t], be = abn1[512 + t], mn = abn1[1024 + t], va = abn1[1536 + t];
    float s = gg * rsqrtf(va + 1e-5f);
    S1[t] = s; F1[t] = be - mn * s;
  }
  float g2 = abn2[o], be2 = abn2[256 + o], mn2 = abn2[512 + o], va2 = abn2[768 + o];
  float s2 = g2 * rsqrtf(va2 + 1e-5f);
  float f2v = be2 - mn2 * s2;
  __syncthreads();
  float acc = 0.f;
  const float* a2r = a2 + o * 512;
  for (int m = 0; m < 512; ++m) acc = fmaf(a2r[m] * S1[m], a1[m * 512 + t], acc);
  wsf[(B_WL / 4) + o * 512 + t] = s2 * acc;
  redu[t] = a2r[t] * F1[t];
  __syncthreads();
  for (int sft = 256; sft >= 1; sft >>= 1) {
    if (t < sft) redu[t] += redu[t + sft];
    __syncthreads();
  }
  if (t == 0) wsf[(B_CPP / 4) + o] = s2 * redu[0] + f2v;
}

// ---------------- kW2: W_dd, W_dx ----------------
__global__ __launch_bounds__(512) void kW2(
    const float* __restrict__ d1, const float* __restrict__ dbn1,
    const float* __restrict__ d2, char* __restrict__ wsb) {
  __shared__ float SD[256], WDDl[512];
  const int t = threadIdx.x;
  float* wsf = (float*)wsb;
  if (t < 256) {
    float gg = dbn1[t], va = dbn1[768 + t];
    SD[t] = gg * rsqrtf(va + 1e-5f);
  }
  __syncthreads();
  {
    int j = t >> 8, v = t & 255;
    float acc = 0.f;
    for (int o = 0; o < 256; ++o) acc = fmaf(d2[j * 256 + o] * SD[o], d1[o * 512 + v], acc);
    WDDl[t] = acc;
    wsf[(B_WDD / 4) + t] = acc;
  }
  __syncthreads();
  {
    int c = t;
    float acc0 = 0.f, acc1 = 0.f;
    for (int v = 0; v < 256; ++v) {
      float wl = wsf[(B_WL / 4) + v * 512 + c];
      acc0 = fmaf(WDDl[v], wl, acc0);
      acc1 = fmaf(WDDl[256 + v], wl, acc1);
    }
    wsf[(B_WDX / 4) + c] = acc0;
    wsf[(B_WDX / 4) + 512 + c] = acc1;
  }
}

// ---------------- kPack: fragment-linear bf16 packs + fp32 transposes ----------------
__global__ __launch_bounds__(256) void kPack(
    const float* __restrict__ wq, const float* __restrict__ wk, const float* __restrict__ wv,
    const float* __restrict__ wr, const float* __restrict__ pw1, const float* __restrict__ pw2,
    const float* __restrict__ d1, char* __restrict__ wsb) {
  int i = blockIdx.x * 256 + threadIdx.x;
  float* wsf = (float*)wsb;
  unsigned short* u16 = (unsigned short*)wsb;
  if (i < 270336) {  // Wbig: 33 tiles, K=512 (ks 0..15)
    int T = i >> 13, r = i & 8191;
    int ks = r >> 9, l = (r >> 3) & 63, j = r & 7;
    int row = T * 16 + (l & 15);
    int col = ks * 32 + (l >> 4) * 8 + j;
    float v;
    if (row < 256) v = wq[row * 512 + col];
    else if (row < 512) v = wsf[(B_WL / 4) + (row - 256) * 512 + col];
    else if (row < 514) v = wsf[(B_WDX / 4) + (row - 512) * 512 + col];
    else v = 0.f;
    u16[(B_WBIG / 2) + i] = (unsigned short)f2bfu(v);
    return;
  }
  i -= 270336;
  if (i < 262144) {  // Wkv: 32 tiles, K=512
    int T = i >> 13, r = i & 8191;
    int ks = r >> 9, l = (r >> 3) & 63, j = r & 7;
    int row = T * 16 + (l & 15);
    int col = ks * 32 + (l >> 4) * 8 + j;
    float v = row < 256 ? wk[row * 512 + col] : wv[(row - 256) * 512 + col];
    u16[(B_WKV / 2) + i] = (unsigned short)f2bfu(v);
    return;
  }
  i -= 262144;
  if (i < 131072) {  // WR: 32 tiles, K=256 (ks 0..7)
    int T = i >> 12, r = i & 4095;
    int ks = r >> 9, l = (r >> 3) & 63, j = r & 7;
    int row = T * 16 + (l & 15);
    int col = ks * 32 + (l >> 4) * 8 + j;
    u16[(B_WR / 2) + i] = (unsigned short)f2bfu(wr[row * 256 + col]);
    return;
  }
  i -= 131072;
  if (i < 262144) { int o = i >> 9, c = i & 511; wsf[(B_PW1T / 4) + c * 512 + o] = pw1[i]; return; }
  i -= 262144;
  if (i < 131072) { int o = i >> 9, c = i & 511; wsf[(B_PW2T / 4) + c * 256 + o] = pw2[i]; return; }
  i -= 131072;
  if (i < 65536) { int o = i >> 8, v = i & 255; wsf[(B_D1BT / 4) + v * 256 + o] = d1[o * 512 + 256 + v]; }
}

// ---------------- k1: keys/values MFMA + ctx/Z/colsum partials ----------------
// 32-pos tiles; 8 waves = (pt, tphalf, hf); 4 tile-pairs per wave.
__global__ __launch_bounds__(512, 2) void k1_reduce(
    const float* __restrict__ x, const float* __restrict__ y,
    const float* __restrict__ bk, const float* __restrict__ bv,
    const char* __restrict__ wsb, float* __restrict__ outp) {
  __shared__ __align__(16) unsigned char Xl[32768];
  __shared__ __align__(16) unsigned char el[16384];
  __shared__ __align__(16) unsigned char vl[16384];
  __shared__ float Red[1536];  // [0..511]=Z, [512..1535]=colsum
  const int t = threadIdx.x;
  const int w = t >> 6, lo16 = t & 15, g = (t >> 4) & 3, l = t & 63;
  const int pt = w & 1, tph = (w >> 1) & 1, hf = w >> 2;
  const int p0 = pt * 16;
  const char* Wkv = wsb + B_WKV;

  for (int i = t; i < 1536; i += 512) Red[i] = 0.f;
  float csum[2][8];
#pragma unroll
  for (int b2 = 0; b2 < 2; ++b2)
#pragma unroll
    for (int i = 0; i < 8; ++i) csum[b2][i] = 0.f;
  f32x4 ctxacc[2][2][2];
#pragma unroll
  for (int b2 = 0; b2 < 2; ++b2)
#pragma unroll
    for (int m = 0; m < 2; ++m)
#pragma unroll
      for (int n = 0; n < 2; ++n) ctxacc[b2][m][n] = (f32x4){0.f, 0.f, 0.f, 0.f};
  const int h = w;  // ctx-phase head
  const int n0 = blockIdx.x * 32;
  const int rowX = p0 + lo16;
  const int bbase = rowX * 1024 + g * 16;
  const int bswz = (rowX & 7) << 4;

#pragma unroll
  for (int b = 0; b < 2; ++b) {
    const float* src = b ? y : x;
    __syncthreads();  // (A)
#pragma unroll
    for (int r = 0; r < 4; ++r) {
      int chunk = r * 512 + t;
      int prow = chunk >> 6, j = chunk & 63;
      const float* gp = src + (size_t)(n0 + prow) * 512 + j * 8;
      float4 u0 = *(const float4*)gp;
      float4 u1 = *(const float4*)(gp + 4);
      csum[b][0] += u0.x; csum[b][1] += u0.y; csum[b][2] += u0.z; csum[b][3] += u0.w;
      csum[b][4] += u1.x; csum[b][5] += u1.y; csum[b][6] += u1.z; csum[b][7] += u1.w;
      uint4 pk;
      pk.x = pack2(u0.x, u0.y); pk.y = pack2(u0.z, u0.w);
      pk.z = pack2(u1.x, u1.y); pk.w = pack2(u1.z, u1.w);
      int byte = (prow * 1024 + j * 16) ^ ((prow & 7) << 4);
      *(uint4*)(Xl + byte) = pk;
    }
    __syncthreads();  // (B)
#pragma unroll
    for (int tp = 0; tp < 4; ++tp) {
      int tq = tph * 4 + tp;
      int t0 = hf * 16 + tq * 2, t1 = hf * 16 + tq * 2 + 1;
      f32x4 a0 = {0.f, 0.f, 0.f, 0.f}, a1 = {0.f, 0.f, 0.f, 0.f};
      const char* ap = Wkv + t0 * 16384 + l * 16;
#pragma unroll
      for (int ks = 0; ks < 16; ++ks) {
        bf16x8 bxf = *(const bf16x8*)(Xl + ((bbase + ks * 64) ^ bswz));
        bf16x8 af0 = *(const bf16x8*)(ap + ks * 1024);
        bf16x8 af1 = *(const bf16x8*)(ap + 16384 + ks * 1024);
        a0 = MFMA(af0, bxf, a0);
        a1 = MFMA(af1, bxf, a1);
      }
      int pp = p0 + lo16;
      if (hf == 0) {  // keys -> e, Z, el
        float e0[4], e1[4];
#pragma unroll
        for (int r = 0; r < 4; ++r) {
          e0[r] = __expf(a0[r] + bk[t0 * 16 + g * 4 + r]);
          e1[r] = __expf(a1[r] + bk[t1 * 16 + g * 4 + r]);
        }
#pragma unroll
        for (int r = 0; r < 4; ++r) {
          float v0 = e0[r], v1 = e1[r];
          for (int m = 8; m >= 1; m >>= 1) {
            v0 += __shfl_xor(v0, m, 16);
            v1 += __shfl_xor(v1, m, 16);
          }
          if (lo16 == 0) {
            atomicAdd(&Red[b * 256 + t0 * 16 + g * 4 + r], v0);
            atomicAdd(&Red[b * 256 + t1 * 16 + g * 4 + r], v1);
          }
        }
#pragma unroll
        for (int r = 0; r < 4; ++r) {
          int row0 = t0 * 16 + g * 4 + r;
          int row1 = t1 * 16 + g * 4 + r;
          *(unsigned short*)(el + ((row0 * 64 + pp * 2) ^ ((row0 & 3) << 4))) = (unsigned short)f2bfu(e0[r]);
          *(unsigned short*)(el + ((row1 * 64 + pp * 2) ^ ((row1 & 3) << 4))) = (unsigned short)f2bfu(e1[r]);
        }
      } else {  // values -> vl
#pragma unroll
        for (int r = 0; r < 4; ++r) {
          int row0 = (t0 - 16) * 16 + g * 4 + r;
          int row1 = (t1 - 16) * 16 + g * 4 + r;
          *(unsigned short*)(vl + ((row0 * 64 + pp * 2) ^ ((row0 & 3) << 4))) = (unsigned short)f2bfu(a0[r] + bv[row0]);
          *(unsigned short*)(vl + ((row1 * 64 + pp * 2) ^ ((row1 & 3) << 4))) = (unsigned short)f2bfu(a1[r] + bv[row1]);
        }
      }
    }
    __syncthreads();  // (C) el, vl ready
#pragma unroll
    for (int m = 0; m < 2; ++m)
#pragma unroll
      for (int n = 0; n < 2; ++n) {
        int rowe = h * 32 + m * 16 + lo16;
        int rowv = h * 32 + n * 16 + lo16;
        bf16x8 ea = *(const bf16x8*)(el + ((rowe * 64 + g * 16) ^ ((rowe & 3) << 4)));
        bf16x8 vb = *(const bf16x8*)(vl + ((rowv * 64 + g * 16) ^ ((rowv & 3) << 4)));
        ctxacc[b][m][n] = MFMA(ea, vb, ctxacc[b][m][n]);
      }
  }
  __syncthreads();  // Red complete
  {
    unsigned* ctxp = (unsigned*)outp + (size_t)blockIdx.x * 8192;
#pragma unroll
    for (int b = 0; b < 2; ++b)
#pragma unroll
      for (int m = 0; m < 2; ++m)
#pragma unroll
        for (int r = 0; r < 4; ++r)
          ctxp[((b * 2 + m) * 4 + r) * 512 + t] = pack2(ctxacc[b][m][0][r], ctxacc[b][m][1][r]);
    float* redp = outp + 8388608 + blockIdx.x * 1536;
    for (int i = t; i < 1536; i += 512) redp[i] = Red[i];
  }
}

// ---------------- k1b: tree-reduce the 1024 partial copies ----------------
__global__ __launch_bounds__(512) void k1b(const float* __restrict__ outp, char* __restrict__ wsb) {
  __shared__ float R[512];
  const int t = threadIdx.x, blk = blockIdx.x;
  float* wsf = (float*)wsb;
  if (blk < 64) {  // ctx: 128 slots per block, 4 partial-sum lanes each
    int sl = t & 127, part = t >> 7;
    int slot = blk * 128 + sl;
    const unsigned* p = (const unsigned*)outp;
    float s0 = 0.f, s1 = 0.f;
    for (int c = part * 256; c < part * 256 + 256; ++c) {
      unsigned wv = p[(size_t)c * 8192 + slot];
      s0 += __uint_as_float(wv << 16);
      s1 += __uint_as_float(wv & 0xffff0000u);
    }
    R[sl * 4 + part] = s0;
    __syncthreads();
    float sum0 = R[sl * 4] + R[sl * 4 + 1] + R[sl * 4 + 2] + R[sl * 4 + 3];
    __syncthreads();
    R[sl * 4 + part] = s1;
    __syncthreads();
    float sum1 = R[sl * 4] + R[sl * 4 + 1] + R[sl * 4 + 2] + R[sl * 4 + 3];
    if (part == 0) {
      int t_ = slot & 511, bmr = slot >> 9;
      int r = bmr & 3, m = (bmr >> 2) & 1, b = bmr >> 3;
      int h = t_ >> 6, g = (t_ >> 4) & 3, lo16 = t_ & 15;
      int klocal = m * 16 + g * 4 + r;
      int base = ((b * 8 + h) * 32 + klocal) * 32;
      wsf[(B_CTXC / 4) + base + lo16] = sum0;
      wsf[(B_CTXC / 4) + base + 16 + lo16] = sum1;
    }
  } else {  // red: 3 blocks x 512 values
    int j = (blk - 64) * 512 + t;
    const float* rp = outp + 8388608;
    float s = 0.f;
    for (int c = 0; c < 1024; ++c) s += rp[(size_t)c * 1536 + j];
    if (j < 512) wsf[(B_ZP / 4) + j] = s;
    else wsf[(B_COLS / 4) + (j - 512)] = s;
  }
}

// ---------------- k2: ctx normalize (packed write), pool chain, constD, biasOut ----------------
__global__ __launch_bounds__(512) void k2_finalize(
    const float* __restrict__ pbn1, const float* __restrict__ pbn2,
    const float* __restrict__ dbn1, const float* __restrict__ d2,
    const float* __restrict__ ea_br, char* __restrict__ wsb) {
  __shared__ float HI[1024], H1[1024], H2l[512], VB[512], slot[4];
  const int t = threadIdx.x;
  float* wsf = (float*)wsb;
  unsigned short* u16 = (unsigned short*)wsb;
  for (int idx = t; idx < 16384; idx += 512) {
    float s = wsf[(B_CTXC / 4) + idx];
    int v = idx & 31, row = idx >> 5;
    int b = row >> 8, kr = row & 255;
    int hh = kr >> 5, kh = kr & 31;
    float val = s / wsf[(B_ZP / 4) + b * 256 + kr];
    int m = v >> 4;
    int lane = (v & 15) + ((kh >> 3) << 4);
    int j = kh & 7;
    u16[(B_CTXT / 2) + (((b * 8 + hh) * 2 + m) << 9) + lane * 8 + j] = (unsigned short)f2bfu(val);
  }
  if (t < 4) slot[t] = 0.f;
  for (int idx = t; idx < 1024; idx += 512) HI[idx] = wsf[(B_COLS / 4) + idx] * (1.f / 32768.f);
  __syncthreads();
  {
    int o = t;
    float gg = pbn1[o], be = pbn1[512 + o], mn = pbn1[1024 + o], va = pbn1[1536 + o];
    float sc = gg * rsqrtf(va + 1e-5f), sh = be - mn * sc;
    for (int b = 0; b < 2; ++b) {
      float acc = 0.f;
      for (int c = 0; c < 512; ++c) acc = fmaf(wsf[(B_PW1T / 4) + c * 512 + o], HI[b * 512 + c], acc);
      H1[b * 512 + o] = acc * sc + sh;
    }
  }
  __syncthreads();
  if (t < 256) {
    int o = t;
    float gg = pbn2[o], be = pbn2[256 + o], mn = pbn2[512 + o], va = pbn2[768 + o];
    float sc = gg * rsqrtf(va + 1e-5f), sh = be - mn * sc;
    for (int b = 0; b < 2; ++b) {
      float acc = 0.f;
      for (int c = 0; c < 512; ++c) acc = fmaf(wsf[(B_PW2T / 4) + c * 256 + o], H1[b * 512 + c], acc);
      float vv = acc * sc + sh;
      H2l[b * 256 + o] = vv;
      wsf[(B_HIGH2 / 4) + b * 256 + o] = vv;
    }
  }
  __syncthreads();
  if (t < 256) {
    int o = t;
    float gg = dbn1[o], be = dbn1[256 + o], mn = dbn1[512 + o], va = dbn1[768 + o];
    float sd = gg * rsqrtf(va + 1e-5f), fd = be - mn * sd;
    for (int b = 0; b < 2; ++b) {
      float acc = 0.f;
      for (int v = 0; v < 256; ++v) acc = fmaf(wsf[(B_D1BT / 4) + v * 256 + o], H2l[b * 256 + v], acc);
      VB[b * 256 + o] = sd * acc + fd;
    }
  }
  __syncthreads();
  if (t < 256) {
    int o = t;
    for (int b = 0; b < 2; ++b)
      for (int j = 0; j < 2; ++j) atomicAdd(&slot[b * 2 + j], d2[j * 256 + o] * VB[b * 256 + o]);
    float cp = wsf[(B_CPP / 4) + o];
    for (int j = 0; j < 2; ++j) {
      float w = wsf[(B_WDD / 4) + j * 256 + o] * cp;
      atomicAdd(&slot[0 + j], w);
      atomicAdd(&slot[2 + j], w);
    }
  }
  __syncthreads();
  if (t < 4) wsf[(B_CONSTD / 4) + t] = slot[t];
  {
    int o = t;
    float bb = 0.5f * ea_br[o];
    if (o >= 256) bb += 0.5f * wsf[(B_CPP / 4) + o - 256];
    wsf[(B_BIASO / 4) + o] = bb;
  }
}

// ---------------- k3: main fused per-position MFMA pass ----------------
// 32-pos tiles; 8 waves = (pt, tphalf, hf); 4 tile-pairs per wave.
__global__ __launch_bounds__(512, 2) void k3_main(
    const float* __restrict__ x, const float* __restrict__ y,
    const float* __restrict__ bq, const char* __restrict__ wsb,
    float* __restrict__ out) {
  __shared__ __align__(16) unsigned char Xl[32768];
  __shared__ __align__(16) unsigned char Ql[16384];
  __shared__ float wgtl[32];
  const int t = threadIdx.x;
  const int w = t >> 6, lo16 = t & 15, g = (t >> 4) & 3, l = t & 63;
  const int pt = w & 1, tph = (w >> 1) & 1, hf = w >> 2;
  const int p0 = pt * 16;
  const int n0 = blockIdx.x * 32;
  const char* Wbig = wsb + B_WBIG;
  const char* WRp = wsb + B_WR;
  const char* CTXT = wsb + B_CTXT;
  const float* wsf = (const float*)wsb;
  unsigned char* Qslab = Ql + pt * 8192;

  f32x4 macc[8];  // hf==0: attS (4 heads x 2 vtiles); hf==1: 0.25*(L0+L1) (4 tq x 2)
#pragma unroll
  for (int i = 0; i < 8; ++i) macc[i] = (f32x4){0.f, 0.f, 0.f, 0.f};
  float wg0 = 0.f, wg1 = 0.f;
  const int rowX = p0 + lo16;
  const int bbase = rowX * 1024 + g * 16;
  const int bswz = (rowX & 7) << 4;
  const int swzq = (lo16 & 7) << 4;

#pragma unroll
  for (int b = 0; b < 2; ++b) {
    const float* src = b ? y : x;
    __syncthreads();  // (A)
#pragma unroll
    for (int r = 0; r < 4; ++r) {
      int chunk = r * 512 + t;
      int prow = chunk >> 6, j = chunk & 63;
      const float* gp = src + (size_t)(n0 + prow) * 512 + j * 8;
      float4 u0 = *(const float4*)gp;
      float4 u1 = *(const float4*)(gp + 4);
      uint4 pk;
      pk.x = pack2(u0.x, u0.y); pk.y = pack2(u0.z, u0.w);
      pk.z = pack2(u1.x, u1.y); pk.w = pack2(u1.z, u1.w);
      int byte = (prow * 1024 + j * 16) ^ ((prow & 7) << 4);
      *(uint4*)(Xl + byte) = pk;
    }
    __syncthreads();  // (B)
#pragma unroll
    for (int tp = 0; tp < 4; ++tp) {
      int tq = tph * 4 + tp;
      int t0 = hf * 16 + tq * 2;
      f32x4 a0 = {0.f, 0.f, 0.f, 0.f}, a1 = {0.f, 0.f, 0.f, 0.f};
      const char* ap = Wbig + t0 * 16384 + l * 16;
#pragma unroll
      for (int ks = 0; ks < 16; ++ks) {
        bf16x8 bxf = *(const bf16x8*)(Xl + ((bbase + ks * 64) ^ bswz));
        bf16x8 af0 = *(const bf16x8*)(ap + ks * 1024);
        bf16x8 af1 = *(const bf16x8*)(ap + 16384 + ks * 1024);
        a0 = MFMA(af0, bxf, a0);
        a1 = MFMA(af1, bxf, a1);
      }
      if (hf == 0) {  // Q for head tq: bias + softmax over 32 head-channels
        int hh = tq;
        float q[8], e[8];
        float mx = -1e30f;
#pragma unroll
        for (int r = 0; r < 4; ++r) {
          q[r] = a0[r] + bq[hh * 32 + g * 4 + r];
          q[4 + r] = a1[r] + bq[hh * 32 + 16 + g * 4 + r];
          mx = fmaxf(mx, fmaxf(q[r], q[4 + r]));
        }
        mx = fmaxf(mx, __shfl_xor(mx, 16, 64));
        mx = fmaxf(mx, __shfl_xor(mx, 32, 64));
        float sm = 0.f;
#pragma unroll
        for (int r = 0; r < 8; ++r) { e[r] = __expf(q[r] - mx); sm += e[r]; }
        sm += __shfl_xor(sm, 16, 64);
        sm += __shfl_xor(sm, 32, 64);
        float inv = 1.f / sm;
        uint2 w0, w1;
        w0.x = pack2(e[0] * inv, e[1] * inv); w0.y = pack2(e[2] * inv, e[3] * inv);
        w1.x = pack2(e[4] * inv, e[5] * inv); w1.y = pack2(e[6] * inv, e[7] * inv);
        int base_q = lo16 * 512 + hh * 64 + g * 8;
        *(uint2*)(Qslab + (base_q ^ swzq)) = w0;
        *(uint2*)(Qslab + ((base_q + 32) ^ swzq)) = w1;
      } else {  // L tiles
        macc[tp * 2] += 0.25f * a0;
        macc[tp * 2 + 1] += 0.25f * a1;
      }
    }
    if (hf == 1 && tph == 0) {  // delta tile (packed tile 32)
      f32x4 ad = {0.f, 0.f, 0.f, 0.f};
      const char* ap = Wbig + 32 * 16384 + l * 16;
#pragma unroll
      for (int ks = 0; ks < 16; ++ks) {
        bf16x8 bxf = *(const bf16x8*)(Xl + ((bbase + ks * 64) ^ bswz));
        bf16x8 af = *(const bf16x8*)(ap + ks * 1024);
        ad = MFMA(af, bxf, ad);
      }
      if (g == 0) {
        float d0 = ad[0] + wsf[(B_CONSTD / 4) + b * 2 + 0];
        float d1 = ad[1] + wsf[(B_CONSTD / 4) + b * 2 + 1];
        int pos = n0 + p0 + lo16;
        float gx = -1.f + 2.f * (float)pos / 32767.f + d0;
        float gy = -1.f + d1;
        float ix = gx * 0.5f, iy = gy * 0.5f;
        float wx = fminf(fmaxf(1.f - fabsf(ix), 0.f), 1.f);
        float wy = fminf(fmaxf(1.f - fabsf(iy), 0.f), 1.f);
        wgtl[p0 + lo16] = wx * wy;
      }
    }
    if (hf == 0) {  // att: own 4 heads
#pragma unroll
      for (int i = 0; i < 4; ++i) {
        int hh = tph * 4 + i;
        bf16x8 qf = *(const bf16x8*)(Qslab + ((lo16 * 512 + hh * 64 + g * 16) ^ swzq));
        const char* cp = CTXT + (b * 8 + hh) * 2048 + l * 16;
        bf16x8 c0 = *(const bf16x8*)(cp);
        bf16x8 c1 = *(const bf16x8*)(cp + 1024);
        macc[i * 2] = MFMA(c0, qf, macc[i * 2]);
        macc[i * 2 + 1] = MFMA(c1, qf, macc[i * 2 + 1]);
      }
    }
    __syncthreads();  // (C) wgtl ready
    if (hf == 0) {
      float wv = wgtl[p0 + lo16];
      if (b == 0) wg0 = wv; else wg1 = wv;
    }
  }
  // attS (hf==0, own 4 heads) -> Qslab
  if (hf == 0) {
#pragma unroll
    for (int i = 0; i < 4; ++i) {
      int hh = tph * 4 + i;
#pragma unroll
      for (int m = 0; m < 2; ++m) {
        f32x4 v = macc[i * 2 + m];
        uint2 wv;
        wv.x = pack2(v[0], v[1]); wv.y = pack2(v[2], v[3]);
        int byte = (lo16 * 512 + hh * 64 + m * 32 + g * 8) ^ swzq;
        *(uint2*)(Qslab + byte) = wv;
      }
    }
  }
  __syncthreads();  // (D)
  const float* bo = wsf + (B_BIASO / 4);
  const size_t rowaddr = (size_t)(n0 + p0 + lo16) * 512;
#pragma unroll
  for (int tp = 0; tp < 4; ++tp) {
    int tq = tph * 4 + tp;
    int ch0 = hf * 256 + tq * 32, ch1 = ch0 + 16;
    int T0 = hf * 16 + tq * 2;
    f32x4 r0 = {0.f, 0.f, 0.f, 0.f}, r1 = {0.f, 0.f, 0.f, 0.f};
    const char* ap = WRp + T0 * 8192 + l * 16;
#pragma unroll
    for (int ks = 0; ks < 8; ++ks) {
      bf16x8 brf = *(const bf16x8*)(Qslab + ((lo16 * 512 + g * 16 + ks * 64) ^ swzq));
      bf16x8 a0 = *(const bf16x8*)(ap + ks * 1024);
      bf16x8 a1 = *(const bf16x8*)(ap + 8192 + ks * 1024);
      r0 = MFMA(a0, brf, r0);
      r1 = MFMA(a1, brf, r1);
    }
#pragma unroll
    for (int half = 0; half < 2; ++half) {
      int cb = (half ? ch1 : ch0) + g * 4;
      f32x4 rr = half ? r1 : r0;
      f32x4 xr = *(const f32x4*)(x + rowaddr + cb);
      f32x4 yr = *(const f32x4*)(y + rowaddr + cb);
      f32x4 bb = *(const f32x4*)(bo + cb);
      f32x4 extra;
      if (hf == 0) {
        f32x4 h20 = *(const f32x4*)(wsf + (B_HIGH2 / 4) + cb);
        f32x4 h21 = *(const f32x4*)(wsf + (B_HIGH2 / 4) + 256 + cb);
        extra = (0.25f * wg0) * h20 + (0.25f * wg1) * h21;
      } else {
        extra = macc[tp * 2 + half];
      }
      f32x4 vout = extra + 0.25f * rr + 0.25f * (xr + yr) + bb;
      *(f32x4*)(out + rowaddr + cb) = vout;
    }
  }
}

extern "C" void kernel_launch(void* const* d_in, const int* in_sizes, int n_in,
                              void* d_out, int out_size, void* d_ws, size_t ws_size,
                              hipStream_t stream) {
  const float* x = (const float*)d_in[0];
  const float* y = (const float*)d_in[1];
  const float* ea_wk = (const float*)d_in[2];
  const float* ea_bk = (const float*)d_in[3];
  const float* ea_wq = (const float*)d_in[4];
  const float* ea_bq = (const float*)d_in[5];
  const float* ea_wv = (const float*)d_in[6];
  const float* ea_bv = (const float*)d_in[7];
  const float* ea_wr = (const float*)d_in[8];
  const float* ea_br = (const float*)d_in[9];
  const float* pool_w1 = (const float*)d_in[10];
  const float* pool_bn1 = (const float*)d_in[11];
  const float* pool_w2 = (const float*)d_in[12];
  const float* pool_bn2 = (const float*)d_in[13];
  const float* adapt_w1 = (const float*)d_in[14];
  const float* adapt_bn1 = (const float*)d_in[15];
  const float* adapt_w2 = (const float*)d_in[16];
  const float* adapt_bn2 = (const float*)d_in[17];
  const float* delta_w1 = (const float*)d_in[18];
  const float* delta_bn1 = (const float*)d_in[19];
  const float* delta_w2 = (const float*)d_in[20];
  char* ws = (char*)d_ws;
  float* out = (float*)d_out;

  kW1<<<256, 512, 0, stream>>>(adapt_w1, adapt_bn1, adapt_w2, adapt_bn2, ws);
  kW2<<<1, 512, 0, stream>>>(delta_w1, delta_bn1, delta_w2, ws);
  kPack<<<4384, 256, 0, stream>>>(ea_wq, ea_wk, ea_wv, ea_wr, pool_w1, pool_w2, delta_w1, ws);
  k1_reduce<<<1024, 512, 0, stream>>>(x, y, ea_bk, ea_bv, ws, out);
  k1b<<<67, 512, 0, stream>>>(out, ws);
  k2_finalize<<<1, 512, 0, stream>>>(pool_bn1, pool_bn2, delta_bn1, delta_w2, ea_br, ws);
  k3_main<<<1024, 512, 0, stream>>>(x, y, ea_bq, ws, out);
}

// Round 10
// 485.017 us; speedup vs baseline: 6.7358x; 1.4274x over previous
//
#include <hip/hip_runtime.h>
#include <math.h>

// ---------------- ws byte offsets ----------------
#define B_CTXC   0          // single summed ctx [2][8][32][32] f32 = 65536 B
#define B_ZP     524288     // [2][256] f32
#define B_COLS   526336     // [2][512] f32
#define B_HIGH2  530432     // [2][256] f32
#define B_CONSTD 532480     // [2][2] f32 (+pad)
#define B_BIASO  532544     // [512] f32
#define B_CPP    534592     // [256] f32 (c'')
#define B_CTXT   535616     // [2][8] x 2 tiles x 1KB bf16, fragment-linear
#define B_WDD    568384     // [2][256] f32
#define B_WDX    570432     // [2][512] f32
#define B_WL     574528     // [256][512] f32 (W_L'')
#define B_WBIG   1098816    // 33 tiles x 16KB bf16, fragment-linear
#define B_WKV    1639488    // 32 tiles x 16KB bf16, fragment-linear
#define B_WR     2163776    // 32 tiles x 8KB bf16, fragment-linear
#define B_PW1T   2425920    // [512][512] f32 transposed
#define B_PW2T   3474496    // [512][256] f32 transposed
#define B_D1BT   3998784    // [256][256] f32 transposed
// d_out scratch (before k3 overwrites): [1024][8192] u32 ctx partials at u32
// index 0 (32MB), [1024][1536] f32 red partials at float offset 8388608.

typedef __attribute__((ext_vector_type(8))) short bf16x8;
typedef __attribute__((ext_vector_type(4))) float f32x4;

#define MFMA(a, b, c) __builtin_amdgcn_mfma_f32_16x16x32_bf16(a, b, c, 0, 0, 0)

__device__ inline unsigned f2bfu(float f) {
  unsigned u = __float_as_uint(f);
  return (u + 0x7FFFu + ((u >> 16) & 1u)) >> 16;
}
__device__ inline unsigned pack2(float a, float b) { return f2bfu(a) | (f2bfu(b) << 16); }

// ---------------- kW1: W_L'' (fp32) + c'' ----------------
__global__ __launch_bounds__(512) void kW1(
    const float* __restrict__ a1, const float* __restrict__ abn1,
    const float* __restrict__ a2, const float* __restrict__ abn2,
    char* __restrict__ wsb) {
  __shared__ float S1[512], F1[512], redu[512];
  const int t = threadIdx.x, o = blockIdx.x;
  float* wsf = (float*)wsb;
  {
    float gg = abn1[t], be = abn1[512 + t], mn = abn1[1024 + t], va = abn1[1536 + t];
    float s = gg * rsqrtf(va + 1e-5f);
    S1[t] = s; F1[t] = be - mn * s;
  }
  float g2 = abn2[o], be2 = abn2[256 + o], mn2 = abn2[512 + o], va2 = abn2[768 + o];
  float s2 = g2 * rsqrtf(va2 + 1e-5f);
  float f2v = be2 - mn2 * s2;
  __syncthreads();
  float acc = 0.f;
  const float* a2r = a2 + o * 512;
  for (int m = 0; m < 512; ++m) acc = fmaf(a2r[m] * S1[m], a1[m * 512 + t], acc);
  wsf[(B_WL / 4) + o * 512 + t] = s2 * acc;
  redu[t] = a2r[t] * F1[t];
  __syncthreads();
  for (int sft = 256; sft >= 1; sft >>= 1) {
    if (t < sft) redu[t] += redu[t + sft];
    __syncthreads();
  }
  if (t == 0) wsf[(B_CPP / 4) + o] = s2 * redu[0] + f2v;
}

// ---------------- kW2: W_dd, W_dx ----------------
__global__ __launch_bounds__(512) void kW2(
    const float* __restrict__ d1, const float* __restrict__ dbn1,
    const float* __restrict__ d2, char* __restrict__ wsb) {
  __shared__ float SD[256], WDDl[512];
  const int t = threadIdx.x;
  float* wsf = (float*)wsb;
  if (t < 256) {
    float gg = dbn1[t], va = dbn1[768 + t];
    SD[t] = gg * rsqrtf(va + 1e-5f);
  }
  __syncthreads();
  {
    int j = t >> 8, v = t & 255;
    float acc = 0.f;
    for (int o = 0; o < 256; ++o) acc = fmaf(d2[j * 256 + o] * SD[o], d1[o * 512 + v], acc);
    WDDl[t] = acc;
    wsf[(B_WDD / 4) + t] = acc;
  }
  __syncthreads();
  {
    int c = t;
    float acc0 = 0.f, acc1 = 0.f;
    for (int v = 0; v < 256; ++v) {
      float wl = wsf[(B_WL / 4) + v * 512 + c];
      acc0 = fmaf(WDDl[v], wl, acc0);
      acc1 = fmaf(WDDl[256 + v], wl, acc1);
    }
    wsf[(B_WDX / 4) + c] = acc0;
    wsf[(B_WDX / 4) + 512 + c] = acc1;
  }
}

// ---------------- kPack: fragment-linear bf16 packs + fp32 transposes ----------------
__global__ __launch_bounds__(256) void kPack(
    const float* __restrict__ wq, const float* __restrict__ wk, const float* __restrict__ wv,
    const float* __restrict__ wr, const float* __restrict__ pw1, const float* __restrict__ pw2,
    const float* __restrict__ d1, char* __restrict__ wsb) {
  int i = blockIdx.x * 256 + threadIdx.x;
  float* wsf = (float*)wsb;
  unsigned short* u16 = (unsigned short*)wsb;
  if (i < 270336) {  // Wbig: 33 tiles, K=512 (ks 0..15)
    int T = i >> 13, r = i & 8191;
    int ks = r >> 9, l = (r >> 3) & 63, j = r & 7;
    int row = T * 16 + (l & 15);
    int col = ks * 32 + (l >> 4) * 8 + j;
    float v;
    if (row < 256) v = wq[row * 512 + col];
    else if (row < 512) v = wsf[(B_WL / 4) + (row - 256) * 512 + col];
    else if (row < 514) v = wsf[(B_WDX / 4) + (row - 512) * 512 + col];
    else v = 0.f;
    u16[(B_WBIG / 2) + i] = (unsigned short)f2bfu(v);
    return;
  }
  i -= 270336;
  if (i < 262144) {  // Wkv: 32 tiles, K=512
    int T = i >> 13, r = i & 8191;
    int ks = r >> 9, l = (r >> 3) & 63, j = r & 7;
    int row = T * 16 + (l & 15);
    int col = ks * 32 + (l >> 4) * 8 + j;
    float v = row < 256 ? wk[row * 512 + col] : wv[(row - 256) * 512 + col];
    u16[(B_WKV / 2) + i] = (unsigned short)f2bfu(v);
    return;
  }
  i -= 262144;
  if (i < 131072) {  // WR: 32 tiles, K=256 (ks 0..7)
    int T = i >> 12, r = i & 4095;
    int ks = r >> 9, l = (r >> 3) & 63, j = r & 7;
    int row = T * 16 + (l & 15);
    int col = ks * 32 + (l >> 4) * 8 + j;
    u16[(B_WR / 2) + i] = (unsigned short)f2bfu(wr[row * 256 + col]);
    return;
  }
  i -= 131072;
  if (i < 262144) { int o = i >> 9, c = i & 511; wsf[(B_PW1T / 4) + c * 512 + o] = pw1[i]; return; }
  i -= 262144;
  if (i < 131072) { int o = i >> 9, c = i & 511; wsf[(B_PW2T / 4) + c * 256 + o] = pw2[i]; return; }
  i -= 131072;
  if (i < 65536) { int o = i >> 8, v = i & 255; wsf[(B_D1BT / 4) + v * 256 + o] = d1[o * 512 + 256 + v]; }
}

// ---------------- k1: b-merged keys/values MFMA + transient ctx ----------------
__global__ __launch_bounds__(512, 1) void k1_reduce(
    const float* __restrict__ x, const float* __restrict__ y,
    const float* __restrict__ bk, const float* __restrict__ bv,
    const char* __restrict__ wsb, float* __restrict__ outp) {
  __shared__ __align__(16) unsigned char Xl[32768];
  __shared__ __align__(16) unsigned char Yl[32768];
  __shared__ __align__(16) unsigned char elx[16384];
  __shared__ __align__(16) unsigned char ely[16384];
  __shared__ __align__(16) unsigned char vlx[16384];
  __shared__ __align__(16) unsigned char vly[16384];
  __shared__ float Red[1536];  // [0..511]=Z(b0,b1), [512..1535]=colsum
  const int t = threadIdx.x;
  const int w = t >> 6, lo16 = t & 15, g = (t >> 4) & 3, l = t & 63;
  const int pt = w & 1, tph = (w >> 1) & 1, hf = w >> 2;
  const int p0 = pt * 16;
  const char* Wkv = wsb + B_WKV;

  for (int i = t; i < 1536; i += 512) Red[i] = 0.f;
  float csum[2][8];
#pragma unroll
  for (int b2 = 0; b2 < 2; ++b2)
#pragma unroll
    for (int i = 0; i < 8; ++i) csum[b2][i] = 0.f;
  const int n0 = blockIdx.x * 32;
  const int rowX = p0 + lo16;
  const int bbase = rowX * 1024 + g * 16;
  const int bswz = (rowX & 7) << 4;
  __syncthreads();  // Red init visible

  // ---- stage x AND y tiles, column sums ----
#pragma unroll
  for (int r = 0; r < 4; ++r) {
    int chunk = r * 512 + t;
    int prow = chunk >> 6, j = chunk & 63;
    const float* gx = x + (size_t)(n0 + prow) * 512 + j * 8;
    const float* gy = y + (size_t)(n0 + prow) * 512 + j * 8;
    float4 x0 = *(const float4*)gx, x1 = *(const float4*)(gx + 4);
    float4 y0 = *(const float4*)gy, y1 = *(const float4*)(gy + 4);
    csum[0][0] += x0.x; csum[0][1] += x0.y; csum[0][2] += x0.z; csum[0][3] += x0.w;
    csum[0][4] += x1.x; csum[0][5] += x1.y; csum[0][6] += x1.z; csum[0][7] += x1.w;
    csum[1][0] += y0.x; csum[1][1] += y0.y; csum[1][2] += y0.z; csum[1][3] += y0.w;
    csum[1][4] += y1.x; csum[1][5] += y1.y; csum[1][6] += y1.z; csum[1][7] += y1.w;
    int byte = (prow * 1024 + j * 16) ^ ((prow & 7) << 4);
    uint4 pk;
    pk.x = pack2(x0.x, x0.y); pk.y = pack2(x0.z, x0.w);
    pk.z = pack2(x1.x, x1.y); pk.w = pack2(x1.z, x1.w);
    *(uint4*)(Xl + byte) = pk;
    pk.x = pack2(y0.x, y0.y); pk.y = pack2(y0.z, y0.w);
    pk.z = pack2(y1.x, y1.y); pk.w = pack2(y1.z, y1.w);
    *(uint4*)(Yl + byte) = pk;
  }
  // colsum partials -> Red (channel = (t&63)*8 + i)
#pragma unroll
  for (int b = 0; b < 2; ++b)
#pragma unroll
    for (int i = 0; i < 8; ++i) atomicAdd(&Red[512 + b * 512 + (t & 63) * 8 + i], csum[b][i]);
  __syncthreads();

  // ---- merged GEMM: each weight fragment -> 2 MFMAs (x and y) ----
#pragma unroll
  for (int tp = 0; tp < 4; ++tp) {
    int tq = tph * 4 + tp;
    int t0 = hf * 16 + tq * 2, t1 = t0 + 1;
    f32x4 ax0 = {0.f, 0.f, 0.f, 0.f}, ax1 = {0.f, 0.f, 0.f, 0.f};
    f32x4 ay0 = {0.f, 0.f, 0.f, 0.f}, ay1 = {0.f, 0.f, 0.f, 0.f};
    const char* ap = Wkv + t0 * 16384 + l * 16;
#pragma unroll
    for (int ks = 0; ks < 16; ++ks) {
      bf16x8 bx = *(const bf16x8*)(Xl + ((bbase + ks * 64) ^ bswz));
      bf16x8 by = *(const bf16x8*)(Yl + ((bbase + ks * 64) ^ bswz));
      bf16x8 af0 = *(const bf16x8*)(ap + ks * 1024);
      bf16x8 af1 = *(const bf16x8*)(ap + 16384 + ks * 1024);
      ax0 = MFMA(af0, bx, ax0); ay0 = MFMA(af0, by, ay0);
      ax1 = MFMA(af1, bx, ax1); ay1 = MFMA(af1, by, ay1);
    }
    int pp = p0 + lo16;
    if (hf == 0) {  // keys -> e, Z, el (both b)
      float ex0[4], ex1[4], ey0[4], ey1[4];
#pragma unroll
      for (int r = 0; r < 4; ++r) {
        float bk0 = bk[t0 * 16 + g * 4 + r], bk1 = bk[t1 * 16 + g * 4 + r];
        ex0[r] = __expf(ax0[r] + bk0); ey0[r] = __expf(ay0[r] + bk0);
        ex1[r] = __expf(ax1[r] + bk1); ey1[r] = __expf(ay1[r] + bk1);
      }
#pragma unroll
      for (int r = 0; r < 4; ++r) {
        float v0 = ex0[r], v1 = ex1[r], v2 = ey0[r], v3 = ey1[r];
        for (int m = 8; m >= 1; m >>= 1) {
          v0 += __shfl_xor(v0, m, 16); v1 += __shfl_xor(v1, m, 16);
          v2 += __shfl_xor(v2, m, 16); v3 += __shfl_xor(v3, m, 16);
        }
        if (lo16 == 0) {
          atomicAdd(&Red[t0 * 16 + g * 4 + r], v0);
          atomicAdd(&Red[t1 * 16 + g * 4 + r], v1);
          atomicAdd(&Red[256 + t0 * 16 + g * 4 + r], v2);
          atomicAdd(&Red[256 + t1 * 16 + g * 4 + r], v3);
        }
      }
#pragma unroll
      for (int r = 0; r < 4; ++r) {
        int row0 = t0 * 16 + g * 4 + r;
        int row1 = t1 * 16 + g * 4 + r;
        int a0 = (row0 * 64 + pp * 2) ^ ((row0 & 3) << 4);
        int a1 = (row1 * 64 + pp * 2) ^ ((row1 & 3) << 4);
        *(unsigned short*)(elx + a0) = (unsigned short)f2bfu(ex0[r]);
        *(unsigned short*)(elx + a1) = (unsigned short)f2bfu(ex1[r]);
        *(unsigned short*)(ely + a0) = (unsigned short)f2bfu(ey0[r]);
        *(unsigned short*)(ely + a1) = (unsigned short)f2bfu(ey1[r]);
      }
    } else {  // values -> vl (both b)
#pragma unroll
      for (int r = 0; r < 4; ++r) {
        int row0 = (t0 - 16) * 16 + g * 4 + r;
        int row1 = (t1 - 16) * 16 + g * 4 + r;
        float bv0 = bv[row0], bv1 = bv[row1];
        int a0 = (row0 * 64 + pp * 2) ^ ((row0 & 3) << 4);
        int a1 = (row1 * 64 + pp * 2) ^ ((row1 & 3) << 4);
        *(unsigned short*)(vlx + a0) = (unsigned short)f2bfu(ax0[r] + bv0);
        *(unsigned short*)(vlx + a1) = (unsigned short)f2bfu(ax1[r] + bv1);
        *(unsigned short*)(vly + a0) = (unsigned short)f2bfu(ay0[r] + bv0);
        *(unsigned short*)(vly + a1) = (unsigned short)f2bfu(ay1[r] + bv1);
      }
    }
  }
  __syncthreads();  // el/vl + Red complete

  // ---- transient ctx: per (b,m): 2 MFMAs -> immediate store ----
  {
    const int h = w;
    unsigned* ctxp = (unsigned*)outp + (size_t)blockIdx.x * 8192;
#pragma unroll
    for (int b = 0; b < 2; ++b) {
      const unsigned char* el = b ? ely : elx;
      const unsigned char* vl = b ? vly : vlx;
#pragma unroll
      for (int m = 0; m < 2; ++m) {
        int rowe = h * 32 + m * 16 + lo16;
        bf16x8 ea = *(const bf16x8*)(el + ((rowe * 64 + g * 16) ^ ((rowe & 3) << 4)));
        f32x4 c0 = {0.f, 0.f, 0.f, 0.f}, c1 = {0.f, 0.f, 0.f, 0.f};
        {
          int rowv = h * 32 + lo16;
          bf16x8 vb = *(const bf16x8*)(vl + ((rowv * 64 + g * 16) ^ ((rowv & 3) << 4)));
          c0 = MFMA(ea, vb, c0);
        }
        {
          int rowv = h * 32 + 16 + lo16;
          bf16x8 vb = *(const bf16x8*)(vl + ((rowv * 64 + g * 16) ^ ((rowv & 3) << 4)));
          c1 = MFMA(ea, vb, c1);
        }
#pragma unroll
        for (int r = 0; r < 4; ++r)
          ctxp[((b * 2 + m) * 4 + r) * 512 + t] = pack2(c0[r], c1[r]);
      }
    }
    float* redp = outp + 8388608 + blockIdx.x * 1536;
    for (int i = t; i < 1536; i += 512) redp[i] = Red[i];
  }
}

// ---------------- k1b: tree-reduce the 1024 partial copies ----------------
__global__ __launch_bounds__(512) void k1b(const float* __restrict__ outp, char* __restrict__ wsb) {
  __shared__ float R[512];
  const int t = threadIdx.x, blk = blockIdx.x;
  float* wsf = (float*)wsb;
  if (blk < 64) {  // ctx: 128 slots per block, 4 partial-sum lanes each
    int sl = t & 127, part = t >> 7;
    int slot = blk * 128 + sl;
    const unsigned* p = (const unsigned*)outp;
    float s0 = 0.f, s1 = 0.f;
    for (int c = part * 256; c < part * 256 + 256; ++c) {
      unsigned wv = p[(size_t)c * 8192 + slot];
      s0 += __uint_as_float(wv << 16);
      s1 += __uint_as_float(wv & 0xffff0000u);
    }
    R[sl * 4 + part] = s0;
    __syncthreads();
    float sum0 = R[sl * 4] + R[sl * 4 + 1] + R[sl * 4 + 2] + R[sl * 4 + 3];
    __syncthreads();
    R[sl * 4 + part] = s1;
    __syncthreads();
    float sum1 = R[sl * 4] + R[sl * 4 + 1] + R[sl * 4 + 2] + R[sl * 4 + 3];
    if (part == 0) {
      int t_ = slot & 511, bmr = slot >> 9;
      int r = bmr & 3, m = (bmr >> 2) & 1, b = bmr >> 3;
      int h = t_ >> 6, g = (t_ >> 4) & 3, lo16 = t_ & 15;
      int klocal = m * 16 + g * 4 + r;
      int base = ((b * 8 + h) * 32 + klocal) * 32;
      wsf[(B_CTXC / 4) + base + lo16] = sum0;
      wsf[(B_CTXC / 4) + base + 16 + lo16] = sum1;
    }
  } else {  // red: 3 blocks x 512 values
    int j = (blk - 64) * 512 + t;
    const float* rp = outp + 8388608;
    float s = 0.f;
    for (int c = 0; c < 1024; ++c) s += rp[(size_t)c * 1536 + j];
    if (j < 512) wsf[(B_ZP / 4) + j] = s;
    else wsf[(B_COLS / 4) + (j - 512)] = s;
  }
}

// ---------------- k2: ctx normalize (packed write), pool chain, constD, biasOut ----------------
__global__ __launch_bounds__(512) void k2_finalize(
    const float* __restrict__ pbn1, const float* __restrict__ pbn2,
    const float* __restrict__ dbn1, const float* __restrict__ d2,
    const float* __restrict__ ea_br, char* __restrict__ wsb) {
  __shared__ float HI[1024], H1[1024], H2l[512], VB[512], slot[4];
  const int t = threadIdx.x;
  float* wsf = (float*)wsb;
  unsigned short* u16 = (unsigned short*)wsb;
  for (int idx = t; idx < 16384; idx += 512) {
    float s = wsf[(B_CTXC / 4) + idx];
    int v = idx & 31, row = idx >> 5;
    int b = row >> 8, kr = row & 255;
    int hh = kr >> 5, kh = kr & 31;
    float val = s / wsf[(B_ZP / 4) + b * 256 + kr];
    int m = v >> 4;
    int lane = (v & 15) + ((kh >> 3) << 4);
    int j = kh & 7;
    u16[(B_CTXT / 2) + (((b * 8 + hh) * 2 + m) << 9) + lane * 8 + j] = (unsigned short)f2bfu(val);
  }
  if (t < 4) slot[t] = 0.f;
  for (int idx = t; idx < 1024; idx += 512) HI[idx] = wsf[(B_COLS / 4) + idx] * (1.f / 32768.f);
  __syncthreads();
  {
    int o = t;
    float gg = pbn1[o], be = pbn1[512 + o], mn = pbn1[1024 + o], va = pbn1[1536 + o];
    float sc = gg * rsqrtf(va + 1e-5f), sh = be - mn * sc;
    for (int b = 0; b < 2; ++b) {
      float acc = 0.f;
      for (int c = 0; c < 512; ++c) acc = fmaf(wsf[(B_PW1T / 4) + c * 512 + o], HI[b * 512 + c], acc);
      H1[b * 512 + o] = acc * sc + sh;
    }
  }
  __syncthreads();
  if (t < 256) {
    int o = t;
    float gg = pbn2[o], be = pbn2[256 + o], mn = pbn2[512 + o], va = pbn2[768 + o];
    float sc = gg * rsqrtf(va + 1e-5f), sh = be - mn * sc;
    for (int b = 0; b < 2; ++b) {
      float acc = 0.f;
      for (int c = 0; c < 512; ++c) acc = fmaf(wsf[(B_PW2T / 4) + c * 256 + o], H1[b * 512 + c], acc);
      float vv = acc * sc + sh;
      H2l[b * 256 + o] = vv;
      wsf[(B_HIGH2 / 4) + b * 256 + o] = vv;
    }
  }
  __syncthreads();
  if (t < 256) {
    int o = t;
    float gg = dbn1[o], be = dbn1[256 + o], mn = dbn1[512 + o], va = dbn1[768 + o];
    float sd = gg * rsqrtf(va + 1e-5f), fd = be - mn * sd;
    for (int b = 0; b < 2; ++b) {
      float acc = 0.f;
      for (int v = 0; v < 256; ++v) acc = fmaf(wsf[(B_D1BT / 4) + v * 256 + o], H2l[b * 256 + v], acc);
      VB[b * 256 + o] = sd * acc + fd;
    }
  }
  __syncthreads();
  if (t < 256) {
    int o = t;
    for (int b = 0; b < 2; ++b)
      for (int j = 0; j < 2; ++j) atomicAdd(&slot[b * 2 + j], d2[j * 256 + o] * VB[b * 256 + o]);
    float cp = wsf[(B_CPP / 4) + o];
    for (int j = 0; j < 2; ++j) {
      float w = wsf[(B_WDD / 4) + j * 256 + o] * cp;
      atomicAdd(&slot[0 + j], w);
      atomicAdd(&slot[2 + j], w);
    }
  }
  __syncthreads();
  if (t < 4) wsf[(B_CONSTD / 4) + t] = slot[t];
  {
    int o = t;
    float bb = 0.5f * ea_br[o];
    if (o >= 256) bb += 0.5f * wsf[(B_CPP / 4) + o - 256];
    wsf[(B_BIASO / 4) + o] = bb;
  }
}

// ---------------- k3: b-merged main pass, LDS f32 accumulator ----------------
__global__ __launch_bounds__(512, 1) void k3_main(
    const float* __restrict__ x, const float* __restrict__ y,
    const float* __restrict__ bq, const char* __restrict__ wsb,
    float* __restrict__ out) {
  __shared__ __align__(16) unsigned char Xl[32768];
  __shared__ __align__(16) unsigned char Yl[32768];
  __shared__ __align__(16) unsigned char ACCb[65536];  // f32 [32 pos][512 ch], swizzled
  __shared__ __align__(16) unsigned char Ql[16384];
  __shared__ float wgtl[64];  // [b][pos]
  const int t = threadIdx.x;
  const int w = t >> 6, lo16 = t & 15, g = (t >> 4) & 3, l = t & 63;
  const int pt = w & 1, tph = (w >> 1) & 1, hf = w >> 2;
  const int p0 = pt * 16;
  const int n0 = blockIdx.x * 32;
  const char* Wbig = wsb + B_WBIG;
  const char* WRp = wsb + B_WR;
  const char* CTXT = wsb + B_CTXT;
  const float* wsf = (const float*)wsb;
  unsigned char* Qslab = Ql + pt * 8192;
  const int rowX = p0 + lo16;
  const int bbase = rowX * 1024 + g * 16;
  const int bswz = (rowX & 7) << 4;
  const int swzq = (lo16 & 7) << 4;

  // ---- stage x,y; init ACC = 0.25*(x+y) ----
#pragma unroll
  for (int r = 0; r < 4; ++r) {
    int chunk = r * 512 + t;
    int prow = chunk >> 6, j = chunk & 63;
    const float* gx = x + (size_t)(n0 + prow) * 512 + j * 8;
    const float* gy = y + (size_t)(n0 + prow) * 512 + j * 8;
    float4 x0 = *(const float4*)gx, x1 = *(const float4*)(gx + 4);
    float4 y0 = *(const float4*)gy, y1 = *(const float4*)(gy + 4);
    int byte = (prow * 1024 + j * 16) ^ ((prow & 7) << 4);
    uint4 pk;
    pk.x = pack2(x0.x, x0.y); pk.y = pack2(x0.z, x0.w);
    pk.z = pack2(x1.x, x1.y); pk.w = pack2(x1.z, x1.w);
    *(uint4*)(Xl + byte) = pk;
    pk.x = pack2(y0.x, y0.y); pk.y = pack2(y0.z, y0.w);
    pk.z = pack2(y1.x, y1.y); pk.w = pack2(y1.z, y1.w);
    *(uint4*)(Yl + byte) = pk;
    // ACC init: XOR applied to EACH address (bugfix from R9: no +16 after XOR)
    int abase = prow * 2048 + j * 32;
    int aswz = (prow & 7) << 4;
    f32x4 a0 = {0.25f * (x0.x + y0.x), 0.25f * (x0.y + y0.y), 0.25f * (x0.z + y0.z), 0.25f * (x0.w + y0.w)};
    f32x4 a1 = {0.25f * (x1.x + y1.x), 0.25f * (x1.y + y1.y), 0.25f * (x1.z + y1.z), 0.25f * (x1.w + y1.w)};
    *(f32x4*)(ACCb + (abase ^ aswz)) = a0;
    *(f32x4*)(ACCb + ((abase + 16) ^ aswz)) = a1;
  }
  __syncthreads();

  unsigned Qy[4][4];  // packed Q for b=1, per tp

  // ---- merged tp loop ----
#pragma unroll
  for (int tp = 0; tp < 4; ++tp) {
    int tq = tph * 4 + tp;
    int t0 = hf * 16 + tq * 2;
    f32x4 ax0 = {0.f, 0.f, 0.f, 0.f}, ax1 = {0.f, 0.f, 0.f, 0.f};
    f32x4 ay0 = {0.f, 0.f, 0.f, 0.f}, ay1 = {0.f, 0.f, 0.f, 0.f};
    const char* ap = Wbig + t0 * 16384 + l * 16;
#pragma unroll
    for (int ks = 0; ks < 16; ++ks) {
      bf16x8 bx = *(const bf16x8*)(Xl + ((bbase + ks * 64) ^ bswz));
      bf16x8 by = *(const bf16x8*)(Yl + ((bbase + ks * 64) ^ bswz));
      bf16x8 af0 = *(const bf16x8*)(ap + ks * 1024);
      bf16x8 af1 = *(const bf16x8*)(ap + 16384 + ks * 1024);
      ax0 = MFMA(af0, bx, ax0); ay0 = MFMA(af0, by, ay0);
      ax1 = MFMA(af1, bx, ax1); ay1 = MFMA(af1, by, ay1);
    }
    if (hf == 0) {  // Q head tq: softmax both b; store b0 now, keep b1 packed
      int hh = tq;
#pragma unroll
      for (int b = 0; b < 2; ++b) {
        f32x4 a0 = b ? ay0 : ax0, a1 = b ? ay1 : ax1;
        float q[8], e[8];
        float mx = -1e30f;
#pragma unroll
        for (int r = 0; r < 4; ++r) {
          q[r] = a0[r] + bq[hh * 32 + g * 4 + r];
          q[4 + r] = a1[r] + bq[hh * 32 + 16 + g * 4 + r];
          mx = fmaxf(mx, fmaxf(q[r], q[4 + r]));
        }
        mx = fmaxf(mx, __shfl_xor(mx, 16, 64));
        mx = fmaxf(mx, __shfl_xor(mx, 32, 64));
        float sm = 0.f;
#pragma unroll
        for (int r = 0; r < 8; ++r) { e[r] = __expf(q[r] - mx); sm += e[r]; }
        sm += __shfl_xor(sm, 16, 64);
        sm += __shfl_xor(sm, 32, 64);
        float inv = 1.f / sm;
        unsigned p0w = pack2(e[0] * inv, e[1] * inv), p1w = pack2(e[2] * inv, e[3] * inv);
        unsigned p2w = pack2(e[4] * inv, e[5] * inv), p3w = pack2(e[6] * inv, e[7] * inv);
        if (b == 0) {
          int base_q = lo16 * 512 + hh * 64 + g * 8;
          uint2 w0; w0.x = p0w; w0.y = p1w;
          uint2 w1; w1.x = p2w; w1.y = p3w;
          *(uint2*)(Qslab + (base_q ^ swzq)) = w0;
          *(uint2*)(Qslab + ((base_q + 32) ^ swzq)) = w1;
        } else {
          Qy[tp][0] = p0w; Qy[tp][1] = p1w; Qy[tp][2] = p2w; Qy[tp][3] = p3w;
        }
      }
    } else {  // L tiles: accumulate 0.25*(Lx+Ly) into ACC
      int tile0 = t0 - 16;  // 0..15 (even)
#pragma unroll
      for (int half = 0; half < 2; ++half) {
        f32x4 axs = half ? ax1 : ax0;
        f32x4 ays = half ? ay1 : ay0;
        int ch4 = 64 + (tile0 + half) * 4 + g;  // ch = 256 + tile*16 + g*4
        int ab = ((p0 + lo16) * 2048 + ch4 * 16) ^ (((p0 + lo16) & 7) << 4);
        f32x4 cur = *(const f32x4*)(ACCb + ab);
        cur += 0.25f * (axs + ays);
        *(f32x4*)(ACCb + ab) = cur;
      }
    }
  }

  // ---- delta (hf1, tph0): both b, one weight read ----
  if (hf == 1 && tph == 0) {
    f32x4 adx = {0.f, 0.f, 0.f, 0.f}, ady = {0.f, 0.f, 0.f, 0.f};
    const char* ap = Wbig + 32 * 16384 + l * 16;
#pragma unroll
    for (int ks = 0; ks < 16; ++ks) {
      bf16x8 bx = *(const bf16x8*)(Xl + ((bbase + ks * 64) ^ bswz));
      bf16x8 by = *(const bf16x8*)(Yl + ((bbase + ks * 64) ^ bswz));
      bf16x8 af = *(const bf16x8*)(ap + ks * 1024);
      adx = MFMA(af, bx, adx);
      ady = MFMA(af, by, ady);
    }
    if (g == 0) {
      int pos = n0 + p0 + lo16;
      float base_gx = -1.f + 2.f * (float)pos / 32767.f;
#pragma unroll
      for (int b = 0; b < 2; ++b) {
        f32x4 ad = b ? ady : adx;
        float d0 = ad[0] + wsf[(B_CONSTD / 4) + b * 2 + 0];
        float d1 = ad[1] + wsf[(B_CONSTD / 4) + b * 2 + 1];
        float gxv = base_gx + d0;
        float gyv = -1.f + d1;
        float ix = gxv * 0.5f, iy = gyv * 0.5f;
        float wx = fminf(fmaxf(1.f - fabsf(ix), 0.f), 1.f);
        float wy = fminf(fmaxf(1.f - fabsf(iy), 0.f), 1.f);
        wgtl[b * 32 + p0 + lo16] = wx * wy;
      }
    }
  }

  // ---- att (hf0): in-wave Q->att, b=0 from Qslab then b=1 ----
  f32x4 attacc[4][2];
#pragma unroll
  for (int i = 0; i < 4; ++i)
#pragma unroll
    for (int m = 0; m < 2; ++m) attacc[i][m] = (f32x4){0.f, 0.f, 0.f, 0.f};
  if (hf == 0) {
#pragma unroll
    for (int i = 0; i < 4; ++i) {
      int hh = tph * 4 + i;
      bf16x8 qf = *(const bf16x8*)(Qslab + ((lo16 * 512 + hh * 64 + g * 16) ^ swzq));
      const char* cp = CTXT + (0 * 8 + hh) * 2048 + l * 16;
      bf16x8 c0 = *(const bf16x8*)(cp);
      bf16x8 c1 = *(const bf16x8*)(cp + 1024);
      attacc[i][0] = MFMA(c0, qf, attacc[i][0]);
      attacc[i][1] = MFMA(c1, qf, attacc[i][1]);
    }
    // overwrite with Q_y (same-wave LDS roundtrip)
#pragma unroll
    for (int tp = 0; tp < 4; ++tp) {
      int hh = tph * 4 + tp;
      int base_q = lo16 * 512 + hh * 64 + g * 8;
      uint2 w0; w0.x = Qy[tp][0]; w0.y = Qy[tp][1];
      uint2 w1; w1.x = Qy[tp][2]; w1.y = Qy[tp][3];
      *(uint2*)(Qslab + (base_q ^ swzq)) = w0;
      *(uint2*)(Qslab + ((base_q + 32) ^ swzq)) = w1;
    }
#pragma unroll
    for (int i = 0; i < 4; ++i) {
      int hh = tph * 4 + i;
      bf16x8 qf = *(const bf16x8*)(Qslab + ((lo16 * 512 + hh * 64 + g * 16) ^ swzq));
      const char* cp = CTXT + (1 * 8 + hh) * 2048 + l * 16;
      bf16x8 c0 = *(const bf16x8*)(cp);
      bf16x8 c1 = *(const bf16x8*)(cp + 1024);
      attacc[i][0] = MFMA(c0, qf, attacc[i][0]);
      attacc[i][1] = MFMA(c1, qf, attacc[i][1]);
    }
    // pack attS -> Qslab
#pragma unroll
    for (int i = 0; i < 4; ++i) {
      int hh = tph * 4 + i;
#pragma unroll
      for (int m = 0; m < 2; ++m) {
        f32x4 v = attacc[i][m];
        uint2 wv;
        wv.x = pack2(v[0], v[1]); wv.y = pack2(v[2], v[3]);
        int byte = (lo16 * 512 + hh * 64 + m * 32 + g * 8) ^ swzq;
        *(uint2*)(Qslab + byte) = wv;
      }
    }
  }
  __syncthreads();  // attS + wgtl + ACC(L) complete

  // ---- reprojection -> ACC ----
#pragma unroll
  for (int tp = 0; tp < 4; ++tp) {
    int tq = tph * 4 + tp;
    int T0 = hf * 16 + tq * 2;
    f32x4 r0 = {0.f, 0.f, 0.f, 0.f}, r1 = {0.f, 0.f, 0.f, 0.f};
    const char* ap = WRp + T0 * 8192 + l * 16;
#pragma unroll
    for (int ks = 0; ks < 8; ++ks) {
      bf16x8 brf = *(const bf16x8*)(Qslab + ((lo16 * 512 + g * 16 + ks * 64) ^ swzq));
      bf16x8 a0 = *(const bf16x8*)(ap + ks * 1024);
      bf16x8 a1 = *(const bf16x8*)(ap + 8192 + ks * 1024);
      r0 = MFMA(a0, brf, r0);
      r1 = MFMA(a1, brf, r1);
    }
#pragma unroll
    for (int half = 0; half < 2; ++half) {
      f32x4 rr = half ? r1 : r0;
      int ch4 = (hf * 256 + tq * 32 + half * 16) / 4 + g;
      int ab = ((p0 + lo16) * 2048 + ch4 * 16) ^ (((p0 + lo16) & 7) << 4);
      f32x4 cur = *(const f32x4*)(ACCb + ab);
      cur += 0.25f * rr;
      *(f32x4*)(ACCb + ab) = cur;
    }
  }
  __syncthreads();  // ACC final

  // ---- output pass: ACC + bias + CAM-sampled term ----
  const float* bo = wsf + (B_BIASO / 4);
#pragma unroll
  for (int i = 0; i < 8; ++i) {
    int idx = i * 512 + t;       // f32x4 index over [32][128]
    int pos = idx >> 7, c4 = idx & 127;
    int ab = (pos * 2048 + c4 * 16) ^ ((pos & 7) << 4);
    f32x4 acc = *(const f32x4*)(ACCb + ab);
    f32x4 bb = *(const f32x4*)(bo + c4 * 4);
    if (c4 < 64) {
      f32x4 h20 = *(const f32x4*)(wsf + (B_HIGH2 / 4) + c4 * 4);
      f32x4 h21 = *(const f32x4*)(wsf + (B_HIGH2 / 4) + 256 + c4 * 4);
      float wg0 = wgtl[pos], wg1 = wgtl[32 + pos];
      acc += (0.25f * wg0) * h20 + (0.25f * wg1) * h21;
    }
    acc += bb;
    *(f32x4*)(out + (size_t)(n0 + pos) * 512 + c4 * 4) = acc;
  }
}

extern "C" void kernel_launch(void* const* d_in, const int* in_sizes, int n_in,
                              void* d_out, int out_size, void* d_ws, size_t ws_size,
                              hipStream_t stream) {
  const float* x = (const float*)d_in[0];
  const float* y = (const float*)d_in[1];
  const float* ea_wk = (const float*)d_in[2];
  const float* ea_bk = (const float*)d_in[3];
  const float* ea_wq = (const float*)d_in[4];
  const float* ea_bq = (const float*)d_in[5];
  const float* ea_wv = (const float*)d_in[6];
  const float* ea_bv = (const float*)d_in[7];
  const float* ea_wr = (const float*)d_in[8];
  const float* ea_br = (const float*)d_in[9];
  const float* pool_w1 = (const float*)d_in[10];
  const float* pool_bn1 = (const float*)d_in[11];
  const float* pool_w2 = (const float*)d_in[12];
  const float* pool_bn2 = (const float*)d_in[13];
  const float* adapt_w1 = (const float*)d_in[14];
  const float* adapt_bn1 = (const float*)d_in[15];
  const float* adapt_w2 = (const float*)d_in[16];
  const float* adapt_bn2 = (const float*)d_in[17];
  const float* delta_w1 = (const float*)d_in[18];
  const float* delta_bn1 = (const float*)d_in[19];
  const float* delta_w2 = (const float*)d_in[20];
  char* ws = (char*)d_ws;
  float* out = (float*)d_out;

  kW1<<<256, 512, 0, stream>>>(adapt_w1, adapt_bn1, adapt_w2, adapt_bn2, ws);
  kW2<<<1, 512, 0, stream>>>(delta_w1, delta_bn1, delta_w2, ws);
  kPack<<<4384, 256, 0, stream>>>(ea_wq, ea_wk, ea_wv, ea_wr, pool_w1, pool_w2, delta_w1, ws);
  k1_reduce<<<1024, 512, 0, stream>>>(x, y, ea_bk, ea_bv, ws, out);
  k1b<<<67, 512, 0, stream>>>(out, ws);
  k2_finalize<<<1, 512, 0, stream>>>(pool_bn1, pool_bn2, delta_bn1, delta_w2, ea_br, ws);
  k3_main<<<1024, 512, 0, stream>>>(x, y, ea_bq, ws, out);
}

// Round 11
// 444.395 us; speedup vs baseline: 7.3516x; 1.0914x over previous
//
#include <hip/hip_runtime.h>
#include <math.h>

// ---------------- ws byte offsets ----------------
#define B_CTXC   0          // single summed ctx [2][8][32][32] f32 = 65536 B
#define B_ZP     524288     // [2][256] f32
#define B_COLS   526336     // [2][512] f32
#define B_HIGH2  530432     // [2][256] f32
#define B_CONSTD 532480     // [2][2] f32 (+pad)
#define B_BIASO  532544     // [512] f32
#define B_CPP    534592     // [256] f32 (c'')
#define B_CTXT   535616     // [2][8] x 2 tiles x 1KB bf16, fragment-linear
#define B_WDD    568384     // [2][256] f32
#define B_WDX    570432     // [2][512] f32
#define B_WL     574528     // [256][512] f32 (W_L'')
#define B_WBIG   1098816    // 33 tiles x 16KB bf16, fragment-linear
#define B_WKV    1639488    // 32 tiles x 16KB bf16, fragment-linear
#define B_WR     2163776    // 32 tiles x 8KB bf16, fragment-linear
#define B_PW1T   2425920    // [512][512] f32 transposed
#define B_PW2T   3474496    // [512][256] f32 transposed
#define B_D1BT   3998784    // [256][256] f32 transposed
// d_out scratch (before k3 overwrites): [1024][8192] u32 ctx partials at u32
// index 0 (32MB), [1024][1536] f32 red partials at float offset 8388608.

typedef __attribute__((ext_vector_type(8))) short bf16x8;
typedef __attribute__((ext_vector_type(4))) float f32x4;

#define MFMA(a, b, c) __builtin_amdgcn_mfma_f32_16x16x32_bf16(a, b, c, 0, 0, 0)

__device__ inline unsigned f2bfu(float f) {
  unsigned u = __float_as_uint(f);
  return (u + 0x7FFFu + ((u >> 16) & 1u)) >> 16;
}
__device__ inline unsigned pack2(float a, float b) { return f2bfu(a) | (f2bfu(b) << 16); }

// ---------------- kW1: W_L'' (fp32) + c'' ----------------
__global__ __launch_bounds__(512) void kW1(
    const float* __restrict__ a1, const float* __restrict__ abn1,
    const float* __restrict__ a2, const float* __restrict__ abn2,
    char* __restrict__ wsb) {
  __shared__ float S1[512], F1[512], redu[512];
  const int t = threadIdx.x, o = blockIdx.x;
  float* wsf = (float*)wsb;
  {
    float gg = abn1[t], be = abn1[512 + t], mn = abn1[1024 + t], va = abn1[1536 + t];
    float s = gg * rsqrtf(va + 1e-5f);
    S1[t] = s; F1[t] = be - mn * s;
  }
  float g2 = abn2[o], be2 = abn2[256 + o], mn2 = abn2[512 + o], va2 = abn2[768 + o];
  float s2 = g2 * rsqrtf(va2 + 1e-5f);
  float f2v = be2 - mn2 * s2;
  __syncthreads();
  float acc = 0.f;
  const float* a2r = a2 + o * 512;
  for (int m = 0; m < 512; ++m) acc = fmaf(a2r[m] * S1[m], a1[m * 512 + t], acc);
  wsf[(B_WL / 4) + o * 512 + t] = s2 * acc;
  redu[t] = a2r[t] * F1[t];
  __syncthreads();
  for (int sft = 256; sft >= 1; sft >>= 1) {
    if (t < sft) redu[t] += redu[t + sft];
    __syncthreads();
  }
  if (t == 0) wsf[(B_CPP / 4) + o] = s2 * redu[0] + f2v;
}

// ---------------- kW2: W_dd, W_dx ----------------
__global__ __launch_bounds__(512) void kW2(
    const float* __restrict__ d1, const float* __restrict__ dbn1,
    const float* __restrict__ d2, char* __restrict__ wsb) {
  __shared__ float SD[256], WDDl[512];
  const int t = threadIdx.x;
  float* wsf = (float*)wsb;
  if (t < 256) {
    float gg = dbn1[t], va = dbn1[768 + t];
    SD[t] = gg * rsqrtf(va + 1e-5f);
  }
  __syncthreads();
  {
    int j = t >> 8, v = t & 255;
    float acc = 0.f;
    for (int o = 0; o < 256; ++o) acc = fmaf(d2[j * 256 + o] * SD[o], d1[o * 512 + v], acc);
    WDDl[t] = acc;
    wsf[(B_WDD / 4) + t] = acc;
  }
  __syncthreads();
  {
    int c = t;
    float acc0 = 0.f, acc1 = 0.f;
    for (int v = 0; v < 256; ++v) {
      float wl = wsf[(B_WL / 4) + v * 512 + c];
      acc0 = fmaf(WDDl[v], wl, acc0);
      acc1 = fmaf(WDDl[256 + v], wl, acc1);
    }
    wsf[(B_WDX / 4) + c] = acc0;
    wsf[(B_WDX / 4) + 512 + c] = acc1;
  }
}

// ---------------- kPack: fragment-linear bf16 packs + fp32 transposes ----------------
__global__ __launch_bounds__(256) void kPack(
    const float* __restrict__ wq, const float* __restrict__ wk, const float* __restrict__ wv,
    const float* __restrict__ wr, const float* __restrict__ pw1, const float* __restrict__ pw2,
    const float* __restrict__ d1, char* __restrict__ wsb) {
  int i = blockIdx.x * 256 + threadIdx.x;
  float* wsf = (float*)wsb;
  unsigned short* u16 = (unsigned short*)wsb;
  if (i < 270336) {  // Wbig: 33 tiles, K=512 (ks 0..15)
    int T = i >> 13, r = i & 8191;
    int ks = r >> 9, l = (r >> 3) & 63, j = r & 7;
    int row = T * 16 + (l & 15);
    int col = ks * 32 + (l >> 4) * 8 + j;
    float v;
    if (row < 256) v = wq[row * 512 + col];
    else if (row < 512) v = wsf[(B_WL / 4) + (row - 256) * 512 + col];
    else if (row < 514) v = wsf[(B_WDX / 4) + (row - 512) * 512 + col];
    else v = 0.f;
    u16[(B_WBIG / 2) + i] = (unsigned short)f2bfu(v);
    return;
  }
  i -= 270336;
  if (i < 262144) {  // Wkv: 32 tiles, K=512
    int T = i >> 13, r = i & 8191;
    int ks = r >> 9, l = (r >> 3) & 63, j = r & 7;
    int row = T * 16 + (l & 15);
    int col = ks * 32 + (l >> 4) * 8 + j;
    float v = row < 256 ? wk[row * 512 + col] : wv[(row - 256) * 512 + col];
    u16[(B_WKV / 2) + i] = (unsigned short)f2bfu(v);
    return;
  }
  i -= 262144;
  if (i < 131072) {  // WR: 32 tiles, K=256 (ks 0..7)
    int T = i >> 12, r = i & 4095;
    int ks = r >> 9, l = (r >> 3) & 63, j = r & 7;
    int row = T * 16 + (l & 15);
    int col = ks * 32 + (l >> 4) * 8 + j;
    u16[(B_WR / 2) + i] = (unsigned short)f2bfu(wr[row * 256 + col]);
    return;
  }
  i -= 131072;
  if (i < 262144) { int o = i >> 9, c = i & 511; wsf[(B_PW1T / 4) + c * 512 + o] = pw1[i]; return; }
  i -= 262144;
  if (i < 131072) { int o = i >> 9, c = i & 511; wsf[(B_PW2T / 4) + c * 256 + o] = pw2[i]; return; }
  i -= 131072;
  if (i < 65536) { int o = i >> 8, v = i & 255; wsf[(B_D1BT / 4) + v * 256 + o] = d1[o * 512 + 256 + v]; }
}

// ---------------- k1: b-merged keys/values MFMA, 16 waves ----------------
__global__ __launch_bounds__(1024, 1) void k1_reduce(
    const float* __restrict__ x, const float* __restrict__ y,
    const float* __restrict__ bk, const float* __restrict__ bv,
    const char* __restrict__ wsb, float* __restrict__ outp) {
  __shared__ __align__(16) unsigned char Xl[32768];
  __shared__ __align__(16) unsigned char Yl[32768];
  __shared__ __align__(16) unsigned char elx[16384];
  __shared__ __align__(16) unsigned char ely[16384];
  __shared__ __align__(16) unsigned char vlx[16384];
  __shared__ __align__(16) unsigned char vly[16384];
  __shared__ float Red[1536];  // [0..511]=Z(b0,b1), [512..1535]=colsum
  const int t = threadIdx.x;
  const int w = t >> 6, lo16 = t & 15, g = (t >> 4) & 3, l = t & 63;
  const int pt = w & 1, tq2 = (w >> 1) & 3, hf = w >> 3;
  const int p0 = pt * 16;
  const char* Wkv = wsb + B_WKV;

  for (int i = t; i < 1536; i += 1024) Red[i] = 0.f;
  float csum[2][8];
#pragma unroll
  for (int b2 = 0; b2 < 2; ++b2)
#pragma unroll
    for (int i = 0; i < 8; ++i) csum[b2][i] = 0.f;
  const int n0 = blockIdx.x * 32;
  const int rowX = p0 + lo16;
  const int bbase = rowX * 1024 + g * 16;
  const int bswz = (rowX & 7) << 4;
  __syncthreads();  // Red init visible

  // ---- stage x AND y tiles, column sums ----
#pragma unroll
  for (int r = 0; r < 2; ++r) {
    int chunk = r * 1024 + t;
    int prow = chunk >> 6, j = chunk & 63;
    const float* gx = x + (size_t)(n0 + prow) * 512 + j * 8;
    const float* gy = y + (size_t)(n0 + prow) * 512 + j * 8;
    float4 x0 = *(const float4*)gx, x1 = *(const float4*)(gx + 4);
    float4 y0 = *(const float4*)gy, y1 = *(const float4*)(gy + 4);
    csum[0][0] += x0.x; csum[0][1] += x0.y; csum[0][2] += x0.z; csum[0][3] += x0.w;
    csum[0][4] += x1.x; csum[0][5] += x1.y; csum[0][6] += x1.z; csum[0][7] += x1.w;
    csum[1][0] += y0.x; csum[1][1] += y0.y; csum[1][2] += y0.z; csum[1][3] += y0.w;
    csum[1][4] += y1.x; csum[1][5] += y1.y; csum[1][6] += y1.z; csum[1][7] += y1.w;
    int byte = (prow * 1024 + j * 16) ^ ((prow & 7) << 4);
    uint4 pk;
    pk.x = pack2(x0.x, x0.y); pk.y = pack2(x0.z, x0.w);
    pk.z = pack2(x1.x, x1.y); pk.w = pack2(x1.z, x1.w);
    *(uint4*)(Xl + byte) = pk;
    pk.x = pack2(y0.x, y0.y); pk.y = pack2(y0.z, y0.w);
    pk.z = pack2(y1.x, y1.y); pk.w = pack2(y1.z, y1.w);
    *(uint4*)(Yl + byte) = pk;
  }
  // colsum partials -> Red (channel = (t&63)*8 + i)
#pragma unroll
  for (int b = 0; b < 2; ++b)
#pragma unroll
    for (int i = 0; i < 8; ++i) atomicAdd(&Red[512 + b * 512 + (t & 63) * 8 + i], csum[b][i]);
  __syncthreads();

  // ---- merged GEMM: each weight fragment -> 2 MFMAs (x and y) ----
#pragma unroll
  for (int tp = 0; tp < 2; ++tp) {
    int tq = tq2 * 2 + tp;
    int t0 = hf * 16 + tq * 2, t1 = t0 + 1;
    f32x4 ax0 = {0.f, 0.f, 0.f, 0.f}, ax1 = {0.f, 0.f, 0.f, 0.f};
    f32x4 ay0 = {0.f, 0.f, 0.f, 0.f}, ay1 = {0.f, 0.f, 0.f, 0.f};
    const char* ap = Wkv + t0 * 16384 + l * 16;
#pragma unroll
    for (int ks = 0; ks < 16; ++ks) {
      bf16x8 bx = *(const bf16x8*)(Xl + ((bbase + ks * 64) ^ bswz));
      bf16x8 by = *(const bf16x8*)(Yl + ((bbase + ks * 64) ^ bswz));
      bf16x8 af0 = *(const bf16x8*)(ap + ks * 1024);
      bf16x8 af1 = *(const bf16x8*)(ap + 16384 + ks * 1024);
      ax0 = MFMA(af0, bx, ax0); ay0 = MFMA(af0, by, ay0);
      ax1 = MFMA(af1, bx, ax1); ay1 = MFMA(af1, by, ay1);
    }
    int pp = p0 + lo16;
    if (hf == 0) {  // keys -> e, Z, el (both b)
      float ex0[4], ex1[4], ey0[4], ey1[4];
#pragma unroll
      for (int r = 0; r < 4; ++r) {
        float bk0 = bk[t0 * 16 + g * 4 + r], bk1 = bk[t1 * 16 + g * 4 + r];
        ex0[r] = __expf(ax0[r] + bk0); ey0[r] = __expf(ay0[r] + bk0);
        ex1[r] = __expf(ax1[r] + bk1); ey1[r] = __expf(ay1[r] + bk1);
      }
#pragma unroll
      for (int r = 0; r < 4; ++r) {
        float v0 = ex0[r], v1 = ex1[r], v2 = ey0[r], v3 = ey1[r];
        for (int m = 8; m >= 1; m >>= 1) {
          v0 += __shfl_xor(v0, m, 16); v1 += __shfl_xor(v1, m, 16);
          v2 += __shfl_xor(v2, m, 16); v3 += __shfl_xor(v3, m, 16);
        }
        if (lo16 == 0) {
          atomicAdd(&Red[t0 * 16 + g * 4 + r], v0);
          atomicAdd(&Red[t1 * 16 + g * 4 + r], v1);
          atomicAdd(&Red[256 + t0 * 16 + g * 4 + r], v2);
          atomicAdd(&Red[256 + t1 * 16 + g * 4 + r], v3);
        }
      }
#pragma unroll
      for (int r = 0; r < 4; ++r) {
        int row0 = t0 * 16 + g * 4 + r;
        int row1 = t1 * 16 + g * 4 + r;
        int a0 = (row0 * 64 + pp * 2) ^ ((row0 & 3) << 4);
        int a1 = (row1 * 64 + pp * 2) ^ ((row1 & 3) << 4);
        *(unsigned short*)(elx + a0) = (unsigned short)f2bfu(ex0[r]);
        *(unsigned short*)(elx + a1) = (unsigned short)f2bfu(ex1[r]);
        *(unsigned short*)(ely + a0) = (unsigned short)f2bfu(ey0[r]);
        *(unsigned short*)(ely + a1) = (unsigned short)f2bfu(ey1[r]);
      }
    } else {  // values -> vl (both b)
#pragma unroll
      for (int r = 0; r < 4; ++r) {
        int row0 = (t0 - 16) * 16 + g * 4 + r;
        int row1 = (t1 - 16) * 16 + g * 4 + r;
        float bv0 = bv[row0], bv1 = bv[row1];
        int a0 = (row0 * 64 + pp * 2) ^ ((row0 & 3) << 4);
        int a1 = (row1 * 64 + pp * 2) ^ ((row1 & 3) << 4);
        *(unsigned short*)(vlx + a0) = (unsigned short)f2bfu(ax0[r] + bv0);
        *(unsigned short*)(vlx + a1) = (unsigned short)f2bfu(ax1[r] + bv1);
        *(unsigned short*)(vly + a0) = (unsigned short)f2bfu(ay0[r] + bv0);
        *(unsigned short*)(vly + a1) = (unsigned short)f2bfu(ay1[r] + bv1);
      }
    }
  }
  __syncthreads();  // el/vl + Red complete

  // ---- transient ctx: wave = (bsel, head); per m: 2 MFMAs -> immediate store ----
  {
    const int h2 = w & 7, bsel = w >> 3;
    const unsigned char* el = bsel ? ely : elx;
    const unsigned char* vl = bsel ? vly : vlx;
    unsigned* ctxp = (unsigned*)outp + (size_t)blockIdx.x * 8192;
#pragma unroll
    for (int m = 0; m < 2; ++m) {
      int rowe = h2 * 32 + m * 16 + lo16;
      bf16x8 ea = *(const bf16x8*)(el + ((rowe * 64 + g * 16) ^ ((rowe & 3) << 4)));
      f32x4 c0 = {0.f, 0.f, 0.f, 0.f}, c1 = {0.f, 0.f, 0.f, 0.f};
      {
        int rowv = h2 * 32 + lo16;
        bf16x8 vb = *(const bf16x8*)(vl + ((rowv * 64 + g * 16) ^ ((rowv & 3) << 4)));
        c0 = MFMA(ea, vb, c0);
      }
      {
        int rowv = h2 * 32 + 16 + lo16;
        bf16x8 vb = *(const bf16x8*)(vl + ((rowv * 64 + g * 16) ^ ((rowv & 3) << 4)));
        c1 = MFMA(ea, vb, c1);
      }
#pragma unroll
      for (int r = 0; r < 4; ++r)
        ctxp[((bsel * 2 + m) * 4 + r) * 512 + h2 * 64 + l] = pack2(c0[r], c1[r]);
    }
    float* redp = outp + 8388608 + blockIdx.x * 1536;
    for (int i = t; i < 1536; i += 1024) redp[i] = Red[i];
  }
}

// ---------------- k1b: tree-reduce the 1024 partial copies ----------------
__global__ __launch_bounds__(512) void k1b(const float* __restrict__ outp, char* __restrict__ wsb) {
  __shared__ float R[512];
  const int t = threadIdx.x, blk = blockIdx.x;
  float* wsf = (float*)wsb;
  if (blk < 64) {  // ctx: 128 slots per block, 4 partial-sum lanes each
    int sl = t & 127, part = t >> 7;
    int slot = blk * 128 + sl;
    const unsigned* p = (const unsigned*)outp;
    float s0 = 0.f, s1 = 0.f;
    for (int c = part * 256; c < part * 256 + 256; ++c) {
      unsigned wv = p[(size_t)c * 8192 + slot];
      s0 += __uint_as_float(wv << 16);
      s1 += __uint_as_float(wv & 0xffff0000u);
    }
    R[sl * 4 + part] = s0;
    __syncthreads();
    float sum0 = R[sl * 4] + R[sl * 4 + 1] + R[sl * 4 + 2] + R[sl * 4 + 3];
    __syncthreads();
    R[sl * 4 + part] = s1;
    __syncthreads();
    float sum1 = R[sl * 4] + R[sl * 4 + 1] + R[sl * 4 + 2] + R[sl * 4 + 3];
    if (part == 0) {
      int t_ = slot & 511, bmr = slot >> 9;
      int r = bmr & 3, m = (bmr >> 2) & 1, b = bmr >> 3;
      int h = t_ >> 6, g = (t_ >> 4) & 3, lo16 = t_ & 15;
      int klocal = m * 16 + g * 4 + r;
      int base = ((b * 8 + h) * 32 + klocal) * 32;
      wsf[(B_CTXC / 4) + base + lo16] = sum0;
      wsf[(B_CTXC / 4) + base + 16 + lo16] = sum1;
    }
  } else {  // red: 3 blocks x 512 values
    int j = (blk - 64) * 512 + t;
    const float* rp = outp + 8388608;
    float s = 0.f;
    for (int c = 0; c < 1024; ++c) s += rp[(size_t)c * 1536 + j];
    if (j < 512) wsf[(B_ZP / 4) + j] = s;
    else wsf[(B_COLS / 4) + (j - 512)] = s;
  }
}

// ---------------- k2: ctx normalize (packed write), pool chain, constD, biasOut ----------------
__global__ __launch_bounds__(512) void k2_finalize(
    const float* __restrict__ pbn1, const float* __restrict__ pbn2,
    const float* __restrict__ dbn1, const float* __restrict__ d2,
    const float* __restrict__ ea_br, char* __restrict__ wsb) {
  __shared__ float HI[1024], H1[1024], H2l[512], VB[512], slot[4];
  const int t = threadIdx.x;
  float* wsf = (float*)wsb;
  unsigned short* u16 = (unsigned short*)wsb;
  for (int idx = t; idx < 16384; idx += 512) {
    float s = wsf[(B_CTXC / 4) + idx];
    int v = idx & 31, row = idx >> 5;
    int b = row >> 8, kr = row & 255;
    int hh = kr >> 5, kh = kr & 31;
    float val = s / wsf[(B_ZP / 4) + b * 256 + kr];
    int m = v >> 4;
    int lane = (v & 15) + ((kh >> 3) << 4);
    int j = kh & 7;
    u16[(B_CTXT / 2) + (((b * 8 + hh) * 2 + m) << 9) + lane * 8 + j] = (unsigned short)f2bfu(val);
  }
  if (t < 4) slot[t] = 0.f;
  for (int idx = t; idx < 1024; idx += 512) HI[idx] = wsf[(B_COLS / 4) + idx] * (1.f / 32768.f);
  __syncthreads();
  {
    int o = t;
    float gg = pbn1[o], be = pbn1[512 + o], mn = pbn1[1024 + o], va = pbn1[1536 + o];
    float sc = gg * rsqrtf(va + 1e-5f), sh = be - mn * sc;
    for (int b = 0; b < 2; ++b) {
      float acc = 0.f;
      for (int c = 0; c < 512; ++c) acc = fmaf(wsf[(B_PW1T / 4) + c * 512 + o], HI[b * 512 + c], acc);
      H1[b * 512 + o] = acc * sc + sh;
    }
  }
  __syncthreads();
  if (t < 256) {
    int o = t;
    float gg = pbn2[o], be = pbn2[256 + o], mn = pbn2[512 + o], va = pbn2[768 + o];
    float sc = gg * rsqrtf(va + 1e-5f), sh = be - mn * sc;
    for (int b = 0; b < 2; ++b) {
      float acc = 0.f;
      for (int c = 0; c < 512; ++c) acc = fmaf(wsf[(B_PW2T / 4) + c * 256 + o], H1[b * 512 + c], acc);
      float vv = acc * sc + sh;
      H2l[b * 256 + o] = vv;
      wsf[(B_HIGH2 / 4) + b * 256 + o] = vv;
    }
  }
  __syncthreads();
  if (t < 256) {
    int o = t;
    float gg = dbn1[o], be = dbn1[256 + o], mn = dbn1[512 + o], va = dbn1[768 + o];
    float sd = gg * rsqrtf(va + 1e-5f), fd = be - mn * sd;
    for (int b = 0; b < 2; ++b) {
      float acc = 0.f;
      for (int v = 0; v < 256; ++v) acc = fmaf(wsf[(B_D1BT / 4) + v * 256 + o], H2l[b * 256 + v], acc);
      VB[b * 256 + o] = sd * acc + fd;
    }
  }
  __syncthreads();
  if (t < 256) {
    int o = t;
    for (int b = 0; b < 2; ++b)
      for (int j = 0; j < 2; ++j) atomicAdd(&slot[b * 2 + j], d2[j * 256 + o] * VB[b * 256 + o]);
    float cp = wsf[(B_CPP / 4) + o];
    for (int j = 0; j < 2; ++j) {
      float w = wsf[(B_WDD / 4) + j * 256 + o] * cp;
      atomicAdd(&slot[0 + j], w);
      atomicAdd(&slot[2 + j], w);
    }
  }
  __syncthreads();
  if (t < 4) wsf[(B_CONSTD / 4) + t] = slot[t];
  {
    int o = t;
    float bb = 0.5f * ea_br[o];
    if (o >= 256) bb += 0.5f * wsf[(B_CPP / 4) + o - 256];
    wsf[(B_BIASO / 4) + o] = bb;
  }
}

// ---------------- k3: b-merged main pass, LDS f32 accumulator, 16 waves ----------------
__global__ __launch_bounds__(1024, 1) void k3_main(
    const float* __restrict__ x, const float* __restrict__ y,
    const float* __restrict__ bq, const char* __restrict__ wsb,
    float* __restrict__ out) {
  __shared__ __align__(16) unsigned char Xl[32768];
  __shared__ __align__(16) unsigned char Yl[32768];
  __shared__ __align__(16) unsigned char ACCb[65536];  // f32 [32 pos][512 ch], swizzled
  __shared__ __align__(16) unsigned char Ql[16384];
  __shared__ float wgtl[64];  // [b][pos]
  const int t = threadIdx.x;
  const int w = t >> 6, lo16 = t & 15, g = (t >> 4) & 3, l = t & 63;
  const int pt = w & 1, tq2 = (w >> 1) & 3, hf = w >> 3;
  const int p0 = pt * 16;
  const int n0 = blockIdx.x * 32;
  const char* Wbig = wsb + B_WBIG;
  const char* WRp = wsb + B_WR;
  const char* CTXT = wsb + B_CTXT;
  const float* wsf = (const float*)wsb;
  unsigned char* Qslab = Ql + pt * 8192;
  const int rowX = p0 + lo16;
  const int bbase = rowX * 1024 + g * 16;
  const int bswz = (rowX & 7) << 4;
  const int swzq = (lo16 & 7) << 4;

  // ---- stage x,y; init ACC = 0.25*(x+y) ----
#pragma unroll
  for (int r = 0; r < 2; ++r) {
    int chunk = r * 1024 + t;
    int prow = chunk >> 6, j = chunk & 63;
    const float* gx = x + (size_t)(n0 + prow) * 512 + j * 8;
    const float* gy = y + (size_t)(n0 + prow) * 512 + j * 8;
    float4 x0 = *(const float4*)gx, x1 = *(const float4*)(gx + 4);
    float4 y0 = *(const float4*)gy, y1 = *(const float4*)(gy + 4);
    int byte = (prow * 1024 + j * 16) ^ ((prow & 7) << 4);
    uint4 pk;
    pk.x = pack2(x0.x, x0.y); pk.y = pack2(x0.z, x0.w);
    pk.z = pack2(x1.x, x1.y); pk.w = pack2(x1.z, x1.w);
    *(uint4*)(Xl + byte) = pk;
    pk.x = pack2(y0.x, y0.y); pk.y = pack2(y0.z, y0.w);
    pk.z = pack2(y1.x, y1.y); pk.w = pack2(y1.z, y1.w);
    *(uint4*)(Yl + byte) = pk;
    int abase = prow * 2048 + j * 32;
    int aswz = (prow & 7) << 4;
    f32x4 a0 = {0.25f * (x0.x + y0.x), 0.25f * (x0.y + y0.y), 0.25f * (x0.z + y0.z), 0.25f * (x0.w + y0.w)};
    f32x4 a1 = {0.25f * (x1.x + y1.x), 0.25f * (x1.y + y1.y), 0.25f * (x1.z + y1.z), 0.25f * (x1.w + y1.w)};
    *(f32x4*)(ACCb + (abase ^ aswz)) = a0;
    *(f32x4*)(ACCb + ((abase + 16) ^ aswz)) = a1;
  }
  __syncthreads();

  unsigned Qy[2][4];  // packed Q for b=1, per tp

  // ---- merged tp loop ----
#pragma unroll
  for (int tp = 0; tp < 2; ++tp) {
    int tq = tq2 * 2 + tp;
    int t0 = hf * 16 + tq * 2;
    f32x4 ax0 = {0.f, 0.f, 0.f, 0.f}, ax1 = {0.f, 0.f, 0.f, 0.f};
    f32x4 ay0 = {0.f, 0.f, 0.f, 0.f}, ay1 = {0.f, 0.f, 0.f, 0.f};
    const char* ap = Wbig + t0 * 16384 + l * 16;
#pragma unroll
    for (int ks = 0; ks < 16; ++ks) {
      bf16x8 bx = *(const bf16x8*)(Xl + ((bbase + ks * 64) ^ bswz));
      bf16x8 by = *(const bf16x8*)(Yl + ((bbase + ks * 64) ^ bswz));
      bf16x8 af0 = *(const bf16x8*)(ap + ks * 1024);
      bf16x8 af1 = *(const bf16x8*)(ap + 16384 + ks * 1024);
      ax0 = MFMA(af0, bx, ax0); ay0 = MFMA(af0, by, ay0);
      ax1 = MFMA(af1, bx, ax1); ay1 = MFMA(af1, by, ay1);
    }
    if (hf == 0) {  // Q head tq: softmax both b; store b0 now, keep b1 packed
      int hh = tq;
#pragma unroll
      for (int b = 0; b < 2; ++b) {
        f32x4 a0 = b ? ay0 : ax0, a1 = b ? ay1 : ax1;
        float q[8], e[8];
        float mx = -1e30f;
#pragma unroll
        for (int r = 0; r < 4; ++r) {
          q[r] = a0[r] + bq[hh * 32 + g * 4 + r];
          q[4 + r] = a1[r] + bq[hh * 32 + 16 + g * 4 + r];
          mx = fmaxf(mx, fmaxf(q[r], q[4 + r]));
        }
        mx = fmaxf(mx, __shfl_xor(mx, 16, 64));
        mx = fmaxf(mx, __shfl_xor(mx, 32, 64));
        float sm = 0.f;
#pragma unroll
        for (int r = 0; r < 8; ++r) { e[r] = __expf(q[r] - mx); sm += e[r]; }
        sm += __shfl_xor(sm, 16, 64);
        sm += __shfl_xor(sm, 32, 64);
        float inv = 1.f / sm;
        unsigned p0w = pack2(e[0] * inv, e[1] * inv), p1w = pack2(e[2] * inv, e[3] * inv);
        unsigned p2w = pack2(e[4] * inv, e[5] * inv), p3w = pack2(e[6] * inv, e[7] * inv);
        if (b == 0) {
          int base_q = lo16 * 512 + hh * 64 + g * 8;
          uint2 w0; w0.x = p0w; w0.y = p1w;
          uint2 w1; w1.x = p2w; w1.y = p3w;
          *(uint2*)(Qslab + (base_q ^ swzq)) = w0;
          *(uint2*)(Qslab + ((base_q + 32) ^ swzq)) = w1;
        } else {
          Qy[tp][0] = p0w; Qy[tp][1] = p1w; Qy[tp][2] = p2w; Qy[tp][3] = p3w;
        }
      }
    } else {  // L tiles: accumulate 0.25*(Lx+Ly) into ACC
      int tile0 = t0 - 16;  // even, 0..14
#pragma unroll
      for (int half = 0; half < 2; ++half) {
        f32x4 axs = half ? ax1 : ax0;
        f32x4 ays = half ? ay1 : ay0;
        int ch4 = 64 + (tile0 + half) * 4 + g;  // ch = 256 + tile*16 + g*4
        int ab = ((p0 + lo16) * 2048 + ch4 * 16) ^ (((p0 + lo16) & 7) << 4);
        f32x4 cur = *(const f32x4*)(ACCb + ab);
        cur += 0.25f * (axs + ays);
        *(f32x4*)(ACCb + ab) = cur;
      }
    }
  }

  // ---- delta (hf1, tq2==0): both b, one weight read ----
  if (hf == 1 && tq2 == 0) {
    f32x4 adx = {0.f, 0.f, 0.f, 0.f}, ady = {0.f, 0.f, 0.f, 0.f};
    const char* ap = Wbig + 32 * 16384 + l * 16;
#pragma unroll
    for (int ks = 0; ks < 16; ++ks) {
      bf16x8 bx = *(const bf16x8*)(Xl + ((bbase + ks * 64) ^ bswz));
      bf16x8 by = *(const bf16x8*)(Yl + ((bbase + ks * 64) ^ bswz));
      bf16x8 af = *(const bf16x8*)(ap + ks * 1024);
      adx = MFMA(af, bx, adx);
      ady = MFMA(af, by, ady);
    }
    if (g == 0) {
      int pos = n0 + p0 + lo16;
      float base_gx = -1.f + 2.f * (float)pos / 32767.f;
#pragma unroll
      for (int b = 0; b < 2; ++b) {
        f32x4 ad = b ? ady : adx;
        float d0 = ad[0] + wsf[(B_CONSTD / 4) + b * 2 + 0];
        float d1 = ad[1] + wsf[(B_CONSTD / 4) + b * 2 + 1];
        float gxv = base_gx + d0;
        float gyv = -1.f + d1;
        float ix = gxv * 0.5f, iy = gyv * 0.5f;
        float wx = fminf(fmaxf(1.f - fabsf(ix), 0.f), 1.f);
        float wy = fminf(fmaxf(1.f - fabsf(iy), 0.f), 1.f);
        wgtl[b * 32 + p0 + lo16] = wx * wy;
      }
    }
  }

  // ---- att (hf0): each wave owns 2 heads; b=0 from Qslab then b=1 in-wave ----
  f32x4 attacc[2][2];
#pragma unroll
  for (int i = 0; i < 2; ++i)
#pragma unroll
    for (int m = 0; m < 2; ++m) attacc[i][m] = (f32x4){0.f, 0.f, 0.f, 0.f};
  if (hf == 0) {
#pragma unroll
    for (int i = 0; i < 2; ++i) {
      int hh = tq2 * 2 + i;
      bf16x8 qf = *(const bf16x8*)(Qslab + ((lo16 * 512 + hh * 64 + g * 16) ^ swzq));
      const char* cp = CTXT + (0 * 8 + hh) * 2048 + l * 16;
      bf16x8 c0 = *(const bf16x8*)(cp);
      bf16x8 c1 = *(const bf16x8*)(cp + 1024);
      attacc[i][0] = MFMA(c0, qf, attacc[i][0]);
      attacc[i][1] = MFMA(c1, qf, attacc[i][1]);
    }
    // overwrite with Q_y (same-wave LDS roundtrip; heads private to this wave)
#pragma unroll
    for (int tp = 0; tp < 2; ++tp) {
      int hh = tq2 * 2 + tp;
      int base_q = lo16 * 512 + hh * 64 + g * 8;
      uint2 w0; w0.x = Qy[tp][0]; w0.y = Qy[tp][1];
      uint2 w1; w1.x = Qy[tp][2]; w1.y = Qy[tp][3];
      *(uint2*)(Qslab + (base_q ^ swzq)) = w0;
      *(uint2*)(Qslab + ((base_q + 32) ^ swzq)) = w1;
    }
#pragma unroll
    for (int i = 0; i < 2; ++i) {
      int hh = tq2 * 2 + i;
      bf16x8 qf = *(const bf16x8*)(Qslab + ((lo16 * 512 + hh * 64 + g * 16) ^ swzq));
      const char* cp = CTXT + (1 * 8 + hh) * 2048 + l * 16;
      bf16x8 c0 = *(const bf16x8*)(cp);
      bf16x8 c1 = *(const bf16x8*)(cp + 1024);
      attacc[i][0] = MFMA(c0, qf, attacc[i][0]);
      attacc[i][1] = MFMA(c1, qf, attacc[i][1]);
    }
    // pack attS -> Qslab
#pragma unroll
    for (int i = 0; i < 2; ++i) {
      int hh = tq2 * 2 + i;
#pragma unroll
      for (int m = 0; m < 2; ++m) {
        f32x4 v = attacc[i][m];
        uint2 wv;
        wv.x = pack2(v[0], v[1]); wv.y = pack2(v[2], v[3]);
        int byte = (lo16 * 512 + hh * 64 + m * 32 + g * 8) ^ swzq;
        *(uint2*)(Qslab + byte) = wv;
      }
    }
  }
  __syncthreads();  // attS + wgtl + ACC(L) complete

  // ---- reprojection -> ACC ----
#pragma unroll
  for (int tp = 0; tp < 2; ++tp) {
    int tq = tq2 * 2 + tp;
    int T0 = hf * 16 + tq * 2;
    f32x4 r0 = {0.f, 0.f, 0.f, 0.f}, r1 = {0.f, 0.f, 0.f, 0.f};
    const char* ap = WRp + T0 * 8192 + l * 16;
#pragma unroll
    for (int ks = 0; ks < 8; ++ks) {
      bf16x8 brf = *(const bf16x8*)(Qslab + ((lo16 * 512 + g * 16 + ks * 64) ^ swzq));
      bf16x8 a0 = *(const bf16x8*)(ap + ks * 1024);
      bf16x8 a1 = *(const bf16x8*)(ap + 8192 + ks * 1024);
      r0 = MFMA(a0, brf, r0);
      r1 = MFMA(a1, brf, r1);
    }
#pragma unroll
    for (int half = 0; half < 2; ++half) {
      f32x4 rr = half ? r1 : r0;
      int ch4 = (hf * 256 + tq * 32 + half * 16) / 4 + g;
      int ab = ((p0 + lo16) * 2048 + ch4 * 16) ^ (((p0 + lo16) & 7) << 4);
      f32x4 cur = *(const f32x4*)(ACCb + ab);
      cur += 0.25f * rr;
      *(f32x4*)(ACCb + ab) = cur;
    }
  }
  __syncthreads();  // ACC final

  // ---- output pass: ACC + bias + CAM-sampled term ----
  const float* bo = wsf + (B_BIASO / 4);
#pragma unroll
  for (int i = 0; i < 4; ++i) {
    int idx = i * 1024 + t;      // f32x4 index over [32][128]
    int pos = idx >> 7, c4 = idx & 127;
    int ab = (pos * 2048 + c4 * 16) ^ ((pos & 7) << 4);
    f32x4 acc = *(const f32x4*)(ACCb + ab);
    f32x4 bb = *(const f32x4*)(bo + c4 * 4);
    if (c4 < 64) {
      f32x4 h20 = *(const f32x4*)(wsf + (B_HIGH2 / 4) + c4 * 4);
      f32x4 h21 = *(const f32x4*)(wsf + (B_HIGH2 / 4) + 256 + c4 * 4);
      float wg0 = wgtl[pos], wg1 = wgtl[32 + pos];
      acc += (0.25f * wg0) * h20 + (0.25f * wg1) * h21;
    }
    acc += bb;
    *(f32x4*)(out + (size_t)(n0 + pos) * 512 + c4 * 4) = acc;
  }
}

extern "C" void kernel_launch(void* const* d_in, const int* in_sizes, int n_in,
                              void* d_out, int out_size, void* d_ws, size_t ws_size,
                              hipStream_t stream) {
  const float* x = (const float*)d_in[0];
  const float* y = (const float*)d_in[1];
  const float* ea_wk = (const float*)d_in[2];
  const float* ea_bk = (const float*)d_in[3];
  const float* ea_wq = (const float*)d_in[4];
  const float* ea_bq = (const float*)d_in[5];
  const float* ea_wv = (const float*)d_in[6];
  const float* ea_bv = (const float*)d_in[7];
  const float* ea_wr = (const float*)d_in[8];
  const float* ea_br = (const float*)d_in[9];
  const float* pool_w1 = (const float*)d_in[10];
  const float* pool_bn1 = (const float*)d_in[11];
  const float* pool_w2 = (const float*)d_in[12];
  const float* pool_bn2 = (const float*)d_in[13];
  const float* adapt_w1 = (const float*)d_in[14];
  const float* adapt_bn1 = (const float*)d_in[15];
  const float* adapt_w2 = (const float*)d_in[16];
  const float* adapt_bn2 = (const float*)d_in[17];
  const float* delta_w1 = (const float*)d_in[18];
  const float* delta_bn1 = (const float*)d_in[19];
  const float* delta_w2 = (const float*)d_in[20];
  char* ws = (char*)d_ws;
  float* out = (float*)d_out;

  kW1<<<256, 512, 0, stream>>>(adapt_w1, adapt_bn1, adapt_w2, adapt_bn2, ws);
  kW2<<<1, 512, 0, stream>>>(delta_w1, delta_bn1, delta_w2, ws);
  kPack<<<4384, 256, 0, stream>>>(ea_wq, ea_wk, ea_wv, ea_wr, pool_w1, pool_w2, delta_w1, ws);
  k1_reduce<<<1024, 1024, 0, stream>>>(x, y, ea_bk, ea_bv, ws, out);
  k1b<<<67, 512, 0, stream>>>(out, ws);
  k2_finalize<<<1, 512, 0, stream>>>(pool_bn1, pool_bn2, delta_bn1, delta_w2, ea_br, ws);
  k3_main<<<1024, 1024, 0, stream>>>(x, y, ea_bq, ws, out);
}

// Round 12
// 376.738 us; speedup vs baseline: 8.6718x; 1.1796x over previous
//
#include <hip/hip_runtime.h>
#include <math.h>

// ---------------- ws byte offsets ----------------
#define B_CTXC   0          // single summed ctx [2][8][32][32] f32 = 65536 B
#define B_ZP     524288     // [2][256] f32
#define B_COLS   526336     // [2][512] f32
#define B_HIGH2  530432     // [2][256] f32
#define B_CONSTD 532480     // [2][2] f32 (+pad)
#define B_BIASO  532544     // [512] f32
#define B_CPP    534592     // [256] f32 (c'')
#define B_CTXT   535616     // [2][8] x 2 tiles x 1KB bf16, fragment-linear
#define B_WDD    568384     // [2][256] f32
#define B_WDX    570432     // [2][512] f32
#define B_WL     574528     // [256][512] f32 (W_L'')
#define B_WBIG   1098816    // 33 tiles x 16KB bf16, fragment-linear
#define B_WKV    1639488    // 32 tiles x 16KB bf16, fragment-linear
#define B_WR     2163776    // 32 tiles x 8KB bf16, fragment-linear
#define B_PW1T   2425920    // [512][512] f32 transposed
#define B_PW2T   3474496    // [512][256] f32 transposed
#define B_D1BT   3998784    // [256][256] f32 transposed
// d_out scratch (before k3 overwrites): [1024][8192] u32 ctx partials at u32
// index 0 (32MB), [1024][1536] f32 red partials at float offset 8388608.

typedef __attribute__((ext_vector_type(8))) short bf16x8;
typedef __attribute__((ext_vector_type(4))) float f32x4;

#define MFMA(a, b, c) __builtin_amdgcn_mfma_f32_16x16x32_bf16(a, b, c, 0, 0, 0)

__device__ inline unsigned f2bfu(float f) {
  unsigned u = __float_as_uint(f);
  return (u + 0x7FFFu + ((u >> 16) & 1u)) >> 16;
}
__device__ inline unsigned pack2(float a, float b) { return f2bfu(a) | (f2bfu(b) << 16); }

// ---------------- kW1: W_L'' (fp32) + c'' ----------------
__global__ __launch_bounds__(512) void kW1(
    const float* __restrict__ a1, const float* __restrict__ abn1,
    const float* __restrict__ a2, const float* __restrict__ abn2,
    char* __restrict__ wsb) {
  __shared__ float S1[512], F1[512], redu[512];
  const int t = threadIdx.x, o = blockIdx.x;
  float* wsf = (float*)wsb;
  {
    float gg = abn1[t], be = abn1[512 + t], mn = abn1[1024 + t], va = abn1[1536 + t];
    float s = gg * rsqrtf(va + 1e-5f);
    S1[t] = s; F1[t] = be - mn * s;
  }
  float g2 = abn2[o], be2 = abn2[256 + o], mn2 = abn2[512 + o], va2 = abn2[768 + o];
  float s2 = g2 * rsqrtf(va2 + 1e-5f);
  float f2v = be2 - mn2 * s2;
  __syncthreads();
  float acc = 0.f;
  const float* a2r = a2 + o * 512;
  for (int m = 0; m < 512; ++m) acc = fmaf(a2r[m] * S1[m], a1[m * 512 + t], acc);
  wsf[(B_WL / 4) + o * 512 + t] = s2 * acc;
  redu[t] = a2r[t] * F1[t];
  __syncthreads();
  for (int sft = 256; sft >= 1; sft >>= 1) {
    if (t < sft) redu[t] += redu[t + sft];
    __syncthreads();
  }
  if (t == 0) wsf[(B_CPP / 4) + o] = s2 * redu[0] + f2v;
}

// ---------------- kW2: W_dd, W_dx ----------------
__global__ __launch_bounds__(512) void kW2(
    const float* __restrict__ d1, const float* __restrict__ dbn1,
    const float* __restrict__ d2, char* __restrict__ wsb) {
  __shared__ float SD[256], WDDl[512];
  const int t = threadIdx.x;
  float* wsf = (float*)wsb;
  if (t < 256) {
    float gg = dbn1[t], va = dbn1[768 + t];
    SD[t] = gg * rsqrtf(va + 1e-5f);
  }
  __syncthreads();
  {
    int j = t >> 8, v = t & 255;
    float acc = 0.f;
    for (int o = 0; o < 256; ++o) acc = fmaf(d2[j * 256 + o] * SD[o], d1[o * 512 + v], acc);
    WDDl[t] = acc;
    wsf[(B_WDD / 4) + t] = acc;
  }
  __syncthreads();
  {
    int c = t;
    float acc0 = 0.f, acc1 = 0.f;
    for (int v = 0; v < 256; ++v) {
      float wl = wsf[(B_WL / 4) + v * 512 + c];
      acc0 = fmaf(WDDl[v], wl, acc0);
      acc1 = fmaf(WDDl[256 + v], wl, acc1);
    }
    wsf[(B_WDX / 4) + c] = acc0;
    wsf[(B_WDX / 4) + 512 + c] = acc1;
  }
}

// ---------------- kPack: fragment-linear bf16 packs + fp32 transposes ----------------
__global__ __launch_bounds__(256) void kPack(
    const float* __restrict__ wq, const float* __restrict__ wk, const float* __restrict__ wv,
    const float* __restrict__ wr, const float* __restrict__ pw1, const float* __restrict__ pw2,
    const float* __restrict__ d1, char* __restrict__ wsb) {
  int i = blockIdx.x * 256 + threadIdx.x;
  float* wsf = (float*)wsb;
  unsigned short* u16 = (unsigned short*)wsb;
  if (i < 270336) {  // Wbig: 33 tiles, K=512 (ks 0..15)
    int T = i >> 13, r = i & 8191;
    int ks = r >> 9, l = (r >> 3) & 63, j = r & 7;
    int row = T * 16 + (l & 15);
    int col = ks * 32 + (l >> 4) * 8 + j;
    float v;
    if (row < 256) v = wq[row * 512 + col];
    else if (row < 512) v = wsf[(B_WL / 4) + (row - 256) * 512 + col];
    else if (row < 514) v = wsf[(B_WDX / 4) + (row - 512) * 512 + col];
    else v = 0.f;
    u16[(B_WBIG / 2) + i] = (unsigned short)f2bfu(v);
    return;
  }
  i -= 270336;
  if (i < 262144) {  // Wkv: 32 tiles, K=512
    int T = i >> 13, r = i & 8191;
    int ks = r >> 9, l = (r >> 3) & 63, j = r & 7;
    int row = T * 16 + (l & 15);
    int col = ks * 32 + (l >> 4) * 8 + j;
    float v = row < 256 ? wk[row * 512 + col] : wv[(row - 256) * 512 + col];
    u16[(B_WKV / 2) + i] = (unsigned short)f2bfu(v);
    return;
  }
  i -= 262144;
  if (i < 131072) {  // WR: 32 tiles, K=256 (ks 0..7)
    int T = i >> 12, r = i & 4095;
    int ks = r >> 9, l = (r >> 3) & 63, j = r & 7;
    int row = T * 16 + (l & 15);
    int col = ks * 32 + (l >> 4) * 8 + j;
    u16[(B_WR / 2) + i] = (unsigned short)f2bfu(wr[row * 256 + col]);
    return;
  }
  i -= 131072;
  if (i < 262144) { int o = i >> 9, c = i & 511; wsf[(B_PW1T / 4) + c * 512 + o] = pw1[i]; return; }
  i -= 262144;
  if (i < 131072) { int o = i >> 9, c = i & 511; wsf[(B_PW2T / 4) + c * 256 + o] = pw2[i]; return; }
  i -= 131072;
  if (i < 65536) { int o = i >> 8, v = i & 255; wsf[(B_D1BT / 4) + v * 256 + o] = d1[o * 512 + 256 + v]; }
}

// ---------------- k1: b-merged keys/values MFMA, 16 waves, no colsum atomics ----------------
__global__ __launch_bounds__(1024, 1) void k1_reduce(
    const float* __restrict__ x, const float* __restrict__ y,
    const float* __restrict__ bk, const float* __restrict__ bv,
    const char* __restrict__ wsb, float* __restrict__ outp) {
  __shared__ __align__(16) unsigned char Xl[32768];
  __shared__ __align__(16) unsigned char Yl[32768];
  __shared__ __align__(16) unsigned char EVl[65536];  // el/vl; staged colsum partials first
  __shared__ float Red[1536];  // [0..511]=Z(b0,b1), [512..1535]=colsum
  unsigned char* elx = EVl;
  unsigned char* ely = EVl + 16384;
  unsigned char* vlx = EVl + 32768;
  unsigned char* vly = EVl + 49152;
  float* PSf = (float*)EVl;
  const int t = threadIdx.x;
  const int w = t >> 6, lo16 = t & 15, g = (t >> 4) & 3, l = t & 63;
  const int pt = w & 1, tq2 = (w >> 1) & 3, hf = w >> 3;
  const int p0 = pt * 16;
  const char* Wkv = wsb + B_WKV;

  if (t < 512) Red[t] = 0.f;  // Z region only (colsum written directly below)
  float csum[2][8];
#pragma unroll
  for (int b2 = 0; b2 < 2; ++b2)
#pragma unroll
    for (int i = 0; i < 8; ++i) csum[b2][i] = 0.f;
  const int n0 = blockIdx.x * 32;
  const int rowX = p0 + lo16;
  const int bbase = rowX * 1024 + g * 16;
  const int bswz = (rowX & 7) << 4;

  // ---- stage x AND y tiles, column sums ----
#pragma unroll
  for (int r = 0; r < 2; ++r) {
    int chunk = r * 1024 + t;
    int prow = chunk >> 6, j = chunk & 63;
    const float* gx = x + (size_t)(n0 + prow) * 512 + j * 8;
    const float* gy = y + (size_t)(n0 + prow) * 512 + j * 8;
    float4 x0 = *(const float4*)gx, x1 = *(const float4*)(gx + 4);
    float4 y0 = *(const float4*)gy, y1 = *(const float4*)(gy + 4);
    csum[0][0] += x0.x; csum[0][1] += x0.y; csum[0][2] += x0.z; csum[0][3] += x0.w;
    csum[0][4] += x1.x; csum[0][5] += x1.y; csum[0][6] += x1.z; csum[0][7] += x1.w;
    csum[1][0] += y0.x; csum[1][1] += y0.y; csum[1][2] += y0.z; csum[1][3] += y0.w;
    csum[1][4] += y1.x; csum[1][5] += y1.y; csum[1][6] += y1.z; csum[1][7] += y1.w;
    int byte = (prow * 1024 + j * 16) ^ ((prow & 7) << 4);
    uint4 pk;
    pk.x = pack2(x0.x, x0.y); pk.y = pack2(x0.z, x0.w);
    pk.z = pack2(x1.x, x1.y); pk.w = pack2(x1.z, x1.w);
    *(uint4*)(Xl + byte) = pk;
    pk.x = pack2(y0.x, y0.y); pk.y = pack2(y0.z, y0.w);
    pk.z = pack2(y1.x, y1.y); pk.w = pack2(y1.z, y1.w);
    *(uint4*)(Yl + byte) = pk;
  }
  // colsum partials -> PS region (no atomics)
#pragma unroll
  for (int b = 0; b < 2; ++b)
#pragma unroll
    for (int i = 0; i < 8; ++i) PSf[t * 16 + b * 8 + i] = csum[b][i];
  __syncthreads();  // staging + PS + Red init visible
  // tree-reduce colsum: slot s = b*512 + ch; thread t handles slot t
  {
    int s = t, b = s >> 9, ch = s & 511, tlow = ch >> 3, ii = ch & 7;
    float sum = 0.f;
#pragma unroll
    for (int w2 = 0; w2 < 16; ++w2) sum += PSf[(w2 * 64 + tlow) * 16 + b * 8 + ii];
    Red[512 + s] = sum;
  }
  __syncthreads();  // PS reads done; el/vl writes may begin

  // ---- merged GEMM: each weight fragment -> 2 MFMAs (x and y) ----
#pragma unroll
  for (int tp = 0; tp < 2; ++tp) {
    int tq = tq2 * 2 + tp;
    int t0 = hf * 16 + tq * 2, t1 = t0 + 1;
    f32x4 ax0 = {0.f, 0.f, 0.f, 0.f}, ax1 = {0.f, 0.f, 0.f, 0.f};
    f32x4 ay0 = {0.f, 0.f, 0.f, 0.f}, ay1 = {0.f, 0.f, 0.f, 0.f};
    const char* ap = Wkv + t0 * 16384 + l * 16;
#pragma unroll
    for (int ks = 0; ks < 16; ++ks) {
      bf16x8 bx = *(const bf16x8*)(Xl + ((bbase + ks * 64) ^ bswz));
      bf16x8 by = *(const bf16x8*)(Yl + ((bbase + ks * 64) ^ bswz));
      bf16x8 af0 = *(const bf16x8*)(ap + ks * 1024);
      bf16x8 af1 = *(const bf16x8*)(ap + 16384 + ks * 1024);
      ax0 = MFMA(af0, bx, ax0); ay0 = MFMA(af0, by, ay0);
      ax1 = MFMA(af1, bx, ax1); ay1 = MFMA(af1, by, ay1);
    }
    int pp = p0 + lo16;
    if (hf == 0) {  // keys -> e, Z, el (both b)
      float ex0[4], ex1[4], ey0[4], ey1[4];
#pragma unroll
      for (int r = 0; r < 4; ++r) {
        float bk0 = bk[t0 * 16 + g * 4 + r], bk1 = bk[t1 * 16 + g * 4 + r];
        ex0[r] = __expf(ax0[r] + bk0); ey0[r] = __expf(ay0[r] + bk0);
        ex1[r] = __expf(ax1[r] + bk1); ey1[r] = __expf(ay1[r] + bk1);
      }
#pragma unroll
      for (int r = 0; r < 4; ++r) {
        float v0 = ex0[r], v1 = ex1[r], v2 = ey0[r], v3 = ey1[r];
        for (int m = 8; m >= 1; m >>= 1) {
          v0 += __shfl_xor(v0, m, 16); v1 += __shfl_xor(v1, m, 16);
          v2 += __shfl_xor(v2, m, 16); v3 += __shfl_xor(v3, m, 16);
        }
        if (lo16 == 0) {
          atomicAdd(&Red[t0 * 16 + g * 4 + r], v0);
          atomicAdd(&Red[t1 * 16 + g * 4 + r], v1);
          atomicAdd(&Red[256 + t0 * 16 + g * 4 + r], v2);
          atomicAdd(&Red[256 + t1 * 16 + g * 4 + r], v3);
        }
      }
#pragma unroll
      for (int r = 0; r < 4; ++r) {
        int row0 = t0 * 16 + g * 4 + r;
        int row1 = t1 * 16 + g * 4 + r;
        int a0 = (row0 * 64 + pp * 2) ^ ((row0 & 3) << 4);
        int a1 = (row1 * 64 + pp * 2) ^ ((row1 & 3) << 4);
        *(unsigned short*)(elx + a0) = (unsigned short)f2bfu(ex0[r]);
        *(unsigned short*)(elx + a1) = (unsigned short)f2bfu(ex1[r]);
        *(unsigned short*)(ely + a0) = (unsigned short)f2bfu(ey0[r]);
        *(unsigned short*)(ely + a1) = (unsigned short)f2bfu(ey1[r]);
      }
    } else {  // values -> vl (both b)
#pragma unroll
      for (int r = 0; r < 4; ++r) {
        int row0 = (t0 - 16) * 16 + g * 4 + r;
        int row1 = (t1 - 16) * 16 + g * 4 + r;
        float bv0 = bv[row0], bv1 = bv[row1];
        int a0 = (row0 * 64 + pp * 2) ^ ((row0 & 3) << 4);
        int a1 = (row1 * 64 + pp * 2) ^ ((row1 & 3) << 4);
        *(unsigned short*)(vlx + a0) = (unsigned short)f2bfu(ax0[r] + bv0);
        *(unsigned short*)(vlx + a1) = (unsigned short)f2bfu(ax1[r] + bv1);
        *(unsigned short*)(vly + a0) = (unsigned short)f2bfu(ay0[r] + bv0);
        *(unsigned short*)(vly + a1) = (unsigned short)f2bfu(ay1[r] + bv1);
      }
    }
  }
  __syncthreads();  // el/vl + Red complete

  // ---- transient ctx: wave = (bsel, head); per m: 2 MFMAs -> immediate store ----
  {
    const int h2 = w & 7, bsel = w >> 3;
    const unsigned char* el = bsel ? ely : elx;
    const unsigned char* vl = bsel ? vly : vlx;
    unsigned* ctxp = (unsigned*)outp + (size_t)blockIdx.x * 8192;
#pragma unroll
    for (int m = 0; m < 2; ++m) {
      int rowe = h2 * 32 + m * 16 + lo16;
      bf16x8 ea = *(const bf16x8*)(el + ((rowe * 64 + g * 16) ^ ((rowe & 3) << 4)));
      f32x4 c0 = {0.f, 0.f, 0.f, 0.f}, c1 = {0.f, 0.f, 0.f, 0.f};
      {
        int rowv = h2 * 32 + lo16;
        bf16x8 vb = *(const bf16x8*)(vl + ((rowv * 64 + g * 16) ^ ((rowv & 3) << 4)));
        c0 = MFMA(ea, vb, c0);
      }
      {
        int rowv = h2 * 32 + 16 + lo16;
        bf16x8 vb = *(const bf16x8*)(vl + ((rowv * 64 + g * 16) ^ ((rowv & 3) << 4)));
        c1 = MFMA(ea, vb, c1);
      }
#pragma unroll
      for (int r = 0; r < 4; ++r)
        ctxp[((bsel * 2 + m) * 4 + r) * 512 + h2 * 64 + l] = pack2(c0[r], c1[r]);
    }
    float* redp = outp + 8388608 + blockIdx.x * 1536;
    for (int i = t; i < 1536; i += 1024) redp[i] = Red[i];
  }
}

// ---------------- k1b: tree-reduce the 1024 partial copies ----------------
__global__ __launch_bounds__(512) void k1b(const float* __restrict__ outp, char* __restrict__ wsb) {
  __shared__ float R[512];
  const int t = threadIdx.x, blk = blockIdx.x;
  float* wsf = (float*)wsb;
  if (blk < 64) {  // ctx: 128 slots per block, 4 partial-sum lanes each
    int sl = t & 127, part = t >> 7;
    int slot = blk * 128 + sl;
    const unsigned* p = (const unsigned*)outp;
    float s0 = 0.f, s1 = 0.f;
    for (int c = part * 256; c < part * 256 + 256; ++c) {
      unsigned wv = p[(size_t)c * 8192 + slot];
      s0 += __uint_as_float(wv << 16);
      s1 += __uint_as_float(wv & 0xffff0000u);
    }
    R[sl * 4 + part] = s0;
    __syncthreads();
    float sum0 = R[sl * 4] + R[sl * 4 + 1] + R[sl * 4 + 2] + R[sl * 4 + 3];
    __syncthreads();
    R[sl * 4 + part] = s1;
    __syncthreads();
    float sum1 = R[sl * 4] + R[sl * 4 + 1] + R[sl * 4 + 2] + R[sl * 4 + 3];
    if (part == 0) {
      int t_ = slot & 511, bmr = slot >> 9;
      int r = bmr & 3, m = (bmr >> 2) & 1, b = bmr >> 3;
      int h = t_ >> 6, g = (t_ >> 4) & 3, lo16 = t_ & 15;
      int klocal = m * 16 + g * 4 + r;
      int base = ((b * 8 + h) * 32 + klocal) * 32;
      wsf[(B_CTXC / 4) + base + lo16] = sum0;
      wsf[(B_CTXC / 4) + base + 16 + lo16] = sum1;
    }
  } else {  // red: 3 blocks x 512 values
    int j = (blk - 64) * 512 + t;
    const float* rp = outp + 8388608;
    float s = 0.f;
    for (int c = 0; c < 1024; ++c) s += rp[(size_t)c * 1536 + j];
    if (j < 512) wsf[(B_ZP / 4) + j] = s;
    else wsf[(B_COLS / 4) + (j - 512)] = s;
  }
}

// ---------------- k2: ctx normalize (packed write), pool chain, constD, biasOut ----------------
__global__ __launch_bounds__(512) void k2_finalize(
    const float* __restrict__ pbn1, const float* __restrict__ pbn2,
    const float* __restrict__ dbn1, const float* __restrict__ d2,
    const float* __restrict__ ea_br, char* __restrict__ wsb) {
  __shared__ float HI[1024], H1[1024], H2l[512], VB[512], slot[4];
  const int t = threadIdx.x;
  float* wsf = (float*)wsb;
  unsigned short* u16 = (unsigned short*)wsb;
  for (int idx = t; idx < 16384; idx += 512) {
    float s = wsf[(B_CTXC / 4) + idx];
    int v = idx & 31, row = idx >> 5;
    int b = row >> 8, kr = row & 255;
    int hh = kr >> 5, kh = kr & 31;
    float val = s / wsf[(B_ZP / 4) + b * 256 + kr];
    int m = v >> 4;
    int lane = (v & 15) + ((kh >> 3) << 4);
    int j = kh & 7;
    u16[(B_CTXT / 2) + (((b * 8 + hh) * 2 + m) << 9) + lane * 8 + j] = (unsigned short)f2bfu(val);
  }
  if (t < 4) slot[t] = 0.f;
  for (int idx = t; idx < 1024; idx += 512) HI[idx] = wsf[(B_COLS / 4) + idx] * (1.f / 32768.f);
  __syncthreads();
  {
    int o = t;
    float gg = pbn1[o], be = pbn1[512 + o], mn = pbn1[1024 + o], va = pbn1[1536 + o];
    float sc = gg * rsqrtf(va + 1e-5f), sh = be - mn * sc;
    for (int b = 0; b < 2; ++b) {
      float acc = 0.f;
      for (int c = 0; c < 512; ++c) acc = fmaf(wsf[(B_PW1T / 4) + c * 512 + o], HI[b * 512 + c], acc);
      H1[b * 512 + o] = acc * sc + sh;
    }
  }
  __syncthreads();
  if (t < 256) {
    int o = t;
    float gg = pbn2[o], be = pbn2[256 + o], mn = pbn2[512 + o], va = pbn2[768 + o];
    float sc = gg * rsqrtf(va + 1e-5f), sh = be - mn * sc;
    for (int b = 0; b < 2; ++b) {
      float acc = 0.f;
      for (int c = 0; c < 512; ++c) acc = fmaf(wsf[(B_PW2T / 4) + c * 256 + o], H1[b * 512 + c], acc);
      float vv = acc * sc + sh;
      H2l[b * 256 + o] = vv;
      wsf[(B_HIGH2 / 4) + b * 256 + o] = vv;
    }
  }
  __syncthreads();
  if (t < 256) {
    int o = t;
    float gg = dbn1[o], be = dbn1[256 + o], mn = dbn1[512 + o], va = dbn1[768 + o];
    float sd = gg * rsqrtf(va + 1e-5f), fd = be - mn * sd;
    for (int b = 0; b < 2; ++b) {
      float acc = 0.f;
      for (int v = 0; v < 256; ++v) acc = fmaf(wsf[(B_D1BT / 4) + v * 256 + o], H2l[b * 256 + v], acc);
      VB[b * 256 + o] = sd * acc + fd;
    }
  }
  __syncthreads();
  if (t < 256) {
    int o = t;
    for (int b = 0; b < 2; ++b)
      for (int j = 0; j < 2; ++j) atomicAdd(&slot[b * 2 + j], d2[j * 256 + o] * VB[b * 256 + o]);
    float cp = wsf[(B_CPP / 4) + o];
    for (int j = 0; j < 2; ++j) {
      float w = wsf[(B_WDD / 4) + j * 256 + o] * cp;
      atomicAdd(&slot[0 + j], w);
      atomicAdd(&slot[2 + j], w);
    }
  }
  __syncthreads();
  if (t < 4) wsf[(B_CONSTD / 4) + t] = slot[t];
  {
    int o = t;
    float bb = 0.5f * ea_br[o];
    if (o >= 256) bb += 0.5f * wsf[(B_CPP / 4) + o - 256];
    wsf[(B_BIASO / 4) + o] = bb;
  }
}

// ---------------- k3: b-merged main pass, LDS f32 accumulator, 16 waves ----------------
__global__ __launch_bounds__(1024, 1) void k3_main(
    const float* __restrict__ x, const float* __restrict__ y,
    const float* __restrict__ bq, const char* __restrict__ wsb,
    float* __restrict__ out) {
  __shared__ __align__(16) unsigned char Xl[32768];
  __shared__ __align__(16) unsigned char Yl[32768];
  __shared__ __align__(16) unsigned char ACCb[65536];  // f32 [32 pos][512 ch], swizzled
  __shared__ __align__(16) unsigned char Ql[16384];
  __shared__ float wgtl[64];  // [b][pos]
  const int t = threadIdx.x;
  const int w = t >> 6, lo16 = t & 15, g = (t >> 4) & 3, l = t & 63;
  const int pt = w & 1, tq2 = (w >> 1) & 3, hf = w >> 3;
  const int p0 = pt * 16;
  const int n0 = blockIdx.x * 32;
  const char* Wbig = wsb + B_WBIG;
  const char* WRp = wsb + B_WR;
  const char* CTXT = wsb + B_CTXT;
  const float* wsf = (const float*)wsb;
  unsigned char* Qslab = Ql + pt * 8192;
  const int rowX = p0 + lo16;
  const int bbase = rowX * 1024 + g * 16;
  const int bswz = (rowX & 7) << 4;
  const int swzq = (lo16 & 7) << 4;

  // ---- stage x,y; init ACC = 0.25*(x+y) ----
#pragma unroll
  for (int r = 0; r < 2; ++r) {
    int chunk = r * 1024 + t;
    int prow = chunk >> 6, j = chunk & 63;
    const float* gx = x + (size_t)(n0 + prow) * 512 + j * 8;
    const float* gy = y + (size_t)(n0 + prow) * 512 + j * 8;
    float4 x0 = *(const float4*)gx, x1 = *(const float4*)(gx + 4);
    float4 y0 = *(const float4*)gy, y1 = *(const float4*)(gy + 4);
    int byte = (prow * 1024 + j * 16) ^ ((prow & 7) << 4);
    uint4 pk;
    pk.x = pack2(x0.x, x0.y); pk.y = pack2(x0.z, x0.w);
    pk.z = pack2(x1.x, x1.y); pk.w = pack2(x1.z, x1.w);
    *(uint4*)(Xl + byte) = pk;
    pk.x = pack2(y0.x, y0.y); pk.y = pack2(y0.z, y0.w);
    pk.z = pack2(y1.x, y1.y); pk.w = pack2(y1.z, y1.w);
    *(uint4*)(Yl + byte) = pk;
    int abase = prow * 2048 + j * 32;
    int aswz = (prow & 7) << 4;
    f32x4 a0 = {0.25f * (x0.x + y0.x), 0.25f * (x0.y + y0.y), 0.25f * (x0.z + y0.z), 0.25f * (x0.w + y0.w)};
    f32x4 a1 = {0.25f * (x1.x + y1.x), 0.25f * (x1.y + y1.y), 0.25f * (x1.z + y1.z), 0.25f * (x1.w + y1.w)};
    *(f32x4*)(ACCb + (abase ^ aswz)) = a0;
    *(f32x4*)(ACCb + ((abase + 16) ^ aswz)) = a1;
  }
  __syncthreads();

  unsigned Qy[2][4];  // packed Q for b=1, per tp

  // ---- merged tp loop ----
#pragma unroll
  for (int tp = 0; tp < 2; ++tp) {
    int tq = tq2 * 2 + tp;
    int t0 = hf * 16 + tq * 2;
    f32x4 ax0 = {0.f, 0.f, 0.f, 0.f}, ax1 = {0.f, 0.f, 0.f, 0.f};
    f32x4 ay0 = {0.f, 0.f, 0.f, 0.f}, ay1 = {0.f, 0.f, 0.f, 0.f};
    const char* ap = Wbig + t0 * 16384 + l * 16;
#pragma unroll
    for (int ks = 0; ks < 16; ++ks) {
      bf16x8 bx = *(const bf16x8*)(Xl + ((bbase + ks * 64) ^ bswz));
      bf16x8 by = *(const bf16x8*)(Yl + ((bbase + ks * 64) ^ bswz));
      bf16x8 af0 = *(const bf16x8*)(ap + ks * 1024);
      bf16x8 af1 = *(const bf16x8*)(ap + 16384 + ks * 1024);
      ax0 = MFMA(af0, bx, ax0); ay0 = MFMA(af0, by, ay0);
      ax1 = MFMA(af1, bx, ax1); ay1 = MFMA(af1, by, ay1);
    }
    if (hf == 0) {  // Q head tq: softmax both b; store b0 now, keep b1 packed
      int hh = tq;
#pragma unroll
      for (int b = 0; b < 2; ++b) {
        f32x4 a0 = b ? ay0 : ax0, a1 = b ? ay1 : ax1;
        float q[8], e[8];
        float mx = -1e30f;
#pragma unroll
        for (int r = 0; r < 4; ++r) {
          q[r] = a0[r] + bq[hh * 32 + g * 4 + r];
          q[4 + r] = a1[r] + bq[hh * 32 + 16 + g * 4 + r];
          mx = fmaxf(mx, fmaxf(q[r], q[4 + r]));
        }
        mx = fmaxf(mx, __shfl_xor(mx, 16, 64));
        mx = fmaxf(mx, __shfl_xor(mx, 32, 64));
        float sm = 0.f;
#pragma unroll
        for (int r = 0; r < 8; ++r) { e[r] = __expf(q[r] - mx); sm += e[r]; }
        sm += __shfl_xor(sm, 16, 64);
        sm += __shfl_xor(sm, 32, 64);
        float inv = 1.f / sm;
        unsigned p0w = pack2(e[0] * inv, e[1] * inv), p1w = pack2(e[2] * inv, e[3] * inv);
        unsigned p2w = pack2(e[4] * inv, e[5] * inv), p3w = pack2(e[6] * inv, e[7] * inv);
        if (b == 0) {
          int base_q = lo16 * 512 + hh * 64 + g * 8;
          uint2 w0; w0.x = p0w; w0.y = p1w;
          uint2 w1; w1.x = p2w; w1.y = p3w;
          *(uint2*)(Qslab + (base_q ^ swzq)) = w0;
          *(uint2*)(Qslab + ((base_q + 32) ^ swzq)) = w1;
        } else {
          Qy[tp][0] = p0w; Qy[tp][1] = p1w; Qy[tp][2] = p2w; Qy[tp][3] = p3w;
        }
      }
    } else {  // L tiles: accumulate 0.25*(Lx+Ly) into ACC
      int tile0 = t0 - 16;  // even, 0..14
#pragma unroll
      for (int half = 0; half < 2; ++half) {
        f32x4 axs = half ? ax1 : ax0;
        f32x4 ays = half ? ay1 : ay0;
        int ch4 = 64 + (tile0 + half) * 4 + g;  // ch = 256 + tile*16 + g*4
        int ab = ((p0 + lo16) * 2048 + ch4 * 16) ^ (((p0 + lo16) & 7) << 4);
        f32x4 cur = *(const f32x4*)(ACCb + ab);
        cur += 0.25f * (axs + ays);
        *(f32x4*)(ACCb + ab) = cur;
      }
    }
  }

  // ---- delta (hf1, tq2==0): both b, one weight read ----
  if (hf == 1 && tq2 == 0) {
    f32x4 adx = {0.f, 0.f, 0.f, 0.f}, ady = {0.f, 0.f, 0.f, 0.f};
    const char* ap = Wbig + 32 * 16384 + l * 16;
#pragma unroll
    for (int ks = 0; ks < 16; ++ks) {
      bf16x8 bx = *(const bf16x8*)(Xl + ((bbase + ks * 64) ^ bswz));
      bf16x8 by = *(const bf16x8*)(Yl + ((bbase + ks * 64) ^ bswz));
      bf16x8 af = *(const bf16x8*)(ap + ks * 1024);
      adx = MFMA(af, bx, adx);
      ady = MFMA(af, by, ady);
    }
    if (g == 0) {
      int pos = n0 + p0 + lo16;
      float base_gx = -1.f + 2.f * (float)pos / 32767.f;
#pragma unroll
      for (int b = 0; b < 2; ++b) {
        f32x4 ad = b ? ady : adx;
        float d0 = ad[0] + wsf[(B_CONSTD / 4) + b * 2 + 0];
        float d1 = ad[1] + wsf[(B_CONSTD / 4) + b * 2 + 1];
        float gxv = base_gx + d0;
        float gyv = -1.f + d1;
        float ix = gxv * 0.5f, iy = gyv * 0.5f;
        float wx = fminf(fmaxf(1.f - fabsf(ix), 0.f), 1.f);
        float wy = fminf(fmaxf(1.f - fabsf(iy), 0.f), 1.f);
        wgtl[b * 32 + p0 + lo16] = wx * wy;
      }
    }
  }

  // ---- att (hf0): each wave owns 2 heads; b=0 from Qslab then b=1 in-wave ----
  f32x4 attacc[2][2];
#pragma unroll
  for (int i = 0; i < 2; ++i)
#pragma unroll
    for (int m = 0; m < 2; ++m) attacc[i][m] = (f32x4){0.f, 0.f, 0.f, 0.f};
  if (hf == 0) {
#pragma unroll
    for (int i = 0; i < 2; ++i) {
      int hh = tq2 * 2 + i;
      bf16x8 qf = *(const bf16x8*)(Qslab + ((lo16 * 512 + hh * 64 + g * 16) ^ swzq));
      const char* cp = CTXT + (0 * 8 + hh) * 2048 + l * 16;
      bf16x8 c0 = *(const bf16x8*)(cp);
      bf16x8 c1 = *(const bf16x8*)(cp + 1024);
      attacc[i][0] = MFMA(c0, qf, attacc[i][0]);
      attacc[i][1] = MFMA(c1, qf, attacc[i][1]);
    }
    // overwrite with Q_y (same-wave LDS roundtrip; heads private to this wave)
#pragma unroll
    for (int tp = 0; tp < 2; ++tp) {
      int hh = tq2 * 2 + tp;
      int base_q = lo16 * 512 + hh * 64 + g * 8;
      uint2 w0; w0.x = Qy[tp][0]; w0.y = Qy[tp][1];
      uint2 w1; w1.x = Qy[tp][2]; w1.y = Qy[tp][3];
      *(uint2*)(Qslab + (base_q ^ swzq)) = w0;
      *(uint2*)(Qslab + ((base_q + 32) ^ swzq)) = w1;
    }
#pragma unroll
    for (int i = 0; i < 2; ++i) {
      int hh = tq2 * 2 + i;
      bf16x8 qf = *(const bf16x8*)(Qslab + ((lo16 * 512 + hh * 64 + g * 16) ^ swzq));
      const char* cp = CTXT + (1 * 8 + hh) * 2048 + l * 16;
      bf16x8 c0 = *(const bf16x8*)(cp);
      bf16x8 c1 = *(const bf16x8*)(cp + 1024);
      attacc[i][0] = MFMA(c0, qf, attacc[i][0]);
      attacc[i][1] = MFMA(c1, qf, attacc[i][1]);
    }
    // pack attS -> Qslab
#pragma unroll
    for (int i = 0; i < 2; ++i) {
      int hh = tq2 * 2 + i;
#pragma unroll
      for (int m = 0; m < 2; ++m) {
        f32x4 v = attacc[i][m];
        uint2 wv;
        wv.x = pack2(v[0], v[1]); wv.y = pack2(v[2], v[3]);
        int byte = (lo16 * 512 + hh * 64 + m * 32 + g * 8) ^ swzq;
        *(uint2*)(Qslab + byte) = wv;
      }
    }
  }
  __syncthreads();  // attS + wgtl + ACC(L) complete

  // ---- reprojection -> ACC ----
#pragma unroll
  for (int tp = 0; tp < 2; ++tp) {
    int tq = tq2 * 2 + tp;
    int T0 = hf * 16 + tq * 2;
    f32x4 r0 = {0.f, 0.f, 0.f, 0.f}, r1 = {0.f, 0.f, 0.f, 0.f};
    const char* ap = WRp + T0 * 8192 + l * 16;
#pragma unroll
    for (int ks = 0; ks < 8; ++ks) {
      bf16x8 brf = *(const bf16x8*)(Qslab + ((lo16 * 512 + g * 16 + ks * 64) ^ swzq));
      bf16x8 a0 = *(const bf16x8*)(ap + ks * 1024);
      bf16x8 a1 = *(const bf16x8*)(ap + 8192 + ks * 1024);
      r0 = MFMA(a0, brf, r0);
      r1 = MFMA(a1, brf, r1);
    }
#pragma unroll
    for (int half = 0; half < 2; ++half) {
      f32x4 rr = half ? r1 : r0;
      int ch4 = (hf * 256 + tq * 32 + half * 16) / 4 + g;
      int ab = ((p0 + lo16) * 2048 + ch4 * 16) ^ (((p0 + lo16) & 7) << 4);
      f32x4 cur = *(const f32x4*)(ACCb + ab);
      cur += 0.25f * rr;
      *(f32x4*)(ACCb + ab) = cur;
    }
  }
  __syncthreads();  // ACC final

  // ---- output pass: ACC + bias + CAM-sampled term ----
  const float* bo = wsf + (B_BIASO / 4);
#pragma unroll
  for (int i = 0; i < 4; ++i) {
    int idx = i * 1024 + t;      // f32x4 index over [32][128]
    int pos = idx >> 7, c4 = idx & 127;
    int ab = (pos * 2048 + c4 * 16) ^ ((pos & 7) << 4);
    f32x4 acc = *(const f32x4*)(ACCb + ab);
    f32x4 bb = *(const f32x4*)(bo + c4 * 4);
    if (c4 < 64) {
      f32x4 h20 = *(const f32x4*)(wsf + (B_HIGH2 / 4) + c4 * 4);
      f32x4 h21 = *(const f32x4*)(wsf + (B_HIGH2 / 4) + 256 + c4 * 4);
      float wg0 = wgtl[pos], wg1 = wgtl[32 + pos];
      acc += (0.25f * wg0) * h20 + (0.25f * wg1) * h21;
    }
    acc += bb;
    *(f32x4*)(out + (size_t)(n0 + pos) * 512 + c4 * 4) = acc;
  }
}

extern "C" void kernel_launch(void* const* d_in, const int* in_sizes, int n_in,
                              void* d_out, int out_size, void* d_ws, size_t ws_size,
                              hipStream_t stream) {
  const float* x = (const float*)d_in[0];
  const float* y = (const float*)d_in[1];
  const float* ea_wk = (const float*)d_in[2];
  const float* ea_bk = (const float*)d_in[3];
  const float* ea_wq = (const float*)d_in[4];
  const float* ea_bq = (const float*)d_in[5];
  const float* ea_wv = (const float*)d_in[6];
  const float* ea_bv = (const float*)d_in[7];
  const float* ea_wr = (const float*)d_in[8];
  const float* ea_br = (const float*)d_in[9];
  const float* pool_w1 = (const float*)d_in[10];
  const float* pool_bn1 = (const float*)d_in[11];
  const float* pool_w2 = (const float*)d_in[12];
  const float* pool_bn2 = (const float*)d_in[13];
  const float* adapt_w1 = (const float*)d_in[14];
  const float* adapt_bn1 = (const float*)d_in[15];
  const float* adapt_w2 = (const float*)d_in[16];
  const float* adapt_bn2 = (const float*)d_in[17];
  const float* delta_w1 = (const float*)d_in[18];
  const float* delta_bn1 = (const float*)d_in[19];
  const float* delta_w2 = (const float*)d_in[20];
  char* ws = (char*)d_ws;
  float* out = (float*)d_out;

  kW1<<<256, 512, 0, stream>>>(adapt_w1, adapt_bn1, adapt_w2, adapt_bn2, ws);
  kW2<<<1, 512, 0, stream>>>(delta_w1, delta_bn1, delta_w2, ws);
  kPack<<<4384, 256, 0, stream>>>(ea_wq, ea_wk, ea_wv, ea_wr, pool_w1, pool_w2, delta_w1, ws);
  k1_reduce<<<1024, 1024, 0, stream>>>(x, y, ea_bk, ea_bv, ws, out);
  k1b<<<67, 512, 0, stream>>>(out, ws);
  k2_finalize<<<1, 512, 0, stream>>>(pool_bn1, pool_bn2, delta_bn1, delta_w2, ea_br, ws);
  k3_main<<<1024, 1024, 0, stream>>>(x, y, ea_bq, ws, out);
}